// Round 2
// baseline (843.455 us; speedup 1.0000x reference)
//
#include <hip/hip_runtime.h>

#define LSP 16384            // H*W
#define NBATCH 8
#define NPOS (NBATCH*LSP)    // 131072
#define NHID 340
#define ATT_SCALE 0.35355339059327373f

// ---- workspace layout (bytes) ----
#define OFF_A        0ULL          // 32MB: xn_t -> resg_t -> xn2_t
#define OFF_B        33554432ULL   // 64MB: kv -> qo ; FFN: pbuf2 (44MB)
#define OFF_GT2      79691776ULL   // 22MB: g_t2 (per 2-batch)
#define OFF_C        100663296ULL  // 32MB: lepe ; FFN: gbuf (22.3MB)
#define OFF_PART     134217728ULL  // 160KB
#define OFF_STATS    134381568ULL  // 40KB
#define OFF_SIN      134422528ULL  // 512KB
#define OFF_COS      134946816ULL  // 512KB
#define OFF_WQ       135471104ULL  // 512x128 bf16
#define OFF_WQO      135602176ULL  // 256x128 bf16
#define OFF_QOB      135667712ULL  // 256 f32
#define OFF_WP       135668736ULL  // 128x128 bf16
#define OFF_WFI      135701504ULL  // 704x128 bf16
#define OFF_WFO      135881728ULL  // 128x352 bf16
#define WS_NEEDED    135971840ULL

typedef __attribute__((ext_vector_type(8))) short short8;
typedef __attribute__((ext_vector_type(4))) float floatx4;

__device__ __forceinline__ float bf2f(unsigned short u){
  union { unsigned int i; float f; } c; c.i = ((unsigned int)u) << 16; return c.f;
}
__device__ __forceinline__ unsigned short f2bf(float f){
  union { float f; unsigned int i; } c; c.f = f;
  unsigned int r = c.i + 0x7fffu + ((c.i >> 16) & 1u);
  return (unsigned short)(r >> 16);
}

// read 12 bf16 (4B-aligned) from LDS -> fp32
__device__ __forceinline__ void load_row12(const unsigned short* p, float* r){
  const unsigned int* q = (const unsigned int*)p;
  #pragma unroll
  for (int i=0;i<6;i++){
    unsigned int u = q[i];
    r[2*i]   = bf2f((unsigned short)(u & 0xffffu));
    r[2*i+1] = bf2f((unsigned short)(u >> 16));
  }
}

// read 10 bf16 (1 edge + aligned 8 + 1 edge) from LDS -> fp32
__device__ __forceinline__ void load_row10(const unsigned short* base, float* r){
  short8 B = *(const short8*)(base + 8);
  r[0] = bf2f(base[7]);
  #pragma unroll
  for (int i=0;i<8;i++) r[1+i] = bf2f((unsigned short)B[i]);
  r[9] = bf2f(base[16]);
}

// ------------------- RoPE tables: sin/cos[l][8] fp32 -------------------
__global__ void rope_kernel(float* __restrict__ sin_t, float* __restrict__ cos_t){
  int l = blockIdx.x*256 + threadIdx.x;
  if (l >= LSP) return;
  int h = l >> 7, w = l & 127;
  float s0 = sinf((float)h),        c0 = cosf((float)h);
  float s1 = sinf((float)h*1e-4f),  c1 = cosf((float)h*1e-4f);
  float s2 = sinf((float)w),        c2 = cosf((float)w);
  float s3 = sinf((float)w*1e-4f),  c3 = cosf((float)w*1e-4f);
  float* sp = sin_t + l*8; float* cp = cos_t + l*8;
  sp[0]=s0; sp[1]=s0; sp[2]=s1; sp[3]=s1; sp[4]=s2; sp[5]=s2; sp[6]=s3; sp[7]=s3;
  cp[0]=c0; cp[1]=c0; cp[2]=c1; cp[3]=c1; cp[4]=c2; cp[5]=c2; cp[6]=c3; cp[7]=c3;
}

// ------------------- weight fp32 -> padded bf16 -------------------
__global__ void wconv_kernel(const float* __restrict__ src, unsigned short* __restrict__ dst,
                             int O, int K, int OP, int KP){
  int i = blockIdx.x*256 + threadIdx.x;
  if (i >= OP*KP) return;
  int o = i / KP, k = i - o*KP;
  float v = (o < O && k < K) ? src[o*K + k] : 0.f;
  dst[i] = f2bf(v);
}

// ------------------- q/o weight+bias reorder: rows [0..128)+[384..512) -------------------
__global__ void reorder_qo_kernel(const float* __restrict__ qkvo_w, const float* __restrict__ qkvo_b,
                                  unsigned short* __restrict__ wqo, float* __restrict__ qo_bias){
  int i = blockIdx.x*256 + threadIdx.x;
  if (i < 256){
    qo_bias[i] = qkvo_b[(i < 128) ? i : i + 256];
  }
  if (i >= 256*128) return;
  int o = i >> 7, k = i & 127;
  int srow = (o < 128) ? o : o + 256;
  wqo[i] = f2bf(qkvo_w[srow*128 + k]);
}

// ------------------- LayerNorm over 128 channels; out position-major bf16 -------------------
// 2 threads per position (64 channels each); grid = NPOS/128 blocks.
__launch_bounds__(256)
__global__ void ln_kernel(const float* __restrict__ x, const float* __restrict__ gam,
                          const float* __restrict__ bet, unsigned short* __restrict__ out_t){
  __shared__ float ps[2][128], pq[2][128];
  int t = threadIdx.x;
  int pidx = t & 127;
  int half = t >> 7;
  int p = blockIdx.x*128 + pidx;
  int b = p >> 14, l = p & 16383;
  const float* xb = x + (((size_t)b) << 21) + (((size_t)(half*64)) << 14) + l;
  float vals[64];
  float s = 0.f, sq = 0.f;
  #pragma unroll 16
  for (int c = 0; c < 64; c++){
    float v = xb[(size_t)c << 14];
    vals[c] = v;
    s += v; sq += v*v;
  }
  ps[half][pidx] = s; pq[half][pidx] = sq;
  __syncthreads();
  float S = ps[0][pidx] + ps[1][pidx];
  float Q = pq[0][pidx] + pq[1][pidx];
  float mu = S * 0.0078125f;
  float var = Q * 0.0078125f - mu*mu;
  float rstd = rsqrtf(var + 1e-5f);
  unsigned short* orow = out_t + ((size_t)p << 7) + half*64;
  #pragma unroll
  for (int c0 = 0; c0 < 64; c0 += 8){
    short8 vv;
    #pragma unroll
    for (int i = 0; i < 8; i++){
      int c = c0 + i;
      int cg = half*64 + c;
      float v = (vals[c] - mu) * rstd * gam[cg] + bet[cg];
      vv[i] = (short)f2bf(v);
    }
    *(short8*)(orow + c0) = vv;
  }
}

// ------------------- MFMA GEMM: out[b][o][l] = sum_k W[o][k]*in_t[b*L+l][k] -------------------
// oc chunk (64 output channels) from blockIdx.y. Epilogue staged through LDS for
// coalesced short8/float4 stores and float4 resid loads.
template<int OPAD, int KPAD, bool HASBIAS, bool RESID, bool OUTBF16>
__launch_bounds__(256)
__global__ void gemm_kernel(const unsigned short* __restrict__ in_t,
                            const unsigned short* __restrict__ wb,
                            const float* __restrict__ bias,
                            const float* __restrict__ resid,
                            void* __restrict__ outp){
  constexpr int KS = KPAD / 32;
  constexpr int SBYTES = OUTBF16 ? (64*136*2) : (64*132*4);
  __shared__ __align__(16) unsigned char smem[SBYTES];
  const int l0 = blockIdx.x * 128;
  const int b = l0 >> 14;
  const int lloc0 = l0 & 16383;
  const int t = threadIdx.x;
  const int lane = t & 63;
  const int wv = t >> 6;
  const int lane15 = lane & 15;
  const int quad = lane >> 4;
  const int oc = blockIdx.y;

  short8 fb[2][KS];
  {
    const unsigned short* base = in_t + ((size_t)(l0 + wv*32 + lane15)) * KPAD + quad*8;
    #pragma unroll
    for (int nt = 0; nt < 2; nt++){
      #pragma unroll
      for (int ks = 0; ks < KS; ks++)
        fb[nt][ks] = *(const short8*)(base + (size_t)nt*16*KPAD + ks*32);
    }
  }
  floatx4 acc[4][2];
  #pragma unroll
  for (int mt=0; mt<4; mt++)
    #pragma unroll
    for (int nt=0; nt<2; nt++)
      acc[mt][nt] = (floatx4){0.f,0.f,0.f,0.f};
  #pragma unroll
  for (int ks = 0; ks < KS; ks++){
    short8 fa[4];
    const unsigned short* wrow = wb + ((size_t)(oc*64 + lane15)) * KPAD + ks*32 + quad*8;
    #pragma unroll
    for (int mt=0; mt<4; mt++)
      fa[mt] = *(const short8*)(wrow + (size_t)mt*16*KPAD);
    #pragma unroll
    for (int mt=0; mt<4; mt++)
      #pragma unroll
      for (int nt=0; nt<2; nt++)
        acc[mt][nt] = __builtin_amdgcn_mfma_f32_16x16x32_bf16(fa[mt], fb[nt][ks], acc[mt][nt], 0, 0, 0);
  }

  if (OUTBF16){
    unsigned short* cs = (unsigned short*)smem;
    #pragma unroll
    for (int mt=0; mt<4; mt++)
      #pragma unroll
      for (int nt=0; nt<2; nt++)
        #pragma unroll
        for (int r=0; r<4; r++){
          const int o = mt*16 + quad*4 + r;
          float v = acc[mt][nt][r];
          if (HASBIAS) v += bias[oc*64 + o];
          cs[o*136 + wv*32 + nt*16 + lane15] = f2bf(v);
        }
    __syncthreads();
    unsigned short* og = (unsigned short*)outp;
    #pragma unroll
    for (int j=0; j<4; j++){
      int idx = j*256 + t;
      int row = idx >> 4;
      int col = (idx & 15) * 8;
      short8 v = *(const short8*)&cs[row*136 + col];
      *(short8*)&og[(((size_t)(b*OPAD + oc*64 + row)) << 14) + lloc0 + col] = v;
    }
  } else {
    float* cf = (float*)smem;
    #pragma unroll
    for (int mt=0; mt<4; mt++)
      #pragma unroll
      for (int nt=0; nt<2; nt++)
        #pragma unroll
        for (int r=0; r<4; r++){
          const int o = mt*16 + quad*4 + r;
          float v = acc[mt][nt][r];
          if (HASBIAS) v += bias[oc*64 + o];
          cf[o*132 + wv*32 + nt*16 + lane15] = v;
        }
    __syncthreads();
    float* og = (float*)outp;
    #pragma unroll
    for (int j=0; j<8; j++){
      int idx = j*256 + t;
      int row = idx >> 5;
      int col = (idx & 31) * 4;
      floatx4 v = *(const floatx4*)&cf[row*132 + col];
      if (RESID){
        floatx4 rv = *(const floatx4*)(resid + (((size_t)(b*128 + oc*64 + row)) << 14) + lloc0 + col);
        v += rv;
      }
      *(floatx4*)&og[(((size_t)(b*OPAD + oc*64 + row)) << 14) + lloc0 + col] = v;
    }
  }
}

// ------------------- lepe: depthwise 5x5, LDS-staged sliding window -------------------
// kv layout: [b][256][L], v at channel 128+c. One block per (b,c) plane.
__launch_bounds__(256)
__global__ void lepe_kernel(const unsigned short* __restrict__ kv,
                            const float* __restrict__ lw, const float* __restrict__ lb,
                            unsigned short* __restrict__ lepe){
  __shared__ unsigned short lds[132*136];     // rows h+2 (0..131), cols w+2 (0..131), stride 136
  int bc = blockIdx.x;                        // b*128 + c
  int b = bc >> 7, c = bc & 127;
  int t = threadIdx.x;
  #pragma unroll
  for (int i = t; i < 132*136/8; i += 256)
    *(short8*)(lds + i*8) = (short8){0,0,0,0,0,0,0,0};
  __syncthreads();
  int band = t >> 4, wi = t & 15, w0 = wi*8;
  const unsigned short* vp = kv + (((size_t)(b*256 + 128 + c)) << 14);
  {
    #pragma unroll
    for (int it = 0; it < 8; it++){
      int hh = band + it*16;
      short8 v = *(const short8*)(vp + (hh<<7) + w0);
      unsigned int* dst = (unsigned int*)&lds[(hh+2)*136 + w0 + 2];
      union { short8 s; unsigned int u[4]; } cv; cv.s = v;
      #pragma unroll
      for (int q=0;q<4;q++) dst[q] = cv.u[q];
    }
  }
  float wt[25];
  #pragma unroll
  for (int i=0;i<25;i++) wt[i] = lw[c*25 + i];
  float bias = lb[c];
  __syncthreads();
  int h0 = band*8;
  float win[5][12];
  #pragma unroll
  for (int m=0;m<4;m++) load_row12(&lds[(h0+m)*136 + w0], win[m]);
  unsigned short* outp = lepe + ((size_t)bc << 14);
  #pragma unroll
  for (int s=0;s<8;s++){
    load_row12(&lds[(h0+4+s)*136 + w0], win[(4+s)%5]);
    short8 ov;
    #pragma unroll
    for (int j=0;j<8;j++){
      float acc = bias;
      #pragma unroll
      for (int dy=0;dy<5;dy++){
        const float* r = win[(s+dy)%5];
        #pragma unroll
        for (int dx=0;dx<5;dx++) acc += wt[dy*5+dx]*r[j+dx];
      }
      ov[j] = (short)f2bf(acc);
    }
    *(short8*)(outp + (h0+s)*128 + w0) = ov;
  }
}

// ------------------- attention reduction partials per (b,head,chunk) -------------------
__launch_bounds__(256)
__global__ void attn_partial(const unsigned short* __restrict__ kv,
                             const float* __restrict__ sin_t, const float* __restrict__ cos_t,
                             float* __restrict__ partials){
  int pair = blockIdx.x >> 2;
  int chunk = blockIdx.x & 3;
  int b = pair >> 4, hd = pair & 15;
  const unsigned short* kb = kv + (((size_t)(b*256 + hd*8)) << 14);
  const unsigned short* vb = kb + ((size_t)128 << 14);
  float red[80];
  #pragma unroll
  for (int i=0;i<80;i++) red[i]=0.f;
  int l0 = chunk*4096;
  for (int li=0; li<16; li++){
    int l = l0 + li*256 + threadIdx.x;
    float k[8], v[8], ks[8];
    #pragma unroll
    for (int e=0;e<8;e++){
      float t = bf2f(kb[((size_t)e<<14)+l]);
      k[e] = t>0.f ? t+1.f : __expf(t);
      v[e] = bf2f(vb[((size_t)e<<14)+l]);
      red[e]   += k[e];
      red[8+e] += v[e];
    }
    const float* sp = sin_t + l*8;
    const float* cp = cos_t + l*8;
    #pragma unroll
    for (int j=0;j<4;j++){
      float x1=k[2*j], x2=k[2*j+1];
      ks[2*j]   = x1*cp[2*j]   - x2*sp[2*j];
      ks[2*j+1] = x2*cp[2*j+1] + x1*sp[2*j+1];
    }
    #pragma unroll
    for (int d=0; d<8; d++)
      #pragma unroll
      for (int e=0;e<8;e++)
        red[16 + d*8 + e] += ks[d]*v[e];
  }
  #pragma unroll
  for (int off=32; off>0; off>>=1){
    #pragma unroll
    for (int i=0;i<80;i++)
      red[i] += __shfl_down(red[i], off);
  }
  __shared__ float lds[4][80];
  int lane = threadIdx.x & 63, wv = threadIdx.x >> 6;
  if (lane==0){
    #pragma unroll
    for (int i=0;i<80;i++) lds[wv][i] = red[i];
  }
  __syncthreads();
  if (threadIdx.x < 80){
    float s = lds[0][threadIdx.x]+lds[1][threadIdx.x]+lds[2][threadIdx.x]+lds[3][threadIdx.x];
    partials[(size_t)blockIdx.x*80 + threadIdx.x] = s;
  }
}

__global__ void attn_combine(const float* __restrict__ partials, float* __restrict__ stats){
  int i = blockIdx.x*256 + threadIdx.x;
  if (i >= 128*80) return;
  int pair = i / 80, idx = i - pair*80;
  float s = partials[(size_t)(pair*4+0)*80+idx] + partials[(size_t)(pair*4+1)*80+idx]
          + partials[(size_t)(pair*4+2)*80+idx] + partials[(size_t)(pair*4+3)*80+idx];
  s *= (idx < 16) ? (1.f/LSP) : (ATT_SCALE/LSP);
  stats[i] = s;
}

// ------------------- attention apply + lepe add + o-gate; out position-major bf16 -------------------
__launch_bounds__(256)
__global__ void attn_apply_kernel(const unsigned short* __restrict__ qo,
                                  const unsigned short* __restrict__ lepe,
                                  const float* __restrict__ stats,
                                  const float* __restrict__ sin_t,
                                  const float* __restrict__ cos_t,
                                  unsigned short* __restrict__ resg_t){
  __shared__ float st[16*80];
  int p0 = blockIdx.x * 256;
  int b = p0 >> 14;
  for (int i = threadIdx.x; i < 16*80; i += 256) st[i] = stats[b*16*80 + i];
  __syncthreads();
  int p = p0 + threadIdx.x;
  int l = p & 16383;
  float sv[8], cv[8];
  {
    const float* sp = sin_t + l*8;
    const float* cp = cos_t + l*8;
    #pragma unroll
    for (int i=0;i<8;i++){ sv[i]=sp[i]; cv[i]=cp[i]; }
  }
  unsigned short* orow = resg_t + ((size_t)p << 7);
  #pragma unroll 1
  for (int hd=0; hd<16; hd++){
    const float* S = st + hd*80;
    const unsigned short* qb = qo + (((size_t)(b*256 + hd*8)) << 14) + l;
    const unsigned short* ob = qb + ((size_t)128 << 14);
    const unsigned short* lb = lepe + (((size_t)(b*128 + hd*8)) << 14) + l;
    float q[8];
    #pragma unroll
    for (int e=0;e<8;e++){
      float t = bf2f(qb[(size_t)e<<14]);
      q[e] = t > 0.f ? t + 1.f : __expf(t);
    }
    float z = 0.f;
    #pragma unroll
    for (int e=0;e<8;e++) z += q[e]*S[e];
    z *= ATT_SCALE;
    float qs[8];
    #pragma unroll
    for (int jj=0;jj<4;jj++){
      float x1=q[2*jj], x2=q[2*jj+1];
      qs[2*jj]   = x1*cv[2*jj]   - x2*sv[2*jj];
      qs[2*jj+1] = x2*cv[2*jj+1] + x1*sv[2*jj+1];
    }
    float fac = 1.f + 1.f/(z + 1e-6f);
    short8 vv;
    #pragma unroll
    for (int e=0;e<8;e++){
      float r = 0.f;
      #pragma unroll
      for (int d=0; d<8; d++) r += qs[d]*S[16 + d*8 + e];
      r = r*fac - z*S[8+e];
      float val = (r + bf2f(lb[(size_t)e<<14])) * bf2f(ob[(size_t)e<<14]);
      vv[e] = (short)f2bf(val);
    }
    *(short8*)(orow + hd*8) = vv;
  }
}

// ------------------- ffn dw3x3 x2 + exact gelu gate, LDS-staged; plane-major out -------------------
// p: [bb][704][L] (bb in 0..1). grid: half(2) x bb(2) x jc(340). out g: [bb][340][L]
#define FPL (66*144)
__launch_bounds__(256)
__global__ void ffn_dwg_kernel(const unsigned short* __restrict__ p,
                               const float* __restrict__ dw,
                               unsigned short* __restrict__ g){
  __shared__ unsigned short lds[2*FPL];     // 2 planes, rows 66 (h-halo), cols w+8 (0..143)
  int bid = blockIdx.x;
  int jc = bid % NHID;
  int rest = bid / NHID;
  int bb = rest & 1;
  int half = rest >> 1;
  int t = threadIdx.x;
  #pragma unroll
  for (int i = t; i < 2*FPL/8; i += 256)
    *(short8*)(lds + i*8) = (short8){0,0,0,0,0,0,0,0};
  __syncthreads();
  int band = t >> 4, wi = t & 15, w0 = wi*8;
  #pragma unroll
  for (int pl=0; pl<2; pl++){
    const unsigned short* src = p + (((size_t)(bb*704 + jc + pl*NHID)) << 14);
    #pragma unroll
    for (int it=0; it<5; it++){
      int r_idx = it*16 + band;
      if (r_idx < 66){
        int h = half*64 - 1 + r_idx;
        if ((unsigned)h < 128u){
          short8 v = *(const short8*)(src + (h<<7) + w0);
          *(short8*)(&lds[pl*FPL + r_idx*144 + w0 + 8]) = v;
        }
      }
    }
  }
  float w1[9], w2[9];
  #pragma unroll
  for (int i=0;i<9;i++){ w1[i] = dw[jc*9 + i]; w2[i] = dw[(jc+NHID)*9 + i]; }
  __syncthreads();
  int rb = band*4;
  float r1[3][10], r2[3][10];
  #pragma unroll
  for (int m=0;m<2;m++){
    load_row10(&lds[(rb+m)*144 + w0], r1[m]);
    load_row10(&lds[FPL + (rb+m)*144 + w0], r2[m]);
  }
  unsigned short* outp = g + (((size_t)(bb*NHID + jc)) << 14);
  #pragma unroll
  for (int s=0;s<4;s++){
    load_row10(&lds[(rb+2+s)*144 + w0], r1[(2+s)%3]);
    load_row10(&lds[FPL + (rb+2+s)*144 + w0], r2[(2+s)%3]);
    int h = half*64 + rb + s;
    short8 ov;
    #pragma unroll
    for (int j=0;j<8;j++){
      float c1 = 0.f, c2 = 0.f;
      #pragma unroll
      for (int dy=0;dy<3;dy++){
        const float* a = r1[(s+dy)%3];
        const float* bpt = r2[(s+dy)%3];
        #pragma unroll
        for (int dx=0;dx<3;dx++){
          c1 += w1[dy*3+dx]*a[j+dx];
          c2 += w2[dy*3+dx]*bpt[j+dx];
        }
      }
      float ge = 0.5f*c1*(1.f + erff(c1*0.70710678118654752f));
      ov[j] = (short)f2bf(ge*c2);
    }
    *(short8*)(outp + h*128 + w0) = ov;
  }
}

// ------------------- transpose g [bb][340][L] -> g_t [bb*L+l][352] (pad zero) -------------------
__global__ void transpose_g_kernel(const unsigned short* __restrict__ g,
                                   unsigned short* __restrict__ g_t){
  __shared__ unsigned short tile[64][68];
  int bid = blockIdx.x;
  int jt = bid % 6;
  int lt = (bid / 6) & 255;
  int b  = bid / (6*256);
  int j0 = jt*64, l0 = lt*64;
  int t = threadIdx.x;
  {
    int jj = t >> 3;
    int lo = (t & 7) * 8;
    #pragma unroll
    for (int rr=0; rr<2; rr++){
      int j = j0 + jj + rr*32;
      unsigned short vals[8];
      if (j < NHID){
        const unsigned short* src = g + (((size_t)(b*NHID + j)) << 14) + l0 + lo;
        short8 vv = *(const short8*)src;
        #pragma unroll
        for (int i=0;i<8;i++) vals[i] = (unsigned short)vv[i];
      } else {
        #pragma unroll
        for (int i=0;i<8;i++) vals[i] = 0;
      }
      #pragma unroll
      for (int i=0;i<8;i++) tile[lo + i][jj + rr*32] = vals[i];
    }
  }
  __syncthreads();
  {
    int r = t >> 2;
    int c0 = (t & 3)*16;
    int jg = j0 + c0;
    if (jg < 352){
      unsigned short* dst = g_t + ((size_t)(b*LSP + l0 + r))*352 + jg;
      short8 v0, v1;
      #pragma unroll
      for (int i=0;i<8;i++){ v0[i] = (short)tile[r][c0 + i]; v1[i] = (short)tile[r][c0 + 8 + i]; }
      *(short8*)dst = v0;
      *(short8*)(dst+8) = v1;
    }
  }
}

extern "C" void kernel_launch(void* const* d_in, const int* in_sizes, int n_in,
                              void* d_out, int out_size, void* d_ws, size_t ws_size,
                              hipStream_t stream){
  (void)in_sizes; (void)n_in; (void)out_size;
  if (ws_size < WS_NEEDED) return;
  const float* x        = (const float*)d_in[0];
  const float* ln1_w    = (const float*)d_in[1];
  const float* ln1_b    = (const float*)d_in[2];
  const float* qkvo_w   = (const float*)d_in[3];
  const float* qkvo_b   = (const float*)d_in[4];
  const float* lepe_w   = (const float*)d_in[5];
  const float* lepe_b   = (const float*)d_in[6];
  const float* proj_w   = (const float*)d_in[7];
  const float* proj_b   = (const float*)d_in[8];
  const float* ln2_w    = (const float*)d_in[9];
  const float* ln2_b    = (const float*)d_in[10];
  const float* ffn_in_w = (const float*)d_in[11];
  const float* ffn_dw_w = (const float*)d_in[12];
  const float* ffn_out_w= (const float*)d_in[13];

  char* ws = (char*)d_ws;
  unsigned short* bufA   = (unsigned short*)(ws + OFF_A);
  unsigned short* bufB   = (unsigned short*)(ws + OFF_B);
  unsigned short* g_t2   = (unsigned short*)(ws + OFF_GT2);
  unsigned short* lepe   = (unsigned short*)(ws + OFF_C);
  unsigned short* gbuf   = (unsigned short*)(ws + OFF_C);   // reuses lepe region in FFN phase
  float* partials        = (float*)(ws + OFF_PART);
  float* stats           = (float*)(ws + OFF_STATS);
  float* sin_t           = (float*)(ws + OFF_SIN);
  float* cos_t           = (float*)(ws + OFF_COS);
  unsigned short* wq     = (unsigned short*)(ws + OFF_WQ);
  unsigned short* wqo    = (unsigned short*)(ws + OFF_WQO);
  float* qo_bias         = (float*)(ws + OFF_QOB);
  unsigned short* wp     = (unsigned short*)(ws + OFF_WP);
  unsigned short* wfi    = (unsigned short*)(ws + OFF_WFI);
  unsigned short* wfo    = (unsigned short*)(ws + OFF_WFO);
  const unsigned short* wkv = wq + 128*128;

  float* out_f = (float*)d_out;
  dim3 blk(256);
  hipLaunchKernelGGL(rope_kernel, dim3(64), blk, 0, stream, sin_t, cos_t);
  hipLaunchKernelGGL(wconv_kernel, dim3((512*128)/256), blk, 0, stream, qkvo_w, wq, 512,128,512,128);
  hipLaunchKernelGGL(reorder_qo_kernel, dim3((256*128)/256), blk, 0, stream, qkvo_w, qkvo_b, wqo, qo_bias);
  hipLaunchKernelGGL(wconv_kernel, dim3((128*128)/256), blk, 0, stream, proj_w, wp, 128,128,128,128);
  hipLaunchKernelGGL(wconv_kernel, dim3((704*128)/256), blk, 0, stream, ffn_in_w, wfi, 680,128,704,128);
  hipLaunchKernelGGL(wconv_kernel, dim3((128*352)/256), blk, 0, stream, ffn_out_w, wfo, 128,340,128,352);

  // attention phase
  hipLaunchKernelGGL(ln_kernel, dim3(1024), blk, 0, stream, x, ln1_w, ln1_b, bufA);
  hipLaunchKernelGGL((gemm_kernel<256,128,true,false,true>), dim3(1024,4), blk, 0, stream,
                     bufA, wkv, qkvo_b + 128, (const float*)nullptr, (void*)bufB);     // kv
  hipLaunchKernelGGL(lepe_kernel, dim3(1024), blk, 0, stream, bufB, lepe_w, lepe_b, lepe);
  hipLaunchKernelGGL(attn_partial, dim3(512), blk, 0, stream, bufB, sin_t, cos_t, partials);
  hipLaunchKernelGGL(attn_combine, dim3(40), blk, 0, stream, partials, stats);
  hipLaunchKernelGGL((gemm_kernel<256,128,true,false,true>), dim3(1024,4), blk, 0, stream,
                     bufA, wqo, qo_bias, (const float*)nullptr, (void*)bufB);          // qo
  hipLaunchKernelGGL(attn_apply_kernel, dim3(512), blk, 0, stream, bufB, lepe, stats, sin_t, cos_t, bufA);
  hipLaunchKernelGGL((gemm_kernel<128,128,true,true,false>), dim3(1024,2), blk, 0, stream,
                     bufA, wp, proj_b, x, (void*)out_f);                               // x1 -> d_out fp32

  // ffn phase
  hipLaunchKernelGGL(ln_kernel, dim3(1024), blk, 0, stream, out_f, ln2_w, ln2_b, bufA);
  for (int bp = 0; bp < 4; bp++){
    const unsigned short* xin = bufA + (size_t)bp*32768*128;
    float* outp = out_f + (size_t)bp*2*128*16384;
    hipLaunchKernelGGL((gemm_kernel<704,128,false,false,true>), dim3(256,11), blk, 0, stream,
                       xin, wfi, (const float*)nullptr, (const float*)nullptr, (void*)bufB);
    hipLaunchKernelGGL(ffn_dwg_kernel, dim3(1360), blk, 0, stream, bufB, ffn_dw_w, gbuf);
    hipLaunchKernelGGL(transpose_g_kernel, dim3(3072), blk, 0, stream, gbuf, g_t2);
    hipLaunchKernelGGL((gemm_kernel<128,352,false,true,false>), dim3(256,2), blk, 0, stream,
                       g_t2, wfo, (const float*)nullptr, outp, (void*)outp);
  }
}

// Round 3
// 728.581 us; speedup vs baseline: 1.1577x; 1.1577x over previous
//
#include <hip/hip_runtime.h>

#define LSP 16384            // H*W
#define NBATCH 8
#define NPOS (NBATCH*LSP)    // 131072
#define NHID 340
#define ATT_SCALE 0.35355339059327373f

// ---- workspace layout (bytes) ----
#define OFF_A        0ULL          // 32MB: xn_t -> resg_t -> xn2_t
#define OFF_B        33554432ULL   // 64MB: kv -> qo ; FFN: pbuf2 (44MB)
#define OFF_GT2      79691776ULL   // 22MB: g_t2 (per 2-batch)
#define OFF_C        100663296ULL  // 32MB: lepe ; FFN: gbuf (22.3MB)
#define OFF_PART     134217728ULL  // 160KB
#define OFF_STATS    134381568ULL  // 40KB
#define OFF_SIN      134422528ULL  // 512KB
#define OFF_COS      134946816ULL  // 512KB
#define OFF_WQ       135471104ULL  // 512x128 bf16
#define OFF_WQO      135602176ULL  // 256x128 bf16
#define OFF_QOB      135667712ULL  // 256 f32
#define OFF_WP       135668736ULL  // 128x128 bf16
#define OFF_WFI      135701504ULL  // 704x128 bf16
#define OFF_WFO      135881728ULL  // 128x352 bf16
#define WS_NEEDED    135971840ULL

typedef __attribute__((ext_vector_type(8))) short short8;
typedef __attribute__((ext_vector_type(4))) float floatx4;

__device__ __forceinline__ float bf2f(unsigned short u){
  union { unsigned int i; float f; } c; c.i = ((unsigned int)u) << 16; return c.f;
}
__device__ __forceinline__ unsigned short f2bf(float f){
  union { float f; unsigned int i; } c; c.f = f;
  unsigned int r = c.i + 0x7fffu + ((c.i >> 16) & 1u);
  return (unsigned short)(r >> 16);
}

// read 12 bf16 (4B-aligned) from LDS -> fp32
__device__ __forceinline__ void load_row12(const unsigned short* p, float* r){
  const unsigned int* q = (const unsigned int*)p;
  #pragma unroll
  for (int i=0;i<6;i++){
    unsigned int u = q[i];
    r[2*i]   = bf2f((unsigned short)(u & 0xffffu));
    r[2*i+1] = bf2f((unsigned short)(u >> 16));
  }
}

// read 10 bf16 (1 edge + aligned 8 + 1 edge) from LDS -> fp32
__device__ __forceinline__ void load_row10(const unsigned short* base, float* r){
  short8 B = *(const short8*)(base + 8);
  r[0] = bf2f(base[7]);
  #pragma unroll
  for (int i=0;i<8;i++) r[1+i] = bf2f((unsigned short)B[i]);
  r[9] = bf2f(base[16]);
}

// ------------------- RoPE tables: sin/cos[l][8] fp32 -------------------
__global__ void rope_kernel(float* __restrict__ sin_t, float* __restrict__ cos_t){
  int l = blockIdx.x*256 + threadIdx.x;
  if (l >= LSP) return;
  int h = l >> 7, w = l & 127;
  float s0 = sinf((float)h),        c0 = cosf((float)h);
  float s1 = sinf((float)h*1e-4f),  c1 = cosf((float)h*1e-4f);
  float s2 = sinf((float)w),        c2 = cosf((float)w);
  float s3 = sinf((float)w*1e-4f),  c3 = cosf((float)w*1e-4f);
  float* sp = sin_t + l*8; float* cp = cos_t + l*8;
  sp[0]=s0; sp[1]=s0; sp[2]=s1; sp[3]=s1; sp[4]=s2; sp[5]=s2; sp[6]=s3; sp[7]=s3;
  cp[0]=c0; cp[1]=c0; cp[2]=c1; cp[3]=c1; cp[4]=c2; cp[5]=c2; cp[6]=c3; cp[7]=c3;
}

// ------------------- weight fp32 -> padded bf16 -------------------
__global__ void wconv_kernel(const float* __restrict__ src, unsigned short* __restrict__ dst,
                             int O, int K, int OP, int KP){
  int i = blockIdx.x*256 + threadIdx.x;
  if (i >= OP*KP) return;
  int o = i / KP, k = i - o*KP;
  float v = (o < O && k < K) ? src[o*K + k] : 0.f;
  dst[i] = f2bf(v);
}

// ------------------- q/o weight+bias reorder: rows [0..128)+[384..512) -------------------
__global__ void reorder_qo_kernel(const float* __restrict__ qkvo_w, const float* __restrict__ qkvo_b,
                                  unsigned short* __restrict__ wqo, float* __restrict__ qo_bias){
  int i = blockIdx.x*256 + threadIdx.x;
  if (i < 256){
    qo_bias[i] = qkvo_b[(i < 128) ? i : i + 256];
  }
  if (i >= 256*128) return;
  int o = i >> 7, k = i & 127;
  int srow = (o < 128) ? o : o + 256;
  wqo[i] = f2bf(qkvo_w[srow*128 + k]);
}

// ------------------- LayerNorm over 128 channels; out position-major bf16 -------------------
// 2 threads per position (64 channels each, FULLY unrolled so vals stay in VGPRs).
// Output staged through LDS tile -> coalesced contiguous stores (block span is 32KB linear).
__launch_bounds__(256)
__global__ void ln_kernel(const float* __restrict__ x, const float* __restrict__ gam,
                          const float* __restrict__ bet, unsigned short* __restrict__ out_t){
  __shared__ float ps[2][128], pq[2][128];
  __shared__ unsigned short tile[128*132];
  int t = threadIdx.x;
  int pidx = t & 127;
  int half = t >> 7;
  int p0 = blockIdx.x*128;
  int p = p0 + pidx;
  int b = p >> 14, l = p & 16383;
  const float* xb = x + (((size_t)b) << 21) + (((size_t)(half*64)) << 14) + l;
  float vals[64];
  float s = 0.f, sq = 0.f;
  #pragma unroll
  for (int c = 0; c < 64; c++){
    float v = xb[(size_t)c << 14];
    vals[c] = v;
    s += v; sq += v*v;
  }
  ps[half][pidx] = s; pq[half][pidx] = sq;
  __syncthreads();
  float S = ps[0][pidx] + ps[1][pidx];
  float Q = pq[0][pidx] + pq[1][pidx];
  float mu = S * 0.0078125f;
  float var = Q * 0.0078125f - mu*mu;
  float rstd = rsqrtf(var + 1e-5f);
  #pragma unroll
  for (int c0 = 0; c0 < 64; c0 += 8){
    short8 vv;
    #pragma unroll
    for (int i = 0; i < 8; i++){
      int c = c0 + i;
      int cg = half*64 + c;
      vv[i] = (short)f2bf((vals[c] - mu) * rstd * gam[cg] + bet[cg]);
    }
    *(short8*)&tile[pidx*132 + half*64 + c0] = vv;
  }
  __syncthreads();
  unsigned short* og = out_t + ((size_t)p0 << 7);
  #pragma unroll
  for (int it = 0; it < 8; it++){
    int idx = it*256 + t;
    int row = idx >> 4;
    int col = (idx & 15) * 8;
    *(short8*)&og[(row << 7) + col] = *(const short8*)&tile[row*132 + col];
  }
}

// ------------------- MFMA GEMM: out[b][o][l] = sum_k W[o][k]*in_t[b*L+l][k] -------------------
// oc chunk (64 output channels) from blockIdx.y. Epilogue staged through LDS for
// coalesced short8/float4 stores and float4 resid loads.
template<int OPAD, int KPAD, bool HASBIAS, bool RESID, bool OUTBF16>
__launch_bounds__(256)
__global__ void gemm_kernel(const unsigned short* __restrict__ in_t,
                            const unsigned short* __restrict__ wb,
                            const float* __restrict__ bias,
                            const float* __restrict__ resid,
                            void* __restrict__ outp){
  constexpr int KS = KPAD / 32;
  constexpr int SBYTES = OUTBF16 ? (64*136*2) : (64*132*4);
  __shared__ __align__(16) unsigned char smem[SBYTES];
  const int l0 = blockIdx.x * 128;
  const int b = l0 >> 14;
  const int lloc0 = l0 & 16383;
  const int t = threadIdx.x;
  const int lane = t & 63;
  const int wv = t >> 6;
  const int lane15 = lane & 15;
  const int quad = lane >> 4;
  const int oc = blockIdx.y;

  short8 fb[2][KS];
  {
    const unsigned short* base = in_t + ((size_t)(l0 + wv*32 + lane15)) * KPAD + quad*8;
    #pragma unroll
    for (int nt = 0; nt < 2; nt++){
      #pragma unroll
      for (int ks = 0; ks < KS; ks++)
        fb[nt][ks] = *(const short8*)(base + (size_t)nt*16*KPAD + ks*32);
    }
  }
  floatx4 acc[4][2];
  #pragma unroll
  for (int mt=0; mt<4; mt++)
    #pragma unroll
    for (int nt=0; nt<2; nt++)
      acc[mt][nt] = (floatx4){0.f,0.f,0.f,0.f};
  #pragma unroll
  for (int ks = 0; ks < KS; ks++){
    short8 fa[4];
    const unsigned short* wrow = wb + ((size_t)(oc*64 + lane15)) * KPAD + ks*32 + quad*8;
    #pragma unroll
    for (int mt=0; mt<4; mt++)
      fa[mt] = *(const short8*)(wrow + (size_t)mt*16*KPAD);
    #pragma unroll
    for (int mt=0; mt<4; mt++)
      #pragma unroll
      for (int nt=0; nt<2; nt++)
        acc[mt][nt] = __builtin_amdgcn_mfma_f32_16x16x32_bf16(fa[mt], fb[nt][ks], acc[mt][nt], 0, 0, 0);
  }

  if (OUTBF16){
    unsigned short* cs = (unsigned short*)smem;
    #pragma unroll
    for (int mt=0; mt<4; mt++)
      #pragma unroll
      for (int nt=0; nt<2; nt++)
        #pragma unroll
        for (int r=0; r<4; r++){
          const int o = mt*16 + quad*4 + r;
          float v = acc[mt][nt][r];
          if (HASBIAS) v += bias[oc*64 + o];
          cs[o*136 + wv*32 + nt*16 + lane15] = f2bf(v);
        }
    __syncthreads();
    unsigned short* og = (unsigned short*)outp;
    #pragma unroll
    for (int j=0; j<4; j++){
      int idx = j*256 + t;
      int row = idx >> 4;
      int col = (idx & 15) * 8;
      short8 v = *(const short8*)&cs[row*136 + col];
      *(short8*)&og[(((size_t)(b*OPAD + oc*64 + row)) << 14) + lloc0 + col] = v;
    }
  } else {
    float* cf = (float*)smem;
    #pragma unroll
    for (int mt=0; mt<4; mt++)
      #pragma unroll
      for (int nt=0; nt<2; nt++)
        #pragma unroll
        for (int r=0; r<4; r++){
          const int o = mt*16 + quad*4 + r;
          float v = acc[mt][nt][r];
          if (HASBIAS) v += bias[oc*64 + o];
          cf[o*132 + wv*32 + nt*16 + lane15] = v;
        }
    __syncthreads();
    float* og = (float*)outp;
    #pragma unroll
    for (int j=0; j<8; j++){
      int idx = j*256 + t;
      int row = idx >> 5;
      int col = (idx & 31) * 4;
      floatx4 v = *(const floatx4*)&cf[row*132 + col];
      if (RESID){
        floatx4 rv = *(const floatx4*)(resid + (((size_t)(b*128 + oc*64 + row)) << 14) + lloc0 + col);
        v += rv;
      }
      *(floatx4*)&og[(((size_t)(b*OPAD + oc*64 + row)) << 14) + lloc0 + col] = v;
    }
  }
}

// ------------------- lepe: depthwise 5x5, LDS-staged sliding window -------------------
// kv layout: [b][256][L], v at channel 128+c. One block per (b,c) plane.
__launch_bounds__(256)
__global__ void lepe_kernel(const unsigned short* __restrict__ kv,
                            const float* __restrict__ lw, const float* __restrict__ lb,
                            unsigned short* __restrict__ lepe){
  __shared__ unsigned short lds[132*136];     // rows h+2 (0..131), cols w+2 (0..131), stride 136
  int bc = blockIdx.x;                        // b*128 + c
  int b = bc >> 7, c = bc & 127;
  int t = threadIdx.x;
  #pragma unroll
  for (int i = t; i < 132*136/8; i += 256)
    *(short8*)(lds + i*8) = (short8){0,0,0,0,0,0,0,0};
  __syncthreads();
  int band = t >> 4, wi = t & 15, w0 = wi*8;
  const unsigned short* vp = kv + (((size_t)(b*256 + 128 + c)) << 14);
  {
    #pragma unroll
    for (int it = 0; it < 8; it++){
      int hh = band + it*16;
      short8 v = *(const short8*)(vp + (hh<<7) + w0);
      unsigned int* dst = (unsigned int*)&lds[(hh+2)*136 + w0 + 2];
      union { short8 s; unsigned int u[4]; } cv; cv.s = v;
      #pragma unroll
      for (int q=0;q<4;q++) dst[q] = cv.u[q];
    }
  }
  float wt[25];
  #pragma unroll
  for (int i=0;i<25;i++) wt[i] = lw[c*25 + i];
  float bias = lb[c];
  __syncthreads();
  int h0 = band*8;
  float win[5][12];
  #pragma unroll
  for (int m=0;m<4;m++) load_row12(&lds[(h0+m)*136 + w0], win[m]);
  unsigned short* outp = lepe + ((size_t)bc << 14);
  #pragma unroll
  for (int s=0;s<8;s++){
    load_row12(&lds[(h0+4+s)*136 + w0], win[(4+s)%5]);
    short8 ov;
    #pragma unroll
    for (int j=0;j<8;j++){
      float acc = bias;
      #pragma unroll
      for (int dy=0;dy<5;dy++){
        const float* r = win[(s+dy)%5];
        #pragma unroll
        for (int dx=0;dx<5;dx++) acc += wt[dy*5+dx]*r[j+dx];
      }
      ov[j] = (short)f2bf(acc);
    }
    *(short8*)(outp + (h0+s)*128 + w0) = ov;
  }
}

// ------------------- attention reduction partials per (b,head,chunk) -------------------
__launch_bounds__(256)
__global__ void attn_partial(const unsigned short* __restrict__ kv,
                             const float* __restrict__ sin_t, const float* __restrict__ cos_t,
                             float* __restrict__ partials){
  int pair = blockIdx.x >> 2;
  int chunk = blockIdx.x & 3;
  int b = pair >> 4, hd = pair & 15;
  const unsigned short* kb = kv + (((size_t)(b*256 + hd*8)) << 14);
  const unsigned short* vb = kb + ((size_t)128 << 14);
  float red[80];
  #pragma unroll
  for (int i=0;i<80;i++) red[i]=0.f;
  int l0 = chunk*4096;
  for (int li=0; li<16; li++){
    int l = l0 + li*256 + threadIdx.x;
    float k[8], v[8], ks[8];
    #pragma unroll
    for (int e=0;e<8;e++){
      float t = bf2f(kb[((size_t)e<<14)+l]);
      k[e] = t>0.f ? t+1.f : __expf(t);
      v[e] = bf2f(vb[((size_t)e<<14)+l]);
      red[e]   += k[e];
      red[8+e] += v[e];
    }
    const float* sp = sin_t + l*8;
    const float* cp = cos_t + l*8;
    #pragma unroll
    for (int j=0;j<4;j++){
      float x1=k[2*j], x2=k[2*j+1];
      ks[2*j]   = x1*cp[2*j]   - x2*sp[2*j];
      ks[2*j+1] = x2*cp[2*j+1] + x1*sp[2*j+1];
    }
    #pragma unroll
    for (int d=0; d<8; d++)
      #pragma unroll
      for (int e=0;e<8;e++)
        red[16 + d*8 + e] += ks[d]*v[e];
  }
  #pragma unroll
  for (int off=32; off>0; off>>=1){
    #pragma unroll
    for (int i=0;i<80;i++)
      red[i] += __shfl_down(red[i], off);
  }
  __shared__ float lds[4][80];
  int lane = threadIdx.x & 63, wv = threadIdx.x >> 6;
  if (lane==0){
    #pragma unroll
    for (int i=0;i<80;i++) lds[wv][i] = red[i];
  }
  __syncthreads();
  if (threadIdx.x < 80){
    float s = lds[0][threadIdx.x]+lds[1][threadIdx.x]+lds[2][threadIdx.x]+lds[3][threadIdx.x];
    partials[(size_t)blockIdx.x*80 + threadIdx.x] = s;
  }
}

__global__ void attn_combine(const float* __restrict__ partials, float* __restrict__ stats){
  int i = blockIdx.x*256 + threadIdx.x;
  if (i >= 128*80) return;
  int pair = i / 80, idx = i - pair*80;
  float s = partials[(size_t)(pair*4+0)*80+idx] + partials[(size_t)(pair*4+1)*80+idx]
          + partials[(size_t)(pair*4+2)*80+idx] + partials[(size_t)(pair*4+3)*80+idx];
  s *= (idx < 16) ? (1.f/LSP) : (ATT_SCALE/LSP);
  stats[i] = s;
}

// ------------------- attention apply + lepe add + o-gate; out position-major bf16 -------------------
// Per-head results staged in LDS tile -> coalesced 64KB linear store.
__launch_bounds__(256)
__global__ void attn_apply_kernel(const unsigned short* __restrict__ qo,
                                  const unsigned short* __restrict__ lepe,
                                  const float* __restrict__ stats,
                                  const float* __restrict__ sin_t,
                                  const float* __restrict__ cos_t,
                                  unsigned short* __restrict__ resg_t){
  __shared__ float st[16*80];
  __shared__ unsigned short tile[256*132];
  int p0 = blockIdx.x * 256;
  int b = p0 >> 14;
  for (int i = threadIdx.x; i < 16*80; i += 256) st[i] = stats[b*16*80 + i];
  __syncthreads();
  int t = threadIdx.x;
  int p = p0 + t;
  int l = p & 16383;
  float sv[8], cv[8];
  {
    const float* sp = sin_t + l*8;
    const float* cp = cos_t + l*8;
    #pragma unroll
    for (int i=0;i<8;i++){ sv[i]=sp[i]; cv[i]=cp[i]; }
  }
  #pragma unroll 1
  for (int hd=0; hd<16; hd++){
    const float* S = st + hd*80;
    const unsigned short* qb = qo + (((size_t)(b*256 + hd*8)) << 14) + l;
    const unsigned short* ob = qb + ((size_t)128 << 14);
    const unsigned short* lb = lepe + (((size_t)(b*128 + hd*8)) << 14) + l;
    float q[8];
    #pragma unroll
    for (int e=0;e<8;e++){
      float tq = bf2f(qb[(size_t)e<<14]);
      q[e] = tq > 0.f ? tq + 1.f : __expf(tq);
    }
    float z = 0.f;
    #pragma unroll
    for (int e=0;e<8;e++) z += q[e]*S[e];
    z *= ATT_SCALE;
    float qs[8];
    #pragma unroll
    for (int jj=0;jj<4;jj++){
      float x1=q[2*jj], x2=q[2*jj+1];
      qs[2*jj]   = x1*cv[2*jj]   - x2*sv[2*jj];
      qs[2*jj+1] = x2*cv[2*jj+1] + x1*sv[2*jj+1];
    }
    float fac = 1.f + 1.f/(z + 1e-6f);
    short8 vv;
    #pragma unroll
    for (int e=0;e<8;e++){
      float r = 0.f;
      #pragma unroll
      for (int d=0; d<8; d++) r += qs[d]*S[16 + d*8 + e];
      r = r*fac - z*S[8+e];
      float val = (r + bf2f(lb[(size_t)e<<14])) * bf2f(ob[(size_t)e<<14]);
      vv[e] = (short)f2bf(val);
    }
    *(short8*)&tile[t*132 + hd*8] = vv;
  }
  __syncthreads();
  unsigned short* og = resg_t + ((size_t)p0 << 7);
  #pragma unroll
  for (int it = 0; it < 16; it++){
    int idx = it*256 + t;
    int row = idx >> 4;
    int col = (idx & 15) * 8;
    *(short8*)&og[(row << 7) + col] = *(const short8*)&tile[row*132 + col];
  }
}

// ------------------- ffn dw3x3 x2 + exact gelu gate, LDS-staged; plane-major out -------------------
// p: [bb][704][L] (bb in 0..1). grid: half(2) x bb(2) x jc(340). out g: [bb][340][L]
#define FPL (66*144)
__launch_bounds__(256)
__global__ void ffn_dwg_kernel(const unsigned short* __restrict__ p,
                               const float* __restrict__ dw,
                               unsigned short* __restrict__ g){
  __shared__ unsigned short lds[2*FPL];     // 2 planes, rows 66 (h-halo), cols w+8 (0..143)
  int bid = blockIdx.x;
  int jc = bid % NHID;
  int rest = bid / NHID;
  int bb = rest & 1;
  int half = rest >> 1;
  int t = threadIdx.x;
  #pragma unroll
  for (int i = t; i < 2*FPL/8; i += 256)
    *(short8*)(lds + i*8) = (short8){0,0,0,0,0,0,0,0};
  __syncthreads();
  int band = t >> 4, wi = t & 15, w0 = wi*8;
  #pragma unroll
  for (int pl=0; pl<2; pl++){
    const unsigned short* src = p + (((size_t)(bb*704 + jc + pl*NHID)) << 14);
    #pragma unroll
    for (int it=0; it<5; it++){
      int r_idx = it*16 + band;
      if (r_idx < 66){
        int h = half*64 - 1 + r_idx;
        if ((unsigned)h < 128u){
          short8 v = *(const short8*)(src + (h<<7) + w0);
          *(short8*)(&lds[pl*FPL + r_idx*144 + w0 + 8]) = v;
        }
      }
    }
  }
  float w1[9], w2[9];
  #pragma unroll
  for (int i=0;i<9;i++){ w1[i] = dw[jc*9 + i]; w2[i] = dw[(jc+NHID)*9 + i]; }
  __syncthreads();
  int rb = band*4;
  float r1[3][10], r2[3][10];
  #pragma unroll
  for (int m=0;m<2;m++){
    load_row10(&lds[(rb+m)*144 + w0], r1[m]);
    load_row10(&lds[FPL + (rb+m)*144 + w0], r2[m]);
  }
  unsigned short* outp = g + (((size_t)(bb*NHID + jc)) << 14);
  #pragma unroll
  for (int s=0;s<4;s++){
    load_row10(&lds[(rb+2+s)*144 + w0], r1[(2+s)%3]);
    load_row10(&lds[FPL + (rb+2+s)*144 + w0], r2[(2+s)%3]);
    int h = half*64 + rb + s;
    short8 ov;
    #pragma unroll
    for (int j=0;j<8;j++){
      float c1 = 0.f, c2 = 0.f;
      #pragma unroll
      for (int dy=0;dy<3;dy++){
        const float* a = r1[(s+dy)%3];
        const float* bpt = r2[(s+dy)%3];
        #pragma unroll
        for (int dx=0;dx<3;dx++){
          c1 += w1[dy*3+dx]*a[j+dx];
          c2 += w2[dy*3+dx]*bpt[j+dx];
        }
      }
      float ge = 0.5f*c1*(1.f + erff(c1*0.70710678118654752f));
      ov[j] = (short)f2bf(ge*c2);
    }
    *(short8*)(outp + h*128 + w0) = ov;
  }
}

// ------------------- transpose g [bb][340][L] -> g_t [bb*L+l][352] (pad zero) -------------------
__global__ void transpose_g_kernel(const unsigned short* __restrict__ g,
                                   unsigned short* __restrict__ g_t){
  __shared__ unsigned short tile[64][68];
  int bid = blockIdx.x;
  int jt = bid % 6;
  int lt = (bid / 6) & 255;
  int b  = bid / (6*256);
  int j0 = jt*64, l0 = lt*64;
  int t = threadIdx.x;
  {
    int jj = t >> 3;
    int lo = (t & 7) * 8;
    #pragma unroll
    for (int rr=0; rr<2; rr++){
      int j = j0 + jj + rr*32;
      unsigned short vals[8];
      if (j < NHID){
        const unsigned short* src = g + (((size_t)(b*NHID + j)) << 14) + l0 + lo;
        short8 vv = *(const short8*)src;
        #pragma unroll
        for (int i=0;i<8;i++) vals[i] = (unsigned short)vv[i];
      } else {
        #pragma unroll
        for (int i=0;i<8;i++) vals[i] = 0;
      }
      #pragma unroll
      for (int i=0;i<8;i++) tile[lo + i][jj + rr*32] = vals[i];
    }
  }
  __syncthreads();
  {
    int r = t >> 2;
    int c0 = (t & 3)*16;
    int jg = j0 + c0;
    if (jg < 352){
      unsigned short* dst = g_t + ((size_t)(b*LSP + l0 + r))*352 + jg;
      short8 v0, v1;
      #pragma unroll
      for (int i=0;i<8;i++){ v0[i] = (short)tile[r][c0 + i]; v1[i] = (short)tile[r][c0 + 8 + i]; }
      *(short8*)dst = v0;
      *(short8*)(dst+8) = v1;
    }
  }
}

extern "C" void kernel_launch(void* const* d_in, const int* in_sizes, int n_in,
                              void* d_out, int out_size, void* d_ws, size_t ws_size,
                              hipStream_t stream){
  (void)in_sizes; (void)n_in; (void)out_size;
  if (ws_size < WS_NEEDED) return;
  const float* x        = (const float*)d_in[0];
  const float* ln1_w    = (const float*)d_in[1];
  const float* ln1_b    = (const float*)d_in[2];
  const float* qkvo_w   = (const float*)d_in[3];
  const float* qkvo_b   = (const float*)d_in[4];
  const float* lepe_w   = (const float*)d_in[5];
  const float* lepe_b   = (const float*)d_in[6];
  const float* proj_w   = (const float*)d_in[7];
  const float* proj_b   = (const float*)d_in[8];
  const float* ln2_w    = (const float*)d_in[9];
  const float* ln2_b    = (const float*)d_in[10];
  const float* ffn_in_w = (const float*)d_in[11];
  const float* ffn_dw_w = (const float*)d_in[12];
  const float* ffn_out_w= (const float*)d_in[13];

  char* ws = (char*)d_ws;
  unsigned short* bufA   = (unsigned short*)(ws + OFF_A);
  unsigned short* bufB   = (unsigned short*)(ws + OFF_B);
  unsigned short* g_t2   = (unsigned short*)(ws + OFF_GT2);
  unsigned short* lepe   = (unsigned short*)(ws + OFF_C);
  unsigned short* gbuf   = (unsigned short*)(ws + OFF_C);   // reuses lepe region in FFN phase
  float* partials        = (float*)(ws + OFF_PART);
  float* stats           = (float*)(ws + OFF_STATS);
  float* sin_t           = (float*)(ws + OFF_SIN);
  float* cos_t           = (float*)(ws + OFF_COS);
  unsigned short* wq     = (unsigned short*)(ws + OFF_WQ);
  unsigned short* wqo    = (unsigned short*)(ws + OFF_WQO);
  float* qo_bias         = (float*)(ws + OFF_QOB);
  unsigned short* wp     = (unsigned short*)(ws + OFF_WP);
  unsigned short* wfi    = (unsigned short*)(ws + OFF_WFI);
  unsigned short* wfo    = (unsigned short*)(ws + OFF_WFO);
  const unsigned short* wkv = wq + 128*128;

  float* out_f = (float*)d_out;
  dim3 blk(256);
  hipLaunchKernelGGL(rope_kernel, dim3(64), blk, 0, stream, sin_t, cos_t);
  hipLaunchKernelGGL(wconv_kernel, dim3((512*128)/256), blk, 0, stream, qkvo_w, wq, 512,128,512,128);
  hipLaunchKernelGGL(reorder_qo_kernel, dim3((256*128)/256), blk, 0, stream, qkvo_w, qkvo_b, wqo, qo_bias);
  hipLaunchKernelGGL(wconv_kernel, dim3((128*128)/256), blk, 0, stream, proj_w, wp, 128,128,128,128);
  hipLaunchKernelGGL(wconv_kernel, dim3((704*128)/256), blk, 0, stream, ffn_in_w, wfi, 680,128,704,128);
  hipLaunchKernelGGL(wconv_kernel, dim3((128*352)/256), blk, 0, stream, ffn_out_w, wfo, 128,340,128,352);

  // attention phase
  hipLaunchKernelGGL(ln_kernel, dim3(1024), blk, 0, stream, x, ln1_w, ln1_b, bufA);
  hipLaunchKernelGGL((gemm_kernel<256,128,true,false,true>), dim3(1024,4), blk, 0, stream,
                     bufA, wkv, qkvo_b + 128, (const float*)nullptr, (void*)bufB);     // kv
  hipLaunchKernelGGL(lepe_kernel, dim3(1024), blk, 0, stream, bufB, lepe_w, lepe_b, lepe);
  hipLaunchKernelGGL(attn_partial, dim3(512), blk, 0, stream, bufB, sin_t, cos_t, partials);
  hipLaunchKernelGGL(attn_combine, dim3(40), blk, 0, stream, partials, stats);
  hipLaunchKernelGGL((gemm_kernel<256,128,true,false,true>), dim3(1024,4), blk, 0, stream,
                     bufA, wqo, qo_bias, (const float*)nullptr, (void*)bufB);          // qo
  hipLaunchKernelGGL(attn_apply_kernel, dim3(512), blk, 0, stream, bufB, lepe, stats, sin_t, cos_t, bufA);
  hipLaunchKernelGGL((gemm_kernel<128,128,true,true,false>), dim3(1024,2), blk, 0, stream,
                     bufA, wp, proj_b, x, (void*)out_f);                               // x1 -> d_out fp32

  // ffn phase
  hipLaunchKernelGGL(ln_kernel, dim3(1024), blk, 0, stream, out_f, ln2_w, ln2_b, bufA);
  for (int bp = 0; bp < 4; bp++){
    const unsigned short* xin = bufA + (size_t)bp*32768*128;
    float* outp = out_f + (size_t)bp*2*128*16384;
    hipLaunchKernelGGL((gemm_kernel<704,128,false,false,true>), dim3(256,11), blk, 0, stream,
                       xin, wfi, (const float*)nullptr, (const float*)nullptr, (void*)bufB);
    hipLaunchKernelGGL(ffn_dwg_kernel, dim3(1360), blk, 0, stream, bufB, ffn_dw_w, gbuf);
    hipLaunchKernelGGL(transpose_g_kernel, dim3(3072), blk, 0, stream, gbuf, g_t2);
    hipLaunchKernelGGL((gemm_kernel<128,352,false,true,false>), dim3(256,2), blk, 0, stream,
                       g_t2, wfo, (const float*)nullptr, outp, (void*)outp);
  }
}

// Round 5
// 725.618 us; speedup vs baseline: 1.1624x; 1.0041x over previous
//
#include <hip/hip_runtime.h>

#define LSP 16384            // H*W
#define NBATCH 8
#define NPOS (NBATCH*LSP)    // 131072
#define NHID 340
#define ATT_SCALE 0.35355339059327373f

// ---- workspace layout (bytes) ----
#define OFF_A        0ULL          // 32MB: xn_t -> resg_t -> xn2_t
#define OFF_B        33554432ULL   // 64MB: kv -> qo ; FFN: pbuf2 (44MB)
#define OFF_GT2      79691776ULL   // 22MB: attn partials (327KB) ; rest free
#define OFF_C        100663296ULL  // 32MB: lepe ; FFN: gbuf (22.3MB)
#define OFF_PART     134217728ULL  // 160KB (unused now)
#define OFF_STATS    134381568ULL  // 40KB
#define OFF_SIN      134422528ULL  // 512KB
#define OFF_COS      134946816ULL  // 512KB
#define OFF_WQ       135471104ULL  // 512x128 bf16
#define OFF_WQO      135602176ULL  // 256x128 bf16
#define OFF_QOB      135667712ULL  // 256 f32
#define OFF_WP       135668736ULL  // 128x128 bf16
#define OFF_WFI      135701504ULL  // 704x128 bf16
#define OFF_WFO      135881728ULL  // 128x352 bf16
#define WS_NEEDED    135971840ULL

typedef __attribute__((ext_vector_type(8))) short short8;
typedef __attribute__((ext_vector_type(4))) float floatx4;

__device__ __forceinline__ float bf2f(unsigned short u){
  union { unsigned int i; float f; } c; c.i = ((unsigned int)u) << 16; return c.f;
}
__device__ __forceinline__ unsigned short f2bf(float f){
  union { float f; unsigned int i; } c; c.f = f;
  unsigned int r = c.i + 0x7fffu + ((c.i >> 16) & 1u);
  return (unsigned short)(r >> 16);
}

// read 12 bf16 (4B-aligned) from LDS -> fp32
__device__ __forceinline__ void load_row12(const unsigned short* p, float* r){
  const unsigned int* q = (const unsigned int*)p;
  #pragma unroll
  for (int i=0;i<6;i++){
    unsigned int u = q[i];
    r[2*i]   = bf2f((unsigned short)(u & 0xffffu));
    r[2*i+1] = bf2f((unsigned short)(u >> 16));
  }
}

// read 10 bf16 (1 edge + aligned 8 + 1 edge) from LDS -> fp32
__device__ __forceinline__ void load_row10(const unsigned short* base, float* r){
  short8 B = *(const short8*)(base + 8);
  r[0] = bf2f(base[7]);
  #pragma unroll
  for (int i=0;i<8;i++) r[1+i] = bf2f((unsigned short)B[i]);
  r[9] = bf2f(base[16]);
}

// ------------------- RoPE tables: sin/cos[l][8] fp32 -------------------
__global__ void rope_kernel(float* __restrict__ sin_t, float* __restrict__ cos_t){
  int l = blockIdx.x*256 + threadIdx.x;
  if (l >= LSP) return;
  int h = l >> 7, w = l & 127;
  float s0 = sinf((float)h),        c0 = cosf((float)h);
  float s1 = sinf((float)h*1e-4f),  c1 = cosf((float)h*1e-4f);
  float s2 = sinf((float)w),        c2 = cosf((float)w);
  float s3 = sinf((float)w*1e-4f),  c3 = cosf((float)w*1e-4f);
  float* sp = sin_t + l*8; float* cp = cos_t + l*8;
  sp[0]=s0; sp[1]=s0; sp[2]=s1; sp[3]=s1; sp[4]=s2; sp[5]=s2; sp[6]=s3; sp[7]=s3;
  cp[0]=c0; cp[1]=c0; cp[2]=c1; cp[3]=c1; cp[4]=c2; cp[5]=c2; cp[6]=c3; cp[7]=c3;
}

// ------------------- weight fp32 -> padded bf16 -------------------
__global__ void wconv_kernel(const float* __restrict__ src, unsigned short* __restrict__ dst,
                             int O, int K, int OP, int KP){
  int i = blockIdx.x*256 + threadIdx.x;
  if (i >= OP*KP) return;
  int o = i / KP, k = i - o*KP;
  float v = (o < O && k < K) ? src[o*K + k] : 0.f;
  dst[i] = f2bf(v);
}

// ------------------- q/o weight+bias reorder: rows [0..128)+[384..512) -------------------
__global__ void reorder_qo_kernel(const float* __restrict__ qkvo_w, const float* __restrict__ qkvo_b,
                                  unsigned short* __restrict__ wqo, float* __restrict__ qo_bias){
  int i = blockIdx.x*256 + threadIdx.x;
  if (i < 256){
    qo_bias[i] = qkvo_b[(i < 128) ? i : i + 256];
  }
  if (i >= 256*128) return;
  int o = i >> 7, k = i & 127;
  int srow = (o < 128) ? o : o + 256;
  wqo[i] = f2bf(qkvo_w[srow*128 + k]);
}

// ------------------- LayerNorm over 128 channels; out position-major bf16 -------------------
__launch_bounds__(256)
__global__ void ln_kernel(const float* __restrict__ x, const float* __restrict__ gam,
                          const float* __restrict__ bet, unsigned short* __restrict__ out_t){
  __shared__ float ps[2][128], pq[2][128];
  __shared__ unsigned short tile[128*132];
  int t = threadIdx.x;
  int pidx = t & 127;
  int half = t >> 7;
  int p0 = blockIdx.x*128;
  int p = p0 + pidx;
  int b = p >> 14, l = p & 16383;
  const float* xb = x + (((size_t)b) << 21) + (((size_t)(half*64)) << 14) + l;
  float vals[64];
  float s = 0.f, sq = 0.f;
  #pragma unroll
  for (int c = 0; c < 64; c++){
    float v = xb[(size_t)c << 14];
    vals[c] = v;
    s += v; sq += v*v;
  }
  ps[half][pidx] = s; pq[half][pidx] = sq;
  __syncthreads();
  float S = ps[0][pidx] + ps[1][pidx];
  float Q = pq[0][pidx] + pq[1][pidx];
  float mu = S * 0.0078125f;
  float var = Q * 0.0078125f - mu*mu;
  float rstd = rsqrtf(var + 1e-5f);
  #pragma unroll
  for (int c0 = 0; c0 < 64; c0 += 8){
    short8 vv;
    #pragma unroll
    for (int i = 0; i < 8; i++){
      int c = c0 + i;
      int cg = half*64 + c;
      vv[i] = (short)f2bf((vals[c] - mu) * rstd * gam[cg] + bet[cg]);
    }
    *(short8*)&tile[pidx*132 + half*64 + c0] = vv;
  }
  __syncthreads();
  unsigned short* og = out_t + ((size_t)p0 << 7);
  #pragma unroll
  for (int it = 0; it < 8; it++){
    int idx = it*256 + t;
    int row = idx >> 4;
    int col = (idx & 15) * 8;
    *(short8*)&og[(row << 7) + col] = *(const short8*)&tile[row*132 + col];
  }
}

// ------------------- MFMA GEMM: out[b][o][l] = sum_k W[o][k]*in_t[b*L+l][k] -------------------
template<int OPAD, int KPAD, bool HASBIAS, bool RESID, bool OUTBF16>
__launch_bounds__(256)
__global__ void gemm_kernel(const unsigned short* __restrict__ in_t,
                            const unsigned short* __restrict__ wb,
                            const float* __restrict__ bias,
                            const float* __restrict__ resid,
                            void* __restrict__ outp){
  constexpr int KS = KPAD / 32;
  constexpr int SBYTES = OUTBF16 ? (64*136*2) : (64*132*4);
  __shared__ __align__(16) unsigned char smem[SBYTES];
  const int l0 = blockIdx.x * 128;
  const int b = l0 >> 14;
  const int lloc0 = l0 & 16383;
  const int t = threadIdx.x;
  const int lane = t & 63;
  const int wv = t >> 6;
  const int lane15 = lane & 15;
  const int quad = lane >> 4;
  const int oc = blockIdx.y;

  short8 fb[2][KS];
  {
    const unsigned short* base = in_t + ((size_t)(l0 + wv*32 + lane15)) * KPAD + quad*8;
    #pragma unroll
    for (int nt = 0; nt < 2; nt++){
      #pragma unroll
      for (int ks = 0; ks < KS; ks++)
        fb[nt][ks] = *(const short8*)(base + (size_t)nt*16*KPAD + ks*32);
    }
  }
  floatx4 acc[4][2];
  #pragma unroll
  for (int mt=0; mt<4; mt++)
    #pragma unroll
    for (int nt=0; nt<2; nt++)
      acc[mt][nt] = (floatx4){0.f,0.f,0.f,0.f};
  #pragma unroll
  for (int ks = 0; ks < KS; ks++){
    short8 fa[4];
    const unsigned short* wrow = wb + ((size_t)(oc*64 + lane15)) * KPAD + ks*32 + quad*8;
    #pragma unroll
    for (int mt=0; mt<4; mt++)
      fa[mt] = *(const short8*)(wrow + (size_t)mt*16*KPAD);
    #pragma unroll
    for (int mt=0; mt<4; mt++)
      #pragma unroll
      for (int nt=0; nt<2; nt++)
        acc[mt][nt] = __builtin_amdgcn_mfma_f32_16x16x32_bf16(fa[mt], fb[nt][ks], acc[mt][nt], 0, 0, 0);
  }

  if (OUTBF16){
    unsigned short* cs = (unsigned short*)smem;
    #pragma unroll
    for (int mt=0; mt<4; mt++)
      #pragma unroll
      for (int nt=0; nt<2; nt++)
        #pragma unroll
        for (int r=0; r<4; r++){
          const int o = mt*16 + quad*4 + r;
          float v = acc[mt][nt][r];
          if (HASBIAS) v += bias[oc*64 + o];
          cs[o*136 + wv*32 + nt*16 + lane15] = f2bf(v);
        }
    __syncthreads();
    unsigned short* og = (unsigned short*)outp;
    #pragma unroll
    for (int j=0; j<4; j++){
      int idx = j*256 + t;
      int row = idx >> 4;
      int col = (idx & 15) * 8;
      short8 v = *(const short8*)&cs[row*136 + col];
      *(short8*)&og[(((size_t)(b*OPAD + oc*64 + row)) << 14) + lloc0 + col] = v;
    }
  } else {
    float* cf = (float*)smem;
    #pragma unroll
    for (int mt=0; mt<4; mt++)
      #pragma unroll
      for (int nt=0; nt<2; nt++)
        #pragma unroll
        for (int r=0; r<4; r++){
          const int o = mt*16 + quad*4 + r;
          float v = acc[mt][nt][r];
          if (HASBIAS) v += bias[oc*64 + o];
          cf[o*132 + wv*32 + nt*16 + lane15] = v;
        }
    __syncthreads();
    float* og = (float*)outp;
    #pragma unroll
    for (int j=0; j<8; j++){
      int idx = j*256 + t;
      int row = idx >> 5;
      int col = (idx & 31) * 4;
      floatx4 v = *(const floatx4*)&cf[row*132 + col];
      if (RESID){
        floatx4 rv = *(const floatx4*)(resid + (((size_t)(b*128 + oc*64 + row)) << 14) + lloc0 + col);
        v += rv;
      }
      *(floatx4*)&og[(((size_t)(b*OPAD + oc*64 + row)) << 14) + lloc0 + col] = v;
    }
  }
}

// ------------------- FFN-out GEMM with fused transpose of g -------------------
// g: [bb][340][16384] plane-major bf16. out[b][o][l] = resid + sum_j W[o][j]*g[j][l].
// Per K-slice of 32 j: stage [128 l][32 j] into LDS (stride 40 shorts, 16B-aligned
// rows for b128 fragment reads), double-buffered.
__launch_bounds__(256)
__global__ void ffn_out_gemm(const unsigned short* __restrict__ g,
                             const unsigned short* __restrict__ wb,
                             float* __restrict__ outp){
  __shared__ __align__(16) unsigned char smem[64*132*4];   // union: 2x 10240B stage | cf
  const int t = threadIdx.x;
  const int l0 = blockIdx.x * 128;
  const int b = l0 >> 14;
  const int lloc0 = l0 & 16383;
  const int lane = t & 63;
  const int wv = t >> 6;
  const int lane15 = lane & 15;
  const int quad = lane >> 4;
  const int oc = blockIdx.y;
  const int jj = t >> 3;      // 0..31 : j within slice
  const int c8 = t & 7;       // chunk base

  auto stage = [&](int s, int bufi){
    unsigned short* buf = (unsigned short*)(smem + bufi*10240);
    int j = s*32 + jj;
    const unsigned short* src = g + (((size_t)(b*NHID + j)) << 14) + lloc0;
    #pragma unroll
    for (int cc=0; cc<2; cc++){
      int c = c8 + cc*8;
      short8 v = (short8){0,0,0,0,0,0,0,0};
      if (j < NHID) v = *(const short8*)(src + c*8);
      #pragma unroll
      for (int e=0; e<8; e++)
        buf[(c*8+e)*40 + jj] = (unsigned short)v[e];
    }
  };

  floatx4 acc[4][2];
  #pragma unroll
  for (int mt=0; mt<4; mt++)
    #pragma unroll
    for (int nt=0; nt<2; nt++)
      acc[mt][nt] = (floatx4){0.f,0.f,0.f,0.f};

  stage(0, 0);
  #pragma unroll 1
  for (int s=0; s<11; s++){
    __syncthreads();
    if (s < 10) stage(s+1, (s+1)&1);
    const unsigned short* cur = (const unsigned short*)(smem + (s&1)*10240);
    short8 fbv[2];
    #pragma unroll
    for (int nt=0; nt<2; nt++)
      fbv[nt] = *(const short8*)&cur[(wv*32 + nt*16 + lane15)*40 + quad*8];
    const unsigned short* wrow = wb + ((size_t)(oc*64 + lane15))*352 + s*32 + quad*8;
    short8 fa[4];
    #pragma unroll
    for (int mt=0; mt<4; mt++)
      fa[mt] = *(const short8*)(wrow + (size_t)mt*16*352);
    #pragma unroll
    for (int mt=0; mt<4; mt++)
      #pragma unroll
      for (int nt=0; nt<2; nt++)
        acc[mt][nt] = __builtin_amdgcn_mfma_f32_16x16x32_bf16(fa[mt], fbv[nt], acc[mt][nt], 0, 0, 0);
  }
  __syncthreads();
  float* cf = (float*)smem;
  #pragma unroll
  for (int mt=0; mt<4; mt++)
    #pragma unroll
    for (int nt=0; nt<2; nt++)
      #pragma unroll
      for (int r=0; r<4; r++){
        const int o = mt*16 + quad*4 + r;
        cf[o*132 + wv*32 + nt*16 + lane15] = acc[mt][nt][r];
      }
  __syncthreads();
  #pragma unroll
  for (int j=0; j<8; j++){
    int idx = j*256 + t;
    int row = idx >> 5;
    int col = (idx & 31) * 4;
    floatx4 v = *(const floatx4*)&cf[row*132 + col];
    size_t oi = (((size_t)(b*128 + oc*64 + row)) << 14) + lloc0 + col;
    floatx4 rv = *(const floatx4*)&outp[oi];
    v += rv;
    *(floatx4*)&outp[oi] = v;
  }
}

// ------------------- lepe: depthwise 5x5, LDS-staged sliding window -------------------
__launch_bounds__(256)
__global__ void lepe_kernel(const unsigned short* __restrict__ kv,
                            const float* __restrict__ lw, const float* __restrict__ lb,
                            unsigned short* __restrict__ lepe){
  __shared__ unsigned short lds[132*136];     // rows h+2 (0..131), cols w+2 (0..131), stride 136
  int bc = blockIdx.x;                        // b*128 + c
  int b = bc >> 7, c = bc & 127;
  int t = threadIdx.x;
  #pragma unroll
  for (int i = t; i < 132*136/8; i += 256)
    *(short8*)(lds + i*8) = (short8){0,0,0,0,0,0,0,0};
  __syncthreads();
  int band = t >> 4, wi = t & 15, w0 = wi*8;
  const unsigned short* vp = kv + (((size_t)(b*256 + 128 + c)) << 14);
  {
    #pragma unroll
    for (int it = 0; it < 8; it++){
      int hh = band + it*16;
      short8 v = *(const short8*)(vp + (hh<<7) + w0);
      unsigned int* dst = (unsigned int*)&lds[(hh+2)*136 + w0 + 2];
      union { short8 s; unsigned int u[4]; } cv; cv.s = v;
      #pragma unroll
      for (int q=0;q<4;q++) dst[q] = cv.u[q];
    }
  }
  float wt[25];
  #pragma unroll
  for (int i=0;i<25;i++) wt[i] = lw[c*25 + i];
  float bias = lb[c];
  __syncthreads();
  int h0 = band*8;
  float win[5][12];
  #pragma unroll
  for (int m=0;m<4;m++) load_row12(&lds[(h0+m)*136 + w0], win[m]);
  unsigned short* outp = lepe + ((size_t)bc << 14);
  #pragma unroll
  for (int s=0;s<8;s++){
    load_row12(&lds[(h0+4+s)*136 + w0], win[(4+s)%5]);
    short8 ov;
    #pragma unroll
    for (int j=0;j<8;j++){
      float acc = bias;
      #pragma unroll
      for (int dy=0;dy<5;dy++){
        const float* r = win[(s+dy)%5];
        #pragma unroll
        for (int dx=0;dx<5;dx++) acc += wt[dy*5+dx]*r[j+dx];
      }
      ov[j] = (short)f2bf(acc);
    }
    *(short8*)(outp + (h0+s)*128 + w0) = ov;
  }
}

// ------------------- attention reduction partials per (b,head,chunk of 2048) -------------------
__launch_bounds__(256)
__global__ void attn_partial(const unsigned short* __restrict__ kv,
                             const float* __restrict__ sin_t, const float* __restrict__ cos_t,
                             float* __restrict__ partials){
  int pair = blockIdx.x >> 3;
  int chunk = blockIdx.x & 7;
  int b = pair >> 4, hd = pair & 15;
  const unsigned short* kb = kv + (((size_t)(b*256 + hd*8)) << 14);
  const unsigned short* vb = kb + ((size_t)128 << 14);
  float red[80];
  #pragma unroll
  for (int i=0;i<80;i++) red[i]=0.f;
  int l0 = chunk*2048;
  for (int li=0; li<8; li++){
    int l = l0 + li*256 + threadIdx.x;
    float k[8], v[8], ks[8];
    #pragma unroll
    for (int e=0;e<8;e++){
      float t = bf2f(kb[((size_t)e<<14)+l]);
      k[e] = t>0.f ? t+1.f : __expf(t);
      v[e] = bf2f(vb[((size_t)e<<14)+l]);
      red[e]   += k[e];
      red[8+e] += v[e];
    }
    const float* sp = sin_t + l*8;
    const float* cp = cos_t + l*8;
    #pragma unroll
    for (int j=0;j<4;j++){
      float x1=k[2*j], x2=k[2*j+1];
      ks[2*j]   = x1*cp[2*j]   - x2*sp[2*j];
      ks[2*j+1] = x2*cp[2*j+1] + x1*sp[2*j+1];
    }
    #pragma unroll
    for (int d=0; d<8; d++)
      #pragma unroll
      for (int e=0;e<8;e++)
        red[16 + d*8 + e] += ks[d]*v[e];
  }
  #pragma unroll
  for (int off=32; off>0; off>>=1){
    #pragma unroll
    for (int i=0;i<80;i++)
      red[i] += __shfl_down(red[i], off);
  }
  __shared__ float lds[4][80];
  int lane = threadIdx.x & 63, wv = threadIdx.x >> 6;
  if (lane==0){
    #pragma unroll
    for (int i=0;i<80;i++) lds[wv][i] = red[i];
  }
  __syncthreads();
  if (threadIdx.x < 80){
    float s = lds[0][threadIdx.x]+lds[1][threadIdx.x]+lds[2][threadIdx.x]+lds[3][threadIdx.x];
    partials[(size_t)blockIdx.x*80 + threadIdx.x] = s;
  }
}

__global__ void attn_combine(const float* __restrict__ partials, float* __restrict__ stats){
  int i = blockIdx.x*256 + threadIdx.x;
  if (i >= 128*80) return;
  int pair = i / 80, idx = i - pair*80;
  float s = 0.f;
  #pragma unroll
  for (int cc=0; cc<8; cc++)
    s += partials[(size_t)(pair*8+cc)*80+idx];
  s *= (idx < 16) ? (1.f/LSP) : (ATT_SCALE/LSP);
  stats[i] = s;
}

// ------------------- attention apply + lepe add + o-gate; out position-major bf16 -------------------
// blockIdx.y selects 8-head half; per-block LDS tile -> coalesced half-row stores.
__launch_bounds__(256)
__global__ void attn_apply_kernel(const unsigned short* __restrict__ qo,
                                  const unsigned short* __restrict__ lepe,
                                  const float* __restrict__ stats,
                                  const float* __restrict__ sin_t,
                                  const float* __restrict__ cos_t,
                                  unsigned short* __restrict__ resg_t){
  __shared__ float st[8*80];
  __shared__ unsigned short tile[256*66];
  int p0 = blockIdx.x * 256;
  int b = p0 >> 14;
  int hg = blockIdx.y;
  for (int i = threadIdx.x; i < 8*80; i += 256) st[i] = stats[b*16*80 + hg*8*80 + i];
  __syncthreads();
  int t = threadIdx.x;
  int p = p0 + t;
  int l = p & 16383;
  float sv[8], cv[8];
  {
    const float* sp = sin_t + l*8;
    const float* cp = cos_t + l*8;
    #pragma unroll
    for (int i=0;i<8;i++){ sv[i]=sp[i]; cv[i]=cp[i]; }
  }
  #pragma unroll 1
  for (int hd8=0; hd8<8; hd8++){
    int hd = hg*8 + hd8;
    const float* S = st + hd8*80;
    const unsigned short* qb = qo + (((size_t)(b*256 + hd*8)) << 14) + l;
    const unsigned short* ob = qb + ((size_t)128 << 14);
    const unsigned short* lb = lepe + (((size_t)(b*128 + hd*8)) << 14) + l;
    float q[8];
    #pragma unroll
    for (int e=0;e<8;e++){
      float tq = bf2f(qb[(size_t)e<<14]);
      q[e] = tq > 0.f ? tq + 1.f : __expf(tq);
    }
    float z = 0.f;
    #pragma unroll
    for (int e=0;e<8;e++) z += q[e]*S[e];
    z *= ATT_SCALE;
    float qs[8];
    #pragma unroll
    for (int jj=0;jj<4;jj++){
      float x1=q[2*jj], x2=q[2*jj+1];
      qs[2*jj]   = x1*cv[2*jj]   - x2*sv[2*jj];
      qs[2*jj+1] = x2*cv[2*jj+1] + x1*sv[2*jj+1];
    }
    float fac = 1.f + 1.f/(z + 1e-6f);
    short8 vv;
    #pragma unroll
    for (int e=0;e<8;e++){
      float r = 0.f;
      #pragma unroll
      for (int d=0; d<8; d++) r += qs[d]*S[16 + d*8 + e];
      r = r*fac - z*S[8+e];
      float val = (r + bf2f(lb[(size_t)e<<14])) * bf2f(ob[(size_t)e<<14]);
      vv[e] = (short)f2bf(val);
    }
    *(short8*)&tile[t*66 + hd8*8] = vv;
  }
  __syncthreads();
  unsigned short* og = resg_t + ((size_t)p0 << 7) + hg*64;
  #pragma unroll
  for (int it = 0; it < 8; it++){
    int idx = it*256 + t;
    int row = idx >> 3;
    int col = (idx & 7) * 8;
    *(short8*)&og[(row << 7) + col] = *(const short8*)&tile[row*66 + col];
  }
}

// ------------------- ffn dw3x3 x2 + exact gelu gate, LDS-staged; plane-major out -------------------
#define FPL (66*144)
__launch_bounds__(256)
__global__ void ffn_dwg_kernel(const unsigned short* __restrict__ p,
                               const float* __restrict__ dw,
                               unsigned short* __restrict__ g){
  __shared__ unsigned short lds[2*FPL];     // 2 planes, rows 66 (h-halo), cols w+8 (0..143)
  int bid = blockIdx.x;
  int jc = bid % NHID;
  int rest = bid / NHID;
  int bb = rest & 1;
  int half = rest >> 1;
  int t = threadIdx.x;
  #pragma unroll
  for (int i = t; i < 2*FPL/8; i += 256)
    *(short8*)(lds + i*8) = (short8){0,0,0,0,0,0,0,0};
  __syncthreads();
  int band = t >> 4, wi = t & 15, w0 = wi*8;
  #pragma unroll
  for (int pl=0; pl<2; pl++){
    const unsigned short* src = p + (((size_t)(bb*704 + jc + pl*NHID)) << 14);
    #pragma unroll
    for (int it=0; it<5; it++){
      int r_idx = it*16 + band;
      if (r_idx < 66){
        int h = half*64 - 1 + r_idx;
        if ((unsigned)h < 128u){
          short8 v = *(const short8*)(src + (h<<7) + w0);
          *(short8*)(&lds[pl*FPL + r_idx*144 + w0 + 8]) = v;
        }
      }
    }
  }
  float w1[9], w2[9];
  #pragma unroll
  for (int i=0;i<9;i++){ w1[i] = dw[jc*9 + i]; w2[i] = dw[(jc+NHID)*9 + i]; }
  __syncthreads();
  int rb = band*4;
  float r1[3][10], r2[3][10];
  #pragma unroll
  for (int m=0;m<2;m++){
    load_row10(&lds[(rb+m)*144 + w0], r1[m]);
    load_row10(&lds[FPL + (rb+m)*144 + w0], r2[m]);
  }
  unsigned short* outp = g + (((size_t)(bb*NHID + jc)) << 14);
  #pragma unroll
  for (int s=0;s<4;s++){
    load_row10(&lds[(rb+2+s)*144 + w0], r1[(2+s)%3]);
    load_row10(&lds[FPL + (rb+2+s)*144 + w0], r2[(2+s)%3]);
    int h = half*64 + rb + s;
    short8 ov;
    #pragma unroll
    for (int j=0;j<8;j++){
      float c1 = 0.f, c2 = 0.f;
      #pragma unroll
      for (int dy=0;dy<3;dy++){
        const float* a = r1[(s+dy)%3];
        const float* bpt = r2[(s+dy)%3];
        #pragma unroll
        for (int dx=0;dx<3;dx++){
          c1 += w1[dy*3+dx]*a[j+dx];
          c2 += w2[dy*3+dx]*bpt[j+dx];
        }
      }
      float ge = 0.5f*c1*(1.f + erff(c1*0.70710678118654752f));
      ov[j] = (short)f2bf(ge*c2);
    }
    *(short8*)(outp + h*128 + w0) = ov;
  }
}

extern "C" void kernel_launch(void* const* d_in, const int* in_sizes, int n_in,
                              void* d_out, int out_size, void* d_ws, size_t ws_size,
                              hipStream_t stream){
  (void)in_sizes; (void)n_in; (void)out_size;
  if (ws_size < WS_NEEDED) return;
  const float* x        = (const float*)d_in[0];
  const float* ln1_w    = (const float*)d_in[1];
  const float* ln1_b    = (const float*)d_in[2];
  const float* qkvo_w   = (const float*)d_in[3];
  const float* qkvo_b   = (const float*)d_in[4];
  const float* lepe_w   = (const float*)d_in[5];
  const float* lepe_b   = (const float*)d_in[6];
  const float* proj_w   = (const float*)d_in[7];
  const float* proj_b   = (const float*)d_in[8];
  const float* ln2_w    = (const float*)d_in[9];
  const float* ln2_b    = (const float*)d_in[10];
  const float* ffn_in_w = (const float*)d_in[11];
  const float* ffn_dw_w = (const float*)d_in[12];
  const float* ffn_out_w= (const float*)d_in[13];

  char* ws = (char*)d_ws;
  unsigned short* bufA   = (unsigned short*)(ws + OFF_A);
  unsigned short* bufB   = (unsigned short*)(ws + OFF_B);
  unsigned short* lepe   = (unsigned short*)(ws + OFF_C);
  unsigned short* gbuf   = (unsigned short*)(ws + OFF_C);   // reuses lepe region in FFN phase
  float* partials        = (float*)(ws + OFF_GT2);          // attention phase only
  float* stats           = (float*)(ws + OFF_STATS);
  float* sin_t           = (float*)(ws + OFF_SIN);
  float* cos_t           = (float*)(ws + OFF_COS);
  unsigned short* wq     = (unsigned short*)(ws + OFF_WQ);
  unsigned short* wqo    = (unsigned short*)(ws + OFF_WQO);
  float* qo_bias         = (float*)(ws + OFF_QOB);
  unsigned short* wp     = (unsigned short*)(ws + OFF_WP);
  unsigned short* wfi    = (unsigned short*)(ws + OFF_WFI);
  unsigned short* wfo    = (unsigned short*)(ws + OFF_WFO);
  const unsigned short* wkv = wq + 128*128;

  float* out_f = (float*)d_out;
  dim3 blk(256);
  hipLaunchKernelGGL(rope_kernel, dim3(64), blk, 0, stream, sin_t, cos_t);
  hipLaunchKernelGGL(wconv_kernel, dim3((512*128)/256), blk, 0, stream, qkvo_w, wq, 512,128,512,128);
  hipLaunchKernelGGL(reorder_qo_kernel, dim3((256*128)/256), blk, 0, stream, qkvo_w, qkvo_b, wqo, qo_bias);
  hipLaunchKernelGGL(wconv_kernel, dim3((128*128)/256), blk, 0, stream, proj_w, wp, 128,128,128,128);
  hipLaunchKernelGGL(wconv_kernel, dim3((704*128)/256), blk, 0, stream, ffn_in_w, wfi, 680,128,704,128);
  hipLaunchKernelGGL(wconv_kernel, dim3((128*352)/256), blk, 0, stream, ffn_out_w, wfo, 128,340,128,352);

  // attention phase
  hipLaunchKernelGGL(ln_kernel, dim3(1024), blk, 0, stream, x, ln1_w, ln1_b, bufA);
  hipLaunchKernelGGL((gemm_kernel<256,128,true,false,true>), dim3(1024,4), blk, 0, stream,
                     bufA, wkv, qkvo_b + 128, (const float*)nullptr, (void*)bufB);     // kv
  hipLaunchKernelGGL(lepe_kernel, dim3(1024), blk, 0, stream, bufB, lepe_w, lepe_b, lepe);
  hipLaunchKernelGGL(attn_partial, dim3(1024), blk, 0, stream, bufB, sin_t, cos_t, partials);
  hipLaunchKernelGGL(attn_combine, dim3(40), blk, 0, stream, partials, stats);
  hipLaunchKernelGGL((gemm_kernel<256,128,true,false,true>), dim3(1024,4), blk, 0, stream,
                     bufA, wqo, qo_bias, (const float*)nullptr, (void*)bufB);          // qo
  hipLaunchKernelGGL(attn_apply_kernel, dim3(512,2), blk, 0, stream, bufB, lepe, stats, sin_t, cos_t, bufA);
  hipLaunchKernelGGL((gemm_kernel<128,128,true,true,false>), dim3(1024,2), blk, 0, stream,
                     bufA, wp, proj_b, x, (void*)out_f);                               // x1 -> d_out fp32

  // ffn phase
  hipLaunchKernelGGL(ln_kernel, dim3(1024), blk, 0, stream, out_f, ln2_w, ln2_b, bufA);
  for (int bp = 0; bp < 4; bp++){
    const unsigned short* xin = bufA + (size_t)bp*32768*128;
    float* outp = out_f + (size_t)bp*2*128*16384;
    hipLaunchKernelGGL((gemm_kernel<704,128,false,false,true>), dim3(256,11), blk, 0, stream,
                       xin, wfi, (const float*)nullptr, (const float*)nullptr, (void*)bufB);
    hipLaunchKernelGGL(ffn_dwg_kernel, dim3(1360), blk, 0, stream, bufB, ffn_dw_w, gbuf);
    hipLaunchKernelGGL(ffn_out_gemm, dim3(256,2), blk, 0, stream, gbuf, wfo, outp);
  }
}

// Round 6
// 685.320 us; speedup vs baseline: 1.2307x; 1.0588x over previous
//
#include <hip/hip_runtime.h>

#define LSP 16384            // H*W
#define NBATCH 8
#define NPOS (NBATCH*LSP)    // 131072
#define NHID 340
#define ATT_SCALE 0.35355339059327373f

// ---- workspace layout (bytes) ----
#define OFF_A        0ULL          // 32MB: xn_t -> resg_t -> xn2_t
#define OFF_B        33554432ULL   // 64MB: kv -> qo ; FFN: pbuf2 (44MB)
#define OFF_GT2      79691776ULL   // 22MB: attn partials (327KB) ; rest free
#define OFF_C        100663296ULL  // 32MB: lepe ; FFN: gbuf (22.3MB)
#define OFF_PART     134217728ULL  // 160KB (unused now)
#define OFF_STATS    134381568ULL  // 40KB
#define OFF_SIN      134422528ULL  // 512KB
#define OFF_COS      134946816ULL  // 512KB
#define OFF_WQ       135471104ULL  // 512x128 bf16
#define OFF_WQO      135602176ULL  // 256x128 bf16
#define OFF_QOB      135667712ULL  // 256 f32
#define OFF_WP       135668736ULL  // 128x128 bf16
#define OFF_WFI      135701504ULL  // 704x128 bf16
#define OFF_WFO      135881728ULL  // 128x352 bf16
#define WS_NEEDED    135971840ULL

typedef __attribute__((ext_vector_type(8))) short short8;
typedef __attribute__((ext_vector_type(4))) float floatx4;

__device__ __forceinline__ float bf2f(unsigned short u){
  union { unsigned int i; float f; } c; c.i = ((unsigned int)u) << 16; return c.f;
}
__device__ __forceinline__ unsigned short f2bf(float f){
  union { float f; unsigned int i; } c; c.f = f;
  unsigned int r = c.i + 0x7fffu + ((c.i >> 16) & 1u);
  return (unsigned short)(r >> 16);
}

// read 12 bf16 (4B-aligned) from LDS -> fp32
__device__ __forceinline__ void load_row12(const unsigned short* p, float* r){
  const unsigned int* q = (const unsigned int*)p;
  #pragma unroll
  for (int i=0;i<6;i++){
    unsigned int u = q[i];
    r[2*i]   = bf2f((unsigned short)(u & 0xffffu));
    r[2*i+1] = bf2f((unsigned short)(u >> 16));
  }
}

// read 10 bf16 (1 edge + aligned 8 + 1 edge) from LDS -> fp32
__device__ __forceinline__ void load_row10(const unsigned short* base, float* r){
  short8 B = *(const short8*)(base + 8);
  r[0] = bf2f(base[7]);
  #pragma unroll
  for (int i=0;i<8;i++) r[1+i] = bf2f((unsigned short)B[i]);
  r[9] = bf2f(base[16]);
}

// ------------------- RoPE tables: sin/cos[l][8] fp32 -------------------
__global__ void rope_kernel(float* __restrict__ sin_t, float* __restrict__ cos_t){
  int l = blockIdx.x*256 + threadIdx.x;
  if (l >= LSP) return;
  int h = l >> 7, w = l & 127;
  float s0 = sinf((float)h),        c0 = cosf((float)h);
  float s1 = sinf((float)h*1e-4f),  c1 = cosf((float)h*1e-4f);
  float s2 = sinf((float)w),        c2 = cosf((float)w);
  float s3 = sinf((float)w*1e-4f),  c3 = cosf((float)w*1e-4f);
  float* sp = sin_t + l*8; float* cp = cos_t + l*8;
  sp[0]=s0; sp[1]=s0; sp[2]=s1; sp[3]=s1; sp[4]=s2; sp[5]=s2; sp[6]=s3; sp[7]=s3;
  cp[0]=c0; cp[1]=c0; cp[2]=c1; cp[3]=c1; cp[4]=c2; cp[5]=c2; cp[6]=c3; cp[7]=c3;
}

// ------------------- weight fp32 -> padded bf16 -------------------
__global__ void wconv_kernel(const float* __restrict__ src, unsigned short* __restrict__ dst,
                             int O, int K, int OP, int KP){
  int i = blockIdx.x*256 + threadIdx.x;
  if (i >= OP*KP) return;
  int o = i / KP, k = i - o*KP;
  float v = (o < O && k < K) ? src[o*K + k] : 0.f;
  dst[i] = f2bf(v);
}

// ------------------- q/o weight+bias reorder: rows [0..128)+[384..512) -------------------
__global__ void reorder_qo_kernel(const float* __restrict__ qkvo_w, const float* __restrict__ qkvo_b,
                                  unsigned short* __restrict__ wqo, float* __restrict__ qo_bias){
  int i = blockIdx.x*256 + threadIdx.x;
  if (i < 256){
    qo_bias[i] = qkvo_b[(i < 128) ? i : i + 256];
  }
  if (i >= 256*128) return;
  int o = i >> 7, k = i & 127;
  int srow = (o < 128) ? o : o + 256;
  wqo[i] = f2bf(qkvo_w[srow*128 + k]);
}

// ------------------- LayerNorm over 128 channels; out position-major bf16 -------------------
__launch_bounds__(256)
__global__ void ln_kernel(const float* __restrict__ x, const float* __restrict__ gam,
                          const float* __restrict__ bet, unsigned short* __restrict__ out_t){
  __shared__ float ps[2][128], pq[2][128];
  __shared__ unsigned short tile[128*132];
  int t = threadIdx.x;
  int pidx = t & 127;
  int half = t >> 7;
  int p0 = blockIdx.x*128;
  int p = p0 + pidx;
  int b = p >> 14, l = p & 16383;
  const float* xb = x + (((size_t)b) << 21) + (((size_t)(half*64)) << 14) + l;
  float vals[64];
  float s = 0.f, sq = 0.f;
  #pragma unroll
  for (int c = 0; c < 64; c++){
    float v = xb[(size_t)c << 14];
    vals[c] = v;
    s += v; sq += v*v;
  }
  ps[half][pidx] = s; pq[half][pidx] = sq;
  __syncthreads();
  float S = ps[0][pidx] + ps[1][pidx];
  float Q = pq[0][pidx] + pq[1][pidx];
  float mu = S * 0.0078125f;
  float var = Q * 0.0078125f - mu*mu;
  float rstd = rsqrtf(var + 1e-5f);
  #pragma unroll
  for (int c0 = 0; c0 < 64; c0 += 8){
    short8 vv;
    #pragma unroll
    for (int i = 0; i < 8; i++){
      int c = c0 + i;
      int cg = half*64 + c;
      vv[i] = (short)f2bf((vals[c] - mu) * rstd * gam[cg] + bet[cg]);
    }
    *(short8*)&tile[pidx*132 + half*64 + c0] = vv;
  }
  __syncthreads();
  unsigned short* og = out_t + ((size_t)p0 << 7);
  #pragma unroll
  for (int it = 0; it < 8; it++){
    int idx = it*256 + t;
    int row = idx >> 4;
    int col = (idx & 15) * 8;
    *(short8*)&og[(row << 7) + col] = *(const short8*)&tile[row*132 + col];
  }
}

// ------------------- MFMA GEMM: out[b][o][l] = sum_k W[o][k]*in_t[b*L+l][k] -------------------
// NL consecutive 128-position tiles per block (bigger blocks -> steadier occupancy).
// oc chunk (64 output channels) from blockIdx.y. LDS-staged coalesced epilogue.
template<int OPAD, int KPAD, int NL, bool HASBIAS, bool RESID, bool OUTBF16>
__launch_bounds__(256)
__global__ void gemm_kernel(const unsigned short* __restrict__ in_t,
                            const unsigned short* __restrict__ wb,
                            const float* __restrict__ bias,
                            const float* __restrict__ resid,
                            void* __restrict__ outp){
  constexpr int KS = KPAD / 32;
  constexpr int SBYTES = OUTBF16 ? (64*136*2) : (64*132*4);
  __shared__ __align__(16) unsigned char smem[SBYTES];
  const int t = threadIdx.x;
  const int lane = t & 63;
  const int wv = t >> 6;
  const int lane15 = lane & 15;
  const int quad = lane >> 4;
  const int oc = blockIdx.y;

  #pragma unroll 1
  for (int tl = 0; tl < NL; tl++){
    const int l0 = (blockIdx.x * NL + tl) * 128;
    const int b = l0 >> 14;
    const int lloc0 = l0 & 16383;

    short8 fb[2][KS];
    {
      const unsigned short* base = in_t + ((size_t)(l0 + wv*32 + lane15)) * KPAD + quad*8;
      #pragma unroll
      for (int nt = 0; nt < 2; nt++){
        #pragma unroll
        for (int ks = 0; ks < KS; ks++)
          fb[nt][ks] = *(const short8*)(base + (size_t)nt*16*KPAD + ks*32);
      }
    }
    floatx4 acc[4][2];
    #pragma unroll
    for (int mt=0; mt<4; mt++)
      #pragma unroll
      for (int nt=0; nt<2; nt++)
        acc[mt][nt] = (floatx4){0.f,0.f,0.f,0.f};
    #pragma unroll
    for (int ks = 0; ks < KS; ks++){
      short8 fa[4];
      const unsigned short* wrow = wb + ((size_t)(oc*64 + lane15)) * KPAD + ks*32 + quad*8;
      #pragma unroll
      for (int mt=0; mt<4; mt++)
        fa[mt] = *(const short8*)(wrow + (size_t)mt*16*KPAD);
      #pragma unroll
      for (int mt=0; mt<4; mt++)
        #pragma unroll
        for (int nt=0; nt<2; nt++)
          acc[mt][nt] = __builtin_amdgcn_mfma_f32_16x16x32_bf16(fa[mt], fb[nt][ks], acc[mt][nt], 0, 0, 0);
    }

    if (tl) __syncthreads();   // protect smem reuse across tiles

    if (OUTBF16){
      unsigned short* cs = (unsigned short*)smem;
      #pragma unroll
      for (int mt=0; mt<4; mt++)
        #pragma unroll
        for (int nt=0; nt<2; nt++)
          #pragma unroll
          for (int r=0; r<4; r++){
            const int o = mt*16 + quad*4 + r;
            float v = acc[mt][nt][r];
            if (HASBIAS) v += bias[oc*64 + o];
            cs[o*136 + wv*32 + nt*16 + lane15] = f2bf(v);
          }
      __syncthreads();
      unsigned short* og = (unsigned short*)outp;
      #pragma unroll
      for (int j=0; j<4; j++){
        int idx = j*256 + t;
        int row = idx >> 4;
        int col = (idx & 15) * 8;
        short8 v = *(const short8*)&cs[row*136 + col];
        *(short8*)&og[(((size_t)(b*OPAD + oc*64 + row)) << 14) + lloc0 + col] = v;
      }
    } else {
      float* cf = (float*)smem;
      #pragma unroll
      for (int mt=0; mt<4; mt++)
        #pragma unroll
        for (int nt=0; nt<2; nt++)
          #pragma unroll
          for (int r=0; r<4; r++){
            const int o = mt*16 + quad*4 + r;
            float v = acc[mt][nt][r];
            if (HASBIAS) v += bias[oc*64 + o];
            cf[o*132 + wv*32 + nt*16 + lane15] = v;
          }
      __syncthreads();
      float* og = (float*)outp;
      #pragma unroll
      for (int j=0; j<8; j++){
        int idx = j*256 + t;
        int row = idx >> 5;
        int col = (idx & 31) * 4;
        floatx4 v = *(const floatx4*)&cf[row*132 + col];
        if (RESID){
          floatx4 rv = *(const floatx4*)(resid + (((size_t)(b*128 + oc*64 + row)) << 14) + lloc0 + col);
          v += rv;
        }
        *(floatx4*)&og[(((size_t)(b*OPAD + oc*64 + row)) << 14) + lloc0 + col] = v;
      }
    }
  }
}

// ------------------- FFN-out GEMM with fused transpose of g -------------------
__launch_bounds__(256)
__global__ void ffn_out_gemm(const unsigned short* __restrict__ g,
                             const unsigned short* __restrict__ wb,
                             float* __restrict__ outp){
  __shared__ __align__(16) unsigned char smem[64*132*4];   // union: 2x 10240B stage | cf
  const int t = threadIdx.x;
  const int l0 = blockIdx.x * 128;
  const int b = l0 >> 14;
  const int lloc0 = l0 & 16383;
  const int lane = t & 63;
  const int wv = t >> 6;
  const int lane15 = lane & 15;
  const int quad = lane >> 4;
  const int oc = blockIdx.y;
  const int jj = t >> 3;      // 0..31 : j within slice
  const int c8 = t & 7;       // chunk base

  auto stage = [&](int s, int bufi){
    unsigned short* buf = (unsigned short*)(smem + bufi*10240);
    int j = s*32 + jj;
    const unsigned short* src = g + (((size_t)(b*NHID + j)) << 14) + lloc0;
    #pragma unroll
    for (int cc=0; cc<2; cc++){
      int c = c8 + cc*8;
      short8 v = (short8){0,0,0,0,0,0,0,0};
      if (j < NHID) v = *(const short8*)(src + c*8);
      #pragma unroll
      for (int e=0; e<8; e++)
        buf[(c*8+e)*40 + jj] = (unsigned short)v[e];
    }
  };

  floatx4 acc[4][2];
  #pragma unroll
  for (int mt=0; mt<4; mt++)
    #pragma unroll
    for (int nt=0; nt<2; nt++)
      acc[mt][nt] = (floatx4){0.f,0.f,0.f,0.f};

  stage(0, 0);
  #pragma unroll 1
  for (int s=0; s<11; s++){
    __syncthreads();
    if (s < 10) stage(s+1, (s+1)&1);
    const unsigned short* cur = (const unsigned short*)(smem + (s&1)*10240);
    short8 fbv[2];
    #pragma unroll
    for (int nt=0; nt<2; nt++)
      fbv[nt] = *(const short8*)&cur[(wv*32 + nt*16 + lane15)*40 + quad*8];
    const unsigned short* wrow = wb + ((size_t)(oc*64 + lane15))*352 + s*32 + quad*8;
    short8 fa[4];
    #pragma unroll
    for (int mt=0; mt<4; mt++)
      fa[mt] = *(const short8*)(wrow + (size_t)mt*16*352);
    #pragma unroll
    for (int mt=0; mt<4; mt++)
      #pragma unroll
      for (int nt=0; nt<2; nt++)
        acc[mt][nt] = __builtin_amdgcn_mfma_f32_16x16x32_bf16(fa[mt], fbv[nt], acc[mt][nt], 0, 0, 0);
  }
  __syncthreads();
  float* cf = (float*)smem;
  #pragma unroll
  for (int mt=0; mt<4; mt++)
    #pragma unroll
    for (int nt=0; nt<2; nt++)
      #pragma unroll
      for (int r=0; r<4; r++){
        const int o = mt*16 + quad*4 + r;
        cf[o*132 + wv*32 + nt*16 + lane15] = acc[mt][nt][r];
      }
  __syncthreads();
  #pragma unroll
  for (int j=0; j<8; j++){
    int idx = j*256 + t;
    int row = idx >> 5;
    int col = (idx & 31) * 4;
    floatx4 v = *(const floatx4*)&cf[row*132 + col];
    size_t oi = (((size_t)(b*128 + oc*64 + row)) << 14) + lloc0 + col;
    floatx4 rv = *(const floatx4*)&outp[oi];
    v += rv;
    *(floatx4*)&outp[oi] = v;
  }
}

// ------------------- lepe: depthwise 5x5, LDS-staged sliding window -------------------
__launch_bounds__(256)
__global__ void lepe_kernel(const unsigned short* __restrict__ kv,
                            const float* __restrict__ lw, const float* __restrict__ lb,
                            unsigned short* __restrict__ lepe){
  __shared__ unsigned short lds[132*136];     // rows h+2 (0..131), cols w+2 (0..131), stride 136
  int bc = blockIdx.x;                        // b*128 + c
  int b = bc >> 7, c = bc & 127;
  int t = threadIdx.x;
  #pragma unroll
  for (int i = t; i < 132*136/8; i += 256)
    *(short8*)(lds + i*8) = (short8){0,0,0,0,0,0,0,0};
  __syncthreads();
  int band = t >> 4, wi = t & 15, w0 = wi*8;
  const unsigned short* vp = kv + (((size_t)(b*256 + 128 + c)) << 14);
  {
    #pragma unroll
    for (int it = 0; it < 8; it++){
      int hh = band + it*16;
      short8 v = *(const short8*)(vp + (hh<<7) + w0);
      unsigned int* dst = (unsigned int*)&lds[(hh+2)*136 + w0 + 2];
      union { short8 s; unsigned int u[4]; } cv; cv.s = v;
      #pragma unroll
      for (int q=0;q<4;q++) dst[q] = cv.u[q];
    }
  }
  float wt[25];
  #pragma unroll
  for (int i=0;i<25;i++) wt[i] = lw[c*25 + i];
  float bias = lb[c];
  __syncthreads();
  int h0 = band*8;
  float win[5][12];
  #pragma unroll
  for (int m=0;m<4;m++) load_row12(&lds[(h0+m)*136 + w0], win[m]);
  unsigned short* outp = lepe + ((size_t)bc << 14);
  #pragma unroll
  for (int s=0;s<8;s++){
    load_row12(&lds[(h0+4+s)*136 + w0], win[(4+s)%5]);
    short8 ov;
    #pragma unroll
    for (int j=0;j<8;j++){
      float acc = bias;
      #pragma unroll
      for (int dy=0;dy<5;dy++){
        const float* r = win[(s+dy)%5];
        #pragma unroll
        for (int dx=0;dx<5;dx++) acc += wt[dy*5+dx]*r[j+dx];
      }
      ov[j] = (short)f2bf(acc);
    }
    *(short8*)(outp + (h0+s)*128 + w0) = ov;
  }
}

// ------------------- attention reduction partials per (b,head,chunk of 2048) -------------------
__launch_bounds__(256)
__global__ void attn_partial(const unsigned short* __restrict__ kv,
                             const float* __restrict__ sin_t, const float* __restrict__ cos_t,
                             float* __restrict__ partials){
  int pair = blockIdx.x >> 3;
  int chunk = blockIdx.x & 7;
  int b = pair >> 4, hd = pair & 15;
  const unsigned short* kb = kv + (((size_t)(b*256 + hd*8)) << 14);
  const unsigned short* vb = kb + ((size_t)128 << 14);
  float red[80];
  #pragma unroll
  for (int i=0;i<80;i++) red[i]=0.f;
  int l0 = chunk*2048;
  for (int li=0; li<8; li++){
    int l = l0 + li*256 + threadIdx.x;
    float k[8], v[8], ks[8];
    #pragma unroll
    for (int e=0;e<8;e++){
      float t = bf2f(kb[((size_t)e<<14)+l]);
      k[e] = t>0.f ? t+1.f : __expf(t);
      v[e] = bf2f(vb[((size_t)e<<14)+l]);
      red[e]   += k[e];
      red[8+e] += v[e];
    }
    const float* sp = sin_t + l*8;
    const float* cp = cos_t + l*8;
    #pragma unroll
    for (int j=0;j<4;j++){
      float x1=k[2*j], x2=k[2*j+1];
      ks[2*j]   = x1*cp[2*j]   - x2*sp[2*j];
      ks[2*j+1] = x2*cp[2*j+1] + x1*sp[2*j+1];
    }
    #pragma unroll
    for (int d=0; d<8; d++)
      #pragma unroll
      for (int e=0;e<8;e++)
        red[16 + d*8 + e] += ks[d]*v[e];
  }
  #pragma unroll
  for (int off=32; off>0; off>>=1){
    #pragma unroll
    for (int i=0;i<80;i++)
      red[i] += __shfl_down(red[i], off);
  }
  __shared__ float lds[4][80];
  int lane = threadIdx.x & 63, wv = threadIdx.x >> 6;
  if (lane==0){
    #pragma unroll
    for (int i=0;i<80;i++) lds[wv][i] = red[i];
  }
  __syncthreads();
  if (threadIdx.x < 80){
    float s = lds[0][threadIdx.x]+lds[1][threadIdx.x]+lds[2][threadIdx.x]+lds[3][threadIdx.x];
    partials[(size_t)blockIdx.x*80 + threadIdx.x] = s;
  }
}

__global__ void attn_combine(const float* __restrict__ partials, float* __restrict__ stats){
  int i = blockIdx.x*256 + threadIdx.x;
  if (i >= 128*80) return;
  int pair = i / 80, idx = i - pair*80;
  float s = 0.f;
  #pragma unroll
  for (int cc=0; cc<8; cc++)
    s += partials[(size_t)(pair*8+cc)*80+idx];
  s *= (idx < 16) ? (1.f/LSP) : (ATT_SCALE/LSP);
  stats[i] = s;
}

// ------------------- attention apply + lepe add + o-gate; out position-major bf16 -------------------
__launch_bounds__(256)
__global__ void attn_apply_kernel(const unsigned short* __restrict__ qo,
                                  const unsigned short* __restrict__ lepe,
                                  const float* __restrict__ stats,
                                  const float* __restrict__ sin_t,
                                  const float* __restrict__ cos_t,
                                  unsigned short* __restrict__ resg_t){
  __shared__ float st[8*80];
  __shared__ unsigned short tile[256*66];
  int p0 = blockIdx.x * 256;
  int b = p0 >> 14;
  int hg = blockIdx.y;
  for (int i = threadIdx.x; i < 8*80; i += 256) st[i] = stats[b*16*80 + hg*8*80 + i];
  __syncthreads();
  int t = threadIdx.x;
  int p = p0 + t;
  int l = p & 16383;
  float sv[8], cv[8];
  {
    const float* sp = sin_t + l*8;
    const float* cp = cos_t + l*8;
    #pragma unroll
    for (int i=0;i<8;i++){ sv[i]=sp[i]; cv[i]=cp[i]; }
  }
  #pragma unroll 1
  for (int hd8=0; hd8<8; hd8++){
    int hd = hg*8 + hd8;
    const float* S = st + hd8*80;
    const unsigned short* qb = qo + (((size_t)(b*256 + hd*8)) << 14) + l;
    const unsigned short* ob = qb + ((size_t)128 << 14);
    const unsigned short* lb = lepe + (((size_t)(b*128 + hd*8)) << 14) + l;
    float q[8];
    #pragma unroll
    for (int e=0;e<8;e++){
      float tq = bf2f(qb[(size_t)e<<14]);
      q[e] = tq > 0.f ? tq + 1.f : __expf(tq);
    }
    float z = 0.f;
    #pragma unroll
    for (int e=0;e<8;e++) z += q[e]*S[e];
    z *= ATT_SCALE;
    float qs[8];
    #pragma unroll
    for (int jj=0;jj<4;jj++){
      float x1=q[2*jj], x2=q[2*jj+1];
      qs[2*jj]   = x1*cv[2*jj]   - x2*sv[2*jj];
      qs[2*jj+1] = x2*cv[2*jj+1] + x1*sv[2*jj+1];
    }
    float fac = 1.f + 1.f/(z + 1e-6f);
    short8 vv;
    #pragma unroll
    for (int e=0;e<8;e++){
      float r = 0.f;
      #pragma unroll
      for (int d=0; d<8; d++) r += qs[d]*S[16 + d*8 + e];
      r = r*fac - z*S[8+e];
      float val = (r + bf2f(lb[(size_t)e<<14])) * bf2f(ob[(size_t)e<<14]);
      vv[e] = (short)f2bf(val);
    }
    *(short8*)&tile[t*66 + hd8*8] = vv;
  }
  __syncthreads();
  unsigned short* og = resg_t + ((size_t)p0 << 7) + hg*64;
  #pragma unroll
  for (int it = 0; it < 8; it++){
    int idx = it*256 + t;
    int row = idx >> 3;
    int col = (idx & 7) * 8;
    *(short8*)&og[(row << 7) + col] = *(const short8*)&tile[row*66 + col];
  }
}

// ------------------- ffn dw3x3 x2 + exact gelu gate, LDS-staged; plane-major out -------------------
#define FPL (66*144)
__launch_bounds__(256)
__global__ void ffn_dwg_kernel(const unsigned short* __restrict__ p,
                               const float* __restrict__ dw,
                               unsigned short* __restrict__ g){
  __shared__ unsigned short lds[2*FPL];     // 2 planes, rows 66 (h-halo), cols w+8 (0..143)
  int bid = blockIdx.x;
  int jc = bid % NHID;
  int rest = bid / NHID;
  int bb = rest & 1;
  int half = rest >> 1;
  int t = threadIdx.x;
  #pragma unroll
  for (int i = t; i < 2*FPL/8; i += 256)
    *(short8*)(lds + i*8) = (short8){0,0,0,0,0,0,0,0};
  __syncthreads();
  int band = t >> 4, wi = t & 15, w0 = wi*8;
  #pragma unroll
  for (int pl=0; pl<2; pl++){
    const unsigned short* src = p + (((size_t)(bb*704 + jc + pl*NHID)) << 14);
    #pragma unroll
    for (int it=0; it<5; it++){
      int r_idx = it*16 + band;
      if (r_idx < 66){
        int h = half*64 - 1 + r_idx;
        if ((unsigned)h < 128u){
          short8 v = *(const short8*)(src + (h<<7) + w0);
          *(short8*)(&lds[pl*FPL + r_idx*144 + w0 + 8]) = v;
        }
      }
    }
  }
  float w1[9], w2[9];
  #pragma unroll
  for (int i=0;i<9;i++){ w1[i] = dw[jc*9 + i]; w2[i] = dw[(jc+NHID)*9 + i]; }
  __syncthreads();
  int rb = band*4;
  float r1[3][10], r2[3][10];
  #pragma unroll
  for (int m=0;m<2;m++){
    load_row10(&lds[(rb+m)*144 + w0], r1[m]);
    load_row10(&lds[FPL + (rb+m)*144 + w0], r2[m]);
  }
  unsigned short* outp = g + (((size_t)(bb*NHID + jc)) << 14);
  #pragma unroll
  for (int s=0;s<4;s++){
    load_row10(&lds[(rb+2+s)*144 + w0], r1[(2+s)%3]);
    load_row10(&lds[FPL + (rb+2+s)*144 + w0], r2[(2+s)%3]);
    int h = half*64 + rb + s;
    short8 ov;
    #pragma unroll
    for (int j=0;j<8;j++){
      float c1 = 0.f, c2 = 0.f;
      #pragma unroll
      for (int dy=0;dy<3;dy++){
        const float* a = r1[(s+dy)%3];
        const float* bpt = r2[(s+dy)%3];
        #pragma unroll
        for (int dx=0;dx<3;dx++){
          c1 += w1[dy*3+dx]*a[j+dx];
          c2 += w2[dy*3+dx]*bpt[j+dx];
        }
      }
      float ge = 0.5f*c1*(1.f + erff(c1*0.70710678118654752f));
      ov[j] = (short)f2bf(ge*c2);
    }
    *(short8*)(outp + h*128 + w0) = ov;
  }
}

extern "C" void kernel_launch(void* const* d_in, const int* in_sizes, int n_in,
                              void* d_out, int out_size, void* d_ws, size_t ws_size,
                              hipStream_t stream){
  (void)in_sizes; (void)n_in; (void)out_size;
  if (ws_size < WS_NEEDED) return;
  const float* x        = (const float*)d_in[0];
  const float* ln1_w    = (const float*)d_in[1];
  const float* ln1_b    = (const float*)d_in[2];
  const float* qkvo_w   = (const float*)d_in[3];
  const float* qkvo_b   = (const float*)d_in[4];
  const float* lepe_w   = (const float*)d_in[5];
  const float* lepe_b   = (const float*)d_in[6];
  const float* proj_w   = (const float*)d_in[7];
  const float* proj_b   = (const float*)d_in[8];
  const float* ln2_w    = (const float*)d_in[9];
  const float* ln2_b    = (const float*)d_in[10];
  const float* ffn_in_w = (const float*)d_in[11];
  const float* ffn_dw_w = (const float*)d_in[12];
  const float* ffn_out_w= (const float*)d_in[13];

  char* ws = (char*)d_ws;
  unsigned short* bufA   = (unsigned short*)(ws + OFF_A);
  unsigned short* bufB   = (unsigned short*)(ws + OFF_B);
  unsigned short* lepe   = (unsigned short*)(ws + OFF_C);
  unsigned short* gbuf   = (unsigned short*)(ws + OFF_C);   // reuses lepe region in FFN phase
  float* partials        = (float*)(ws + OFF_GT2);          // attention phase only
  float* stats           = (float*)(ws + OFF_STATS);
  float* sin_t           = (float*)(ws + OFF_SIN);
  float* cos_t           = (float*)(ws + OFF_COS);
  unsigned short* wq     = (unsigned short*)(ws + OFF_WQ);
  unsigned short* wqo    = (unsigned short*)(ws + OFF_WQO);
  float* qo_bias         = (float*)(ws + OFF_QOB);
  unsigned short* wp     = (unsigned short*)(ws + OFF_WP);
  unsigned short* wfi    = (unsigned short*)(ws + OFF_WFI);
  unsigned short* wfo    = (unsigned short*)(ws + OFF_WFO);
  const unsigned short* wkv = wq + 128*128;

  float* out_f = (float*)d_out;
  dim3 blk(256);
  hipLaunchKernelGGL(rope_kernel, dim3(64), blk, 0, stream, sin_t, cos_t);
  hipLaunchKernelGGL(wconv_kernel, dim3((512*128)/256), blk, 0, stream, qkvo_w, wq, 512,128,512,128);
  hipLaunchKernelGGL(reorder_qo_kernel, dim3((256*128)/256), blk, 0, stream, qkvo_w, qkvo_b, wqo, qo_bias);
  hipLaunchKernelGGL(wconv_kernel, dim3((128*128)/256), blk, 0, stream, proj_w, wp, 128,128,128,128);
  hipLaunchKernelGGL(wconv_kernel, dim3((704*128)/256), blk, 0, stream, ffn_in_w, wfi, 680,128,704,128);
  hipLaunchKernelGGL(wconv_kernel, dim3((128*352)/256), blk, 0, stream, ffn_out_w, wfo, 128,340,128,352);

  // attention phase
  hipLaunchKernelGGL(ln_kernel, dim3(1024), blk, 0, stream, x, ln1_w, ln1_b, bufA);
  hipLaunchKernelGGL((gemm_kernel<256,128,2,true,false,true>), dim3(512,4), blk, 0, stream,
                     bufA, wkv, qkvo_b + 128, (const float*)nullptr, (void*)bufB);     // kv
  hipLaunchKernelGGL(lepe_kernel, dim3(1024), blk, 0, stream, bufB, lepe_w, lepe_b, lepe);
  hipLaunchKernelGGL(attn_partial, dim3(1024), blk, 0, stream, bufB, sin_t, cos_t, partials);
  hipLaunchKernelGGL(attn_combine, dim3(40), blk, 0, stream, partials, stats);
  hipLaunchKernelGGL((gemm_kernel<256,128,2,true,false,true>), dim3(512,4), blk, 0, stream,
                     bufA, wqo, qo_bias, (const float*)nullptr, (void*)bufB);          // qo
  hipLaunchKernelGGL(attn_apply_kernel, dim3(512,2), blk, 0, stream, bufB, lepe, stats, sin_t, cos_t, bufA);
  hipLaunchKernelGGL((gemm_kernel<128,128,1,true,true,false>), dim3(1024,2), blk, 0, stream,
                     bufA, wp, proj_b, x, (void*)out_f);                               // x1 -> d_out fp32

  // ffn phase
  hipLaunchKernelGGL(ln_kernel, dim3(1024), blk, 0, stream, out_f, ln2_w, ln2_b, bufA);
  for (int bp = 0; bp < 4; bp++){
    const unsigned short* xin = bufA + (size_t)bp*32768*128;
    float* outp = out_f + (size_t)bp*2*128*16384;
    hipLaunchKernelGGL((gemm_kernel<704,128,2,false,false,true>), dim3(128,11), blk, 0, stream,
                       xin, wfi, (const float*)nullptr, (const float*)nullptr, (void*)bufB);
    hipLaunchKernelGGL(ffn_dwg_kernel, dim3(1360), blk, 0, stream, bufB, ffn_dw_w, gbuf);
    hipLaunchKernelGGL(ffn_out_gemm, dim3(256,2), blk, 0, stream, gbuf, wfo, outp);
  }
}

// Round 7
// 670.483 us; speedup vs baseline: 1.2580x; 1.0221x over previous
//
#include <hip/hip_runtime.h>

#define LSP 16384            // H*W
#define NBATCH 8
#define NPOS (NBATCH*LSP)    // 131072
#define NHID 340
#define ATT_SCALE 0.35355339059327373f

// ---- workspace layout (bytes) ----
#define OFF_A        0ULL          // 32MB: xn_t -> resg_t -> xn2_t (in-place by proj_ln)
#define OFF_B        33554432ULL   // 67MB: kv -> qo ; FFN: pbuf2 (46MB)
#define OFF_C        100663296ULL  // 32MB: lepe ; FFN: gbuf (22.3MB)
#define OFF_STATS    134381568ULL  // 40KB
#define OFF_SIN      134422528ULL  // 512KB
#define OFF_COS      134946816ULL  // 512KB
#define OFF_WQ       135471104ULL  // 512x128 bf16
#define OFF_WQO      135602176ULL  // 256x128 bf16
#define OFF_QOB      135667712ULL  // 256 f32
#define OFF_WP       135668736ULL  // 128x128 bf16
#define OFF_WFI      135701504ULL  // 704x128 bf16
#define OFF_WFO      135881728ULL  // 128x352 bf16
#define WS_NEEDED    135971840ULL
// NOTE: attn partials (1024*80*4 = 327KB) live in d_out during the attention
// phase (d_out is dead until proj_ln writes it). Old OFF_GT2 slot overlapped
// bufB's kv tail -> latent race, removed.

typedef __attribute__((ext_vector_type(8))) short short8;
typedef __attribute__((ext_vector_type(4))) float floatx4;

__device__ __forceinline__ float bf2f(unsigned short u){
  union { unsigned int i; float f; } c; c.i = ((unsigned int)u) << 16; return c.f;
}
__device__ __forceinline__ unsigned short f2bf(float f){
  union { float f; unsigned int i; } c; c.f = f;
  unsigned int r = c.i + 0x7fffu + ((c.i >> 16) & 1u);
  return (unsigned short)(r >> 16);
}

// read 12 bf16 (4B-aligned) from LDS -> fp32
__device__ __forceinline__ void load_row12(const unsigned short* p, float* r){
  const unsigned int* q = (const unsigned int*)p;
  #pragma unroll
  for (int i=0;i<6;i++){
    unsigned int u = q[i];
    r[2*i]   = bf2f((unsigned short)(u & 0xffffu));
    r[2*i+1] = bf2f((unsigned short)(u >> 16));
  }
}

// read 10 bf16 (1 edge + aligned 8 + 1 edge) from LDS -> fp32
__device__ __forceinline__ void load_row10(const unsigned short* base, float* r){
  short8 B = *(const short8*)(base + 8);
  r[0] = bf2f(base[7]);
  #pragma unroll
  for (int i=0;i<8;i++) r[1+i] = bf2f((unsigned short)B[i]);
  r[9] = bf2f(base[16]);
}

// ------------------- RoPE tables: sin/cos[l][8] fp32 -------------------
__global__ void rope_kernel(float* __restrict__ sin_t, float* __restrict__ cos_t){
  int l = blockIdx.x*256 + threadIdx.x;
  if (l >= LSP) return;
  int h = l >> 7, w = l & 127;
  float s0 = sinf((float)h),        c0 = cosf((float)h);
  float s1 = sinf((float)h*1e-4f),  c1 = cosf((float)h*1e-4f);
  float s2 = sinf((float)w),        c2 = cosf((float)w);
  float s3 = sinf((float)w*1e-4f),  c3 = cosf((float)w*1e-4f);
  float* sp = sin_t + l*8; float* cp = cos_t + l*8;
  sp[0]=s0; sp[1]=s0; sp[2]=s1; sp[3]=s1; sp[4]=s2; sp[5]=s2; sp[6]=s3; sp[7]=s3;
  cp[0]=c0; cp[1]=c0; cp[2]=c1; cp[3]=c1; cp[4]=c2; cp[5]=c2; cp[6]=c3; cp[7]=c3;
}

// ------------------- weight fp32 -> padded bf16 -------------------
__global__ void wconv_kernel(const float* __restrict__ src, unsigned short* __restrict__ dst,
                             int O, int K, int OP, int KP){
  int i = blockIdx.x*256 + threadIdx.x;
  if (i >= OP*KP) return;
  int o = i / KP, k = i - o*KP;
  float v = (o < O && k < K) ? src[o*K + k] : 0.f;
  dst[i] = f2bf(v);
}

// ------------------- q/o weight+bias reorder: rows [0..128)+[384..512) -------------------
__global__ void reorder_qo_kernel(const float* __restrict__ qkvo_w, const float* __restrict__ qkvo_b,
                                  unsigned short* __restrict__ wqo, float* __restrict__ qo_bias){
  int i = blockIdx.x*256 + threadIdx.x;
  if (i < 256){
    qo_bias[i] = qkvo_b[(i < 128) ? i : i + 256];
  }
  if (i >= 256*128) return;
  int o = i >> 7, k = i & 127;
  int srow = (o < 128) ? o : o + 256;
  wqo[i] = f2bf(qkvo_w[srow*128 + k]);
}

// ------------------- LayerNorm over 128 channels; out position-major bf16 -------------------
__launch_bounds__(256)
__global__ void ln_kernel(const float* __restrict__ x, const float* __restrict__ gam,
                          const float* __restrict__ bet, unsigned short* __restrict__ out_t){
  __shared__ float ps[2][128], pq[2][128];
  __shared__ unsigned short tile[128*132];
  int t = threadIdx.x;
  int pidx = t & 127;
  int half = t >> 7;
  int p0 = blockIdx.x*128;
  int p = p0 + pidx;
  int b = p >> 14, l = p & 16383;
  const float* xb = x + (((size_t)b) << 21) + (((size_t)(half*64)) << 14) + l;
  float vals[64];
  float s = 0.f, sq = 0.f;
  #pragma unroll
  for (int c = 0; c < 64; c++){
    float v = xb[(size_t)c << 14];
    vals[c] = v;
    s += v; sq += v*v;
  }
  ps[half][pidx] = s; pq[half][pidx] = sq;
  __syncthreads();
  float S = ps[0][pidx] + ps[1][pidx];
  float Q = pq[0][pidx] + pq[1][pidx];
  float mu = S * 0.0078125f;
  float var = Q * 0.0078125f - mu*mu;
  float rstd = rsqrtf(var + 1e-5f);
  #pragma unroll
  for (int c0 = 0; c0 < 64; c0 += 8){
    short8 vv;
    #pragma unroll
    for (int i = 0; i < 8; i++){
      int c = c0 + i;
      int cg = half*64 + c;
      vv[i] = (short)f2bf((vals[c] - mu) * rstd * gam[cg] + bet[cg]);
    }
    *(short8*)&tile[pidx*132 + half*64 + c0] = vv;
  }
  __syncthreads();
  unsigned short* og = out_t + ((size_t)p0 << 7);
  #pragma unroll
  for (int it = 0; it < 8; it++){
    int idx = it*256 + t;
    int row = idx >> 4;
    int col = (idx & 15) * 8;
    *(short8*)&og[(row << 7) + col] = *(const short8*)&tile[row*132 + col];
  }
}

// ------------------- MFMA GEMM: out[b][o][l] = sum_k W[o][k]*in_t[b*L+l][k] -------------------
// NL consecutive 128-position tiles per block. oc chunk from blockIdx.y.
template<int OPAD, int KPAD, int NL, bool HASBIAS, bool RESID, bool OUTBF16>
__launch_bounds__(256)
__global__ void gemm_kernel(const unsigned short* __restrict__ in_t,
                            const unsigned short* __restrict__ wb,
                            const float* __restrict__ bias,
                            const float* __restrict__ resid,
                            void* __restrict__ outp){
  constexpr int KS = KPAD / 32;
  constexpr int SBYTES = OUTBF16 ? (64*136*2) : (64*132*4);
  __shared__ __align__(16) unsigned char smem[SBYTES];
  const int t = threadIdx.x;
  const int lane = t & 63;
  const int wv = t >> 6;
  const int lane15 = lane & 15;
  const int quad = lane >> 4;
  const int oc = blockIdx.y;

  #pragma unroll 1
  for (int tl = 0; tl < NL; tl++){
    const int l0 = (blockIdx.x * NL + tl) * 128;
    const int b = l0 >> 14;
    const int lloc0 = l0 & 16383;

    short8 fb[2][KS];
    {
      const unsigned short* base = in_t + ((size_t)(l0 + wv*32 + lane15)) * KPAD + quad*8;
      #pragma unroll
      for (int nt = 0; nt < 2; nt++){
        #pragma unroll
        for (int ks = 0; ks < KS; ks++)
          fb[nt][ks] = *(const short8*)(base + (size_t)nt*16*KPAD + ks*32);
      }
    }
    floatx4 acc[4][2];
    #pragma unroll
    for (int mt=0; mt<4; mt++)
      #pragma unroll
      for (int nt=0; nt<2; nt++)
        acc[mt][nt] = (floatx4){0.f,0.f,0.f,0.f};
    #pragma unroll
    for (int ks = 0; ks < KS; ks++){
      short8 fa[4];
      const unsigned short* wrow = wb + ((size_t)(oc*64 + lane15)) * KPAD + ks*32 + quad*8;
      #pragma unroll
      for (int mt=0; mt<4; mt++)
        fa[mt] = *(const short8*)(wrow + (size_t)mt*16*KPAD);
      #pragma unroll
      for (int mt=0; mt<4; mt++)
        #pragma unroll
        for (int nt=0; nt<2; nt++)
          acc[mt][nt] = __builtin_amdgcn_mfma_f32_16x16x32_bf16(fa[mt], fb[nt][ks], acc[mt][nt], 0, 0, 0);
    }

    if (tl) __syncthreads();   // protect smem reuse across tiles

    if (OUTBF16){
      unsigned short* cs = (unsigned short*)smem;
      #pragma unroll
      for (int mt=0; mt<4; mt++)
        #pragma unroll
        for (int nt=0; nt<2; nt++)
          #pragma unroll
          for (int r=0; r<4; r++){
            const int o = mt*16 + quad*4 + r;
            float v = acc[mt][nt][r];
            if (HASBIAS) v += bias[oc*64 + o];
            cs[o*136 + wv*32 + nt*16 + lane15] = f2bf(v);
          }
      __syncthreads();
      unsigned short* og = (unsigned short*)outp;
      #pragma unroll
      for (int j=0; j<4; j++){
        int idx = j*256 + t;
        int row = idx >> 4;
        int col = (idx & 15) * 8;
        short8 v = *(const short8*)&cs[row*136 + col];
        *(short8*)&og[(((size_t)(b*OPAD + oc*64 + row)) << 14) + lloc0 + col] = v;
      }
    } else {
      float* cf = (float*)smem;
      #pragma unroll
      for (int mt=0; mt<4; mt++)
        #pragma unroll
        for (int nt=0; nt<2; nt++)
          #pragma unroll
          for (int r=0; r<4; r++){
            const int o = mt*16 + quad*4 + r;
            float v = acc[mt][nt][r];
            if (HASBIAS) v += bias[oc*64 + o];
            cf[o*132 + wv*32 + nt*16 + lane15] = v;
          }
      __syncthreads();
      float* og = (float*)outp;
      #pragma unroll
      for (int j=0; j<8; j++){
        int idx = j*256 + t;
        int row = idx >> 5;
        int col = (idx & 31) * 4;
        floatx4 v = *(const floatx4*)&cf[row*132 + col];
        if (RESID){
          floatx4 rv = *(const floatx4*)(resid + (((size_t)(b*128 + oc*64 + row)) << 14) + lloc0 + col);
          v += rv;
        }
        *(floatx4*)&og[(((size_t)(b*OPAD + oc*64 + row)) << 14) + lloc0 + col] = v;
      }
    }
  }
}

// ------------------- proj GEMM + residual + LayerNorm2 fused -------------------
// in_t: resg bf16 position-major. Computes x1 = W*in + b + x (fp32 -> x1out),
// then LN over the block's own 128-channel tile -> xn2 bf16 position-major,
// written IN PLACE over in_t rows (safe: full input tile register-loaded first).
__launch_bounds__(256)
__global__ void proj_ln_kernel(const unsigned short* __restrict__ in_t,
                               const unsigned short* __restrict__ wb,
                               const float* __restrict__ bias,
                               const float* __restrict__ resid,
                               const float* __restrict__ gam,
                               const float* __restrict__ bet,
                               float* __restrict__ x1out,
                               unsigned short* __restrict__ xn2out){
  __shared__ __align__(16) unsigned char smem[128*132*4];   // cf fp32 -> reused as tb ushort[128][136]
  __shared__ float ssum[8][128], qsum[8][128];
  __shared__ float muA[128], rsA[128];
  const int t = threadIdx.x;
  const int l0 = blockIdx.x * 128;
  const int b = l0 >> 14;
  const int lloc0 = l0 & 16383;
  const int lane = t & 63;
  const int wv = t >> 6;
  const int lane15 = lane & 15;
  const int quad = lane >> 4;

  // full input tile -> registers (enables in-place xn2 write later)
  short8 fb[2][4];
  {
    const unsigned short* base = in_t + ((size_t)(l0 + wv*32 + lane15)) * 128 + quad*8;
    #pragma unroll
    for (int nt = 0; nt < 2; nt++)
      #pragma unroll
      for (int ks = 0; ks < 4; ks++)
        fb[nt][ks] = *(const short8*)(base + (size_t)nt*16*128 + ks*32);
  }

  float* cf = (float*)smem;
  #pragma unroll 1
  for (int oc = 0; oc < 2; oc++){
    floatx4 acc[4][2];
    #pragma unroll
    for (int mt=0; mt<4; mt++)
      #pragma unroll
      for (int nt=0; nt<2; nt++)
        acc[mt][nt] = (floatx4){0.f,0.f,0.f,0.f};
    #pragma unroll
    for (int ks = 0; ks < 4; ks++){
      short8 fa[4];
      const unsigned short* wrow = wb + ((size_t)(oc*64 + lane15)) * 128 + ks*32 + quad*8;
      #pragma unroll
      for (int mt=0; mt<4; mt++)
        fa[mt] = *(const short8*)(wrow + (size_t)mt*16*128);
      #pragma unroll
      for (int mt=0; mt<4; mt++)
        #pragma unroll
        for (int nt=0; nt<2; nt++)
          acc[mt][nt] = __builtin_amdgcn_mfma_f32_16x16x32_bf16(fa[mt], fb[nt][ks], acc[mt][nt], 0, 0, 0);
    }
    #pragma unroll
    for (int mt=0; mt<4; mt++)
      #pragma unroll
      for (int nt=0; nt<2; nt++)
        #pragma unroll
        for (int r=0; r<4; r++){
          const int o = oc*64 + mt*16 + quad*4 + r;
          cf[o*132 + wv*32 + nt*16 + lane15] = acc[mt][nt][r] + bias[o];
        }
  }
  __syncthreads();

  // pass A: x1 = cf + resid -> global; keep in regs; per-position partial stats
  const int colg = (t & 31) * 4;
  const int rsub = t >> 5;             // 0..7
  floatx4 x1r[16];
  floatx4 s4 = (floatx4){0.f,0.f,0.f,0.f};
  floatx4 q4 = (floatx4){0.f,0.f,0.f,0.f};
  #pragma unroll
  for (int j=0; j<16; j++){
    int row = j*8 + rsub;              // channel 0..127
    floatx4 v = *(const floatx4*)&cf[row*132 + colg];
    floatx4 rv = *(const floatx4*)&resid[(((size_t)(b*128 + row)) << 14) + lloc0 + colg];
    v += rv;
    *(floatx4*)&x1out[(((size_t)(b*128 + row)) << 14) + lloc0 + colg] = v;
    x1r[j] = v;
    s4 += v;
    q4 += v*v;
  }
  #pragma unroll
  for (int e=0; e<4; e++){
    ssum[rsub][colg+e] = s4[e];
    qsum[rsub][colg+e] = q4[e];
  }
  __syncthreads();
  if (t < 128){
    float S = 0.f, Q = 0.f;
    #pragma unroll
    for (int g=0; g<8; g++){ S += ssum[g][t]; Q += qsum[g][t]; }
    float mu = S * 0.0078125f;
    float var = Q * 0.0078125f - mu*mu;
    muA[t] = mu;
    rsA[t] = rsqrtf(var + 1e-5f);
  }
  __syncthreads();

  // pass B: xn2 bf16 into transposed LDS tile (reuses cf memory; cf fully consumed)
  unsigned short* tb = (unsigned short*)smem;
  #pragma unroll
  for (int j=0; j<16; j++){
    int row = j*8 + rsub;
    float ga = gam[row], be = bet[row];
    #pragma unroll
    for (int e=0; e<4; e++){
      int p = colg + e;
      float xv = (x1r[j][e] - muA[p]) * rsA[p] * ga + be;
      tb[p*136 + row] = f2bf(xv);
    }
  }
  __syncthreads();
  unsigned short* og = xn2out + ((size_t)l0 << 7);
  #pragma unroll
  for (int it = 0; it < 8; it++){
    int idx = it*256 + t;
    int prow = idx >> 4;
    int ccol = (idx & 15) * 8;
    *(short8*)&og[(prow << 7) + ccol] = *(const short8*)&tb[prow*136 + ccol];
  }
}

// ------------------- FFN-out GEMM with fused transpose of g -------------------
__launch_bounds__(256)
__global__ void ffn_out_gemm(const unsigned short* __restrict__ g,
                             const unsigned short* __restrict__ wb,
                             float* __restrict__ outp){
  __shared__ __align__(16) unsigned char smem[64*132*4];   // union: 2x 10240B stage | cf
  const int t = threadIdx.x;
  const int l0 = blockIdx.x * 128;
  const int b = l0 >> 14;
  const int lloc0 = l0 & 16383;
  const int lane = t & 63;
  const int wv = t >> 6;
  const int lane15 = lane & 15;
  const int quad = lane >> 4;
  const int oc = blockIdx.y;
  const int jj = t >> 3;      // 0..31 : j within slice
  const int c8 = t & 7;       // chunk base

  auto stage = [&](int s, int bufi){
    unsigned short* buf = (unsigned short*)(smem + bufi*10240);
    int j = s*32 + jj;
    const unsigned short* src = g + (((size_t)(b*NHID + j)) << 14) + lloc0;
    #pragma unroll
    for (int cc=0; cc<2; cc++){
      int c = c8 + cc*8;
      short8 v = (short8){0,0,0,0,0,0,0,0};
      if (j < NHID) v = *(const short8*)(src + c*8);
      #pragma unroll
      for (int e=0; e<8; e++)
        buf[(c*8+e)*40 + jj] = (unsigned short)v[e];
    }
  };

  floatx4 acc[4][2];
  #pragma unroll
  for (int mt=0; mt<4; mt++)
    #pragma unroll
    for (int nt=0; nt<2; nt++)
      acc[mt][nt] = (floatx4){0.f,0.f,0.f,0.f};

  stage(0, 0);
  #pragma unroll 1
  for (int s=0; s<11; s++){
    __syncthreads();
    if (s < 10) stage(s+1, (s+1)&1);
    const unsigned short* cur = (const unsigned short*)(smem + (s&1)*10240);
    short8 fbv[2];
    #pragma unroll
    for (int nt=0; nt<2; nt++)
      fbv[nt] = *(const short8*)&cur[(wv*32 + nt*16 + lane15)*40 + quad*8];
    const unsigned short* wrow = wb + ((size_t)(oc*64 + lane15))*352 + s*32 + quad*8;
    short8 fa[4];
    #pragma unroll
    for (int mt=0; mt<4; mt++)
      fa[mt] = *(const short8*)(wrow + (size_t)mt*16*352);
    #pragma unroll
    for (int mt=0; mt<4; mt++)
      #pragma unroll
      for (int nt=0; nt<2; nt++)
        acc[mt][nt] = __builtin_amdgcn_mfma_f32_16x16x32_bf16(fa[mt], fbv[nt], acc[mt][nt], 0, 0, 0);
  }
  __syncthreads();
  float* cf = (float*)smem;
  #pragma unroll
  for (int mt=0; mt<4; mt++)
    #pragma unroll
    for (int nt=0; nt<2; nt++)
      #pragma unroll
      for (int r=0; r<4; r++){
        const int o = mt*16 + quad*4 + r;
        cf[o*132 + wv*32 + nt*16 + lane15] = acc[mt][nt][r];
      }
  __syncthreads();
  #pragma unroll
  for (int j=0; j<8; j++){
    int idx = j*256 + t;
    int row = idx >> 5;
    int col = (idx & 31) * 4;
    floatx4 v = *(const floatx4*)&cf[row*132 + col];
    size_t oi = (((size_t)(b*128 + oc*64 + row)) << 14) + lloc0 + col;
    floatx4 rv = *(const floatx4*)&outp[oi];
    v += rv;
    *(floatx4*)&outp[oi] = v;
  }
}

// ------------------- lepe: depthwise 5x5, LDS-staged sliding window -------------------
__launch_bounds__(256)
__global__ void lepe_kernel(const unsigned short* __restrict__ kv,
                            const float* __restrict__ lw, const float* __restrict__ lb,
                            unsigned short* __restrict__ lepe){
  __shared__ unsigned short lds[132*136];     // rows h+2 (0..131), cols w+2 (0..131), stride 136
  int bc = blockIdx.x;                        // b*128 + c
  int b = bc >> 7, c = bc & 127;
  int t = threadIdx.x;
  #pragma unroll
  for (int i = t; i < 132*136/8; i += 256)
    *(short8*)(lds + i*8) = (short8){0,0,0,0,0,0,0,0};
  __syncthreads();
  int band = t >> 4, wi = t & 15, w0 = wi*8;
  const unsigned short* vp = kv + (((size_t)(b*256 + 128 + c)) << 14);
  {
    #pragma unroll
    for (int it = 0; it < 8; it++){
      int hh = band + it*16;
      short8 v = *(const short8*)(vp + (hh<<7) + w0);
      unsigned int* dst = (unsigned int*)&lds[(hh+2)*136 + w0 + 2];
      union { short8 s; unsigned int u[4]; } cv; cv.s = v;
      #pragma unroll
      for (int q=0;q<4;q++) dst[q] = cv.u[q];
    }
  }
  float wt[25];
  #pragma unroll
  for (int i=0;i<25;i++) wt[i] = lw[c*25 + i];
  float bias = lb[c];
  __syncthreads();
  int h0 = band*8;
  float win[5][12];
  #pragma unroll
  for (int m=0;m<4;m++) load_row12(&lds[(h0+m)*136 + w0], win[m]);
  unsigned short* outp = lepe + ((size_t)bc << 14);
  #pragma unroll
  for (int s=0;s<8;s++){
    load_row12(&lds[(h0+4+s)*136 + w0], win[(4+s)%5]);
    short8 ov;
    #pragma unroll
    for (int j=0;j<8;j++){
      float acc = bias;
      #pragma unroll
      for (int dy=0;dy<5;dy++){
        const float* r = win[(s+dy)%5];
        #pragma unroll
        for (int dx=0;dx<5;dx++) acc += wt[dy*5+dx]*r[j+dx];
      }
      ov[j] = (short)f2bf(acc);
    }
    *(short8*)(outp + (h0+s)*128 + w0) = ov;
  }
}

// ------------------- attention reduction partials per (b,head,chunk of 2048) -------------------
__launch_bounds__(256)
__global__ void attn_partial(const unsigned short* __restrict__ kv,
                             const float* __restrict__ sin_t, const float* __restrict__ cos_t,
                             float* __restrict__ partials){
  int pair = blockIdx.x >> 3;
  int chunk = blockIdx.x & 7;
  int b = pair >> 4, hd = pair & 15;
  const unsigned short* kb = kv + (((size_t)(b*256 + hd*8)) << 14);
  const unsigned short* vb = kb + ((size_t)128 << 14);
  float red[80];
  #pragma unroll
  for (int i=0;i<80;i++) red[i]=0.f;
  int l0 = chunk*2048;
  for (int li=0; li<8; li++){
    int l = l0 + li*256 + threadIdx.x;
    float k[8], v[8], ks[8];
    #pragma unroll
    for (int e=0;e<8;e++){
      float t = bf2f(kb[((size_t)e<<14)+l]);
      k[e] = t>0.f ? t+1.f : __expf(t);
      v[e] = bf2f(vb[((size_t)e<<14)+l]);
      red[e]   += k[e];
      red[8+e] += v[e];
    }
    const float* sp = sin_t + l*8;
    const float* cp = cos_t + l*8;
    #pragma unroll
    for (int j=0;j<4;j++){
      float x1=k[2*j], x2=k[2*j+1];
      ks[2*j]   = x1*cp[2*j]   - x2*sp[2*j];
      ks[2*j+1] = x2*cp[2*j+1] + x1*sp[2*j+1];
    }
    #pragma unroll
    for (int d=0; d<8; d++)
      #pragma unroll
      for (int e=0;e<8;e++)
        red[16 + d*8 + e] += ks[d]*v[e];
  }
  #pragma unroll
  for (int off=32; off>0; off>>=1){
    #pragma unroll
    for (int i=0;i<80;i++)
      red[i] += __shfl_down(red[i], off);
  }
  __shared__ float lds[4][80];
  int lane = threadIdx.x & 63, wv = threadIdx.x >> 6;
  if (lane==0){
    #pragma unroll
    for (int i=0;i<80;i++) lds[wv][i] = red[i];
  }
  __syncthreads();
  if (threadIdx.x < 80){
    float s = lds[0][threadIdx.x]+lds[1][threadIdx.x]+lds[2][threadIdx.x]+lds[3][threadIdx.x];
    partials[(size_t)blockIdx.x*80 + threadIdx.x] = s;
  }
}

__global__ void attn_combine(const float* __restrict__ partials, float* __restrict__ stats){
  int i = blockIdx.x*256 + threadIdx.x;
  if (i >= 128*80) return;
  int pair = i / 80, idx = i - pair*80;
  float s = 0.f;
  #pragma unroll
  for (int cc=0; cc<8; cc++)
    s += partials[(size_t)(pair*8+cc)*80+idx];
  s *= (idx < 16) ? (1.f/LSP) : (ATT_SCALE/LSP);
  stats[i] = s;
}

// ------------------- attention apply + lepe add + o-gate; out position-major bf16 -------------------
__launch_bounds__(256)
__global__ void attn_apply_kernel(const unsigned short* __restrict__ qo,
                                  const unsigned short* __restrict__ lepe,
                                  const float* __restrict__ stats,
                                  const float* __restrict__ sin_t,
                                  const float* __restrict__ cos_t,
                                  unsigned short* __restrict__ resg_t){
  __shared__ float st[8*80];
  __shared__ unsigned short tile[256*66];
  int p0 = blockIdx.x * 256;
  int b = p0 >> 14;
  int hg = blockIdx.y;
  for (int i = threadIdx.x; i < 8*80; i += 256) st[i] = stats[b*16*80 + hg*8*80 + i];
  __syncthreads();
  int t = threadIdx.x;
  int p = p0 + t;
  int l = p & 16383;
  float sv[8], cv[8];
  {
    const float* sp = sin_t + l*8;
    const float* cp = cos_t + l*8;
    #pragma unroll
    for (int i=0;i<8;i++){ sv[i]=sp[i]; cv[i]=cp[i]; }
  }
  #pragma unroll 1
  for (int hd8=0; hd8<8; hd8++){
    int hd = hg*8 + hd8;
    const float* S = st + hd8*80;
    const unsigned short* qb = qo + (((size_t)(b*256 + hd*8)) << 14) + l;
    const unsigned short* ob = qb + ((size_t)128 << 14);
    const unsigned short* lb = lepe + (((size_t)(b*128 + hd*8)) << 14) + l;
    float q[8];
    #pragma unroll
    for (int e=0;e<8;e++){
      float tq = bf2f(qb[(size_t)e<<14]);
      q[e] = tq > 0.f ? tq + 1.f : __expf(tq);
    }
    float z = 0.f;
    #pragma unroll
    for (int e=0;e<8;e++) z += q[e]*S[e];
    z *= ATT_SCALE;
    float qs[8];
    #pragma unroll
    for (int jj=0;jj<4;jj++){
      float x1=q[2*jj], x2=q[2*jj+1];
      qs[2*jj]   = x1*cv[2*jj]   - x2*sv[2*jj];
      qs[2*jj+1] = x2*cv[2*jj+1] + x1*sv[2*jj+1];
    }
    float fac = 1.f + 1.f/(z + 1e-6f);
    short8 vv;
    #pragma unroll
    for (int e=0;e<8;e++){
      float r = 0.f;
      #pragma unroll
      for (int d=0; d<8; d++) r += qs[d]*S[16 + d*8 + e];
      r = r*fac - z*S[8+e];
      float val = (r + bf2f(lb[(size_t)e<<14])) * bf2f(ob[(size_t)e<<14]);
      vv[e] = (short)f2bf(val);
    }
    *(short8*)&tile[t*66 + hd8*8] = vv;
  }
  __syncthreads();
  unsigned short* og = resg_t + ((size_t)p0 << 7) + hg*64;
  #pragma unroll
  for (int it = 0; it < 8; it++){
    int idx = it*256 + t;
    int row = idx >> 3;
    int col = (idx & 7) * 8;
    *(short8*)&og[(row << 7) + col] = *(const short8*)&tile[row*66 + col];
  }
}

// ------------------- ffn dw3x3 x2 + exact gelu gate, LDS-staged; plane-major out -------------------
#define FPL (66*144)
__launch_bounds__(256)
__global__ void ffn_dwg_kernel(const unsigned short* __restrict__ p,
                               const float* __restrict__ dw,
                               unsigned short* __restrict__ g){
  __shared__ unsigned short lds[2*FPL];     // 2 planes, rows 66 (h-halo), cols w+8 (0..143)
  int bid = blockIdx.x;
  int jc = bid % NHID;
  int rest = bid / NHID;
  int bb = rest & 1;
  int half = rest >> 1;
  int t = threadIdx.x;
  #pragma unroll
  for (int i = t; i < 2*FPL/8; i += 256)
    *(short8*)(lds + i*8) = (short8){0,0,0,0,0,0,0,0};
  __syncthreads();
  int band = t >> 4, wi = t & 15, w0 = wi*8;
  #pragma unroll
  for (int pl=0; pl<2; pl++){
    const unsigned short* src = p + (((size_t)(bb*704 + jc + pl*NHID)) << 14);
    #pragma unroll
    for (int it=0; it<5; it++){
      int r_idx = it*16 + band;
      if (r_idx < 66){
        int h = half*64 - 1 + r_idx;
        if ((unsigned)h < 128u){
          short8 v = *(const short8*)(src + (h<<7) + w0);
          *(short8*)(&lds[pl*FPL + r_idx*144 + w0 + 8]) = v;
        }
      }
    }
  }
  float w1[9], w2[9];
  #pragma unroll
  for (int i=0;i<9;i++){ w1[i] = dw[jc*9 + i]; w2[i] = dw[(jc+NHID)*9 + i]; }
  __syncthreads();
  int rb = band*4;
  float r1[3][10], r2[3][10];
  #pragma unroll
  for (int m=0;m<2;m++){
    load_row10(&lds[(rb+m)*144 + w0], r1[m]);
    load_row10(&lds[FPL + (rb+m)*144 + w0], r2[m]);
  }
  unsigned short* outp = g + (((size_t)(bb*NHID + jc)) << 14);
  #pragma unroll
  for (int s=0;s<4;s++){
    load_row10(&lds[(rb+2+s)*144 + w0], r1[(2+s)%3]);
    load_row10(&lds[FPL + (rb+2+s)*144 + w0], r2[(2+s)%3]);
    int h = half*64 + rb + s;
    short8 ov;
    #pragma unroll
    for (int j=0;j<8;j++){
      float c1 = 0.f, c2 = 0.f;
      #pragma unroll
      for (int dy=0;dy<3;dy++){
        const float* a = r1[(s+dy)%3];
        const float* bpt = r2[(s+dy)%3];
        #pragma unroll
        for (int dx=0;dx<3;dx++){
          c1 += w1[dy*3+dx]*a[j+dx];
          c2 += w2[dy*3+dx]*bpt[j+dx];
        }
      }
      float ge = 0.5f*c1*(1.f + erff(c1*0.70710678118654752f));
      ov[j] = (short)f2bf(ge*c2);
    }
    *(short8*)(outp + h*128 + w0) = ov;
  }
}

extern "C" void kernel_launch(void* const* d_in, const int* in_sizes, int n_in,
                              void* d_out, int out_size, void* d_ws, size_t ws_size,
                              hipStream_t stream){
  (void)in_sizes; (void)n_in; (void)out_size;
  if (ws_size < WS_NEEDED) return;
  const float* x        = (const float*)d_in[0];
  const float* ln1_w    = (const float*)d_in[1];
  const float* ln1_b    = (const float*)d_in[2];
  const float* qkvo_w   = (const float*)d_in[3];
  const float* qkvo_b   = (const float*)d_in[4];
  const float* lepe_w   = (const float*)d_in[5];
  const float* lepe_b   = (const float*)d_in[6];
  const float* proj_w   = (const float*)d_in[7];
  const float* proj_b   = (const float*)d_in[8];
  const float* ln2_w    = (const float*)d_in[9];
  const float* ln2_b    = (const float*)d_in[10];
  const float* ffn_in_w = (const float*)d_in[11];
  const float* ffn_dw_w = (const float*)d_in[12];
  const float* ffn_out_w= (const float*)d_in[13];

  char* ws = (char*)d_ws;
  unsigned short* bufA   = (unsigned short*)(ws + OFF_A);
  unsigned short* bufB   = (unsigned short*)(ws + OFF_B);
  unsigned short* lepe   = (unsigned short*)(ws + OFF_C);
  unsigned short* gbuf   = (unsigned short*)(ws + OFF_C);   // reuses lepe region in FFN phase
  float* stats           = (float*)(ws + OFF_STATS);
  float* sin_t           = (float*)(ws + OFF_SIN);
  float* cos_t           = (float*)(ws + OFF_COS);
  unsigned short* wq     = (unsigned short*)(ws + OFF_WQ);
  unsigned short* wqo    = (unsigned short*)(ws + OFF_WQO);
  float* qo_bias         = (float*)(ws + OFF_QOB);
  unsigned short* wp     = (unsigned short*)(ws + OFF_WP);
  unsigned short* wfi    = (unsigned short*)(ws + OFF_WFI);
  unsigned short* wfo    = (unsigned short*)(ws + OFF_WFO);
  const unsigned short* wkv = wq + 128*128;

  float* out_f = (float*)d_out;
  float* partials = out_f;       // d_out is dead until proj_ln -> safe attn-phase scratch
  dim3 blk(256);
  hipLaunchKernelGGL(rope_kernel, dim3(64), blk, 0, stream, sin_t, cos_t);
  hipLaunchKernelGGL(wconv_kernel, dim3((512*128)/256), blk, 0, stream, qkvo_w, wq, 512,128,512,128);
  hipLaunchKernelGGL(reorder_qo_kernel, dim3((256*128)/256), blk, 0, stream, qkvo_w, qkvo_b, wqo, qo_bias);
  hipLaunchKernelGGL(wconv_kernel, dim3((128*128)/256), blk, 0, stream, proj_w, wp, 128,128,128,128);
  hipLaunchKernelGGL(wconv_kernel, dim3((704*128)/256), blk, 0, stream, ffn_in_w, wfi, 680,128,704,128);
  hipLaunchKernelGGL(wconv_kernel, dim3((128*352)/256), blk, 0, stream, ffn_out_w, wfo, 128,340,128,352);

  // attention phase
  hipLaunchKernelGGL(ln_kernel, dim3(1024), blk, 0, stream, x, ln1_w, ln1_b, bufA);
  hipLaunchKernelGGL((gemm_kernel<256,128,4,true,false,true>), dim3(256,4), blk, 0, stream,
                     bufA, wkv, qkvo_b + 128, (const float*)nullptr, (void*)bufB);     // kv
  hipLaunchKernelGGL(lepe_kernel, dim3(1024), blk, 0, stream, bufB, lepe_w, lepe_b, lepe);
  hipLaunchKernelGGL(attn_partial, dim3(1024), blk, 0, stream, bufB, sin_t, cos_t, partials);
  hipLaunchKernelGGL(attn_combine, dim3(40), blk, 0, stream, partials, stats);
  hipLaunchKernelGGL((gemm_kernel<256,128,4,true,false,true>), dim3(256,4), blk, 0, stream,
                     bufA, wqo, qo_bias, (const float*)nullptr, (void*)bufB);          // qo
  hipLaunchKernelGGL(attn_apply_kernel, dim3(512,2), blk, 0, stream, bufB, lepe, stats, sin_t, cos_t, bufA);
  hipLaunchKernelGGL(proj_ln_kernel, dim3(1024), blk, 0, stream,
                     bufA, wp, proj_b, x, ln2_w, ln2_b, out_f, bufA);                  // x1 -> d_out, xn2 -> bufA

  // ffn phase
  for (int bp = 0; bp < 4; bp++){
    const unsigned short* xin = bufA + (size_t)bp*32768*128;
    float* outp = out_f + (size_t)bp*2*128*16384;
    hipLaunchKernelGGL((gemm_kernel<704,128,2,false,false,true>), dim3(128,11), blk, 0, stream,
                       xin, wfi, (const float*)nullptr, (const float*)nullptr, (void*)bufB);
    hipLaunchKernelGGL(ffn_dwg_kernel, dim3(1360), blk, 0, stream, bufB, ffn_dw_w, gbuf);
    hipLaunchKernelGGL(ffn_out_gemm, dim3(256,2), blk, 0, stream, gbuf, wfo, outp);
  }
}

// Round 9
// 662.359 us; speedup vs baseline: 1.2734x; 1.0123x over previous
//
#include <hip/hip_runtime.h>

#define LSP 16384            // H*W
#define NBATCH 8
#define NPOS (NBATCH*LSP)    // 131072
#define NHID 340
#define ATT_SCALE 0.35355339059327373f

// ---- workspace layout (bytes) ----
#define OFF_A        0ULL          // 32MB: xn_t -> resg_t -> xn2_t (in-place by proj_ln)
#define OFF_B        33554432ULL   // 67MB: kv -> qo ; FFN: pbuf2 (46MB)
#define OFF_C        100663296ULL  // 32MB: lepe ; FFN: gbuf (22.3MB)
#define OFF_STATS    134381568ULL  // 40KB
#define OFF_SIN      134422528ULL  // 512KB
#define OFF_COS      134946816ULL  // 512KB
#define OFF_WQ       135471104ULL  // 512x128 bf16
#define OFF_WQO      135602176ULL  // 256x128 bf16
#define OFF_QOB      135667712ULL  // 256 f32
#define OFF_WP       135668736ULL  // 128x128 bf16
#define OFF_WFI      135701504ULL  // 704x128 bf16
#define OFF_WFO      135881728ULL  // 128x352 bf16
#define WS_NEEDED    135971840ULL
// NOTE: attn partials (1024*80*4 = 327KB) live in d_out during the attention
// phase (d_out is dead until proj_ln writes it).

typedef __attribute__((ext_vector_type(8))) short short8;
typedef __attribute__((ext_vector_type(4))) float floatx4;

__device__ __forceinline__ float bf2f(unsigned short u){
  union { unsigned int i; float f; } c; c.i = ((unsigned int)u) << 16; return c.f;
}
__device__ __forceinline__ unsigned short f2bf(float f){
  union { float f; unsigned int i; } c; c.f = f;
  unsigned int r = c.i + 0x7fffu + ((c.i >> 16) & 1u);
  return (unsigned short)(r >> 16);
}

// read 12 bf16 (4B-aligned) from LDS -> fp32
__device__ __forceinline__ void load_row12(const unsigned short* p, float* r){
  const unsigned int* q = (const unsigned int*)p;
  #pragma unroll
  for (int i=0;i<6;i++){
    unsigned int u = q[i];
    r[2*i]   = bf2f((unsigned short)(u & 0xffffu));
    r[2*i+1] = bf2f((unsigned short)(u >> 16));
  }
}

// read 10 bf16 (1 edge + aligned 8 + 1 edge) from LDS -> fp32
__device__ __forceinline__ void load_row10(const unsigned short* base, float* r){
  short8 B = *(const short8*)(base + 8);
  r[0] = bf2f(base[7]);
  #pragma unroll
  for (int i=0;i<8;i++) r[1+i] = bf2f((unsigned short)B[i]);
  r[9] = bf2f(base[16]);
}

// ------------------- RoPE tables: sin/cos[l][8] fp32 -------------------
__global__ void rope_kernel(float* __restrict__ sin_t, float* __restrict__ cos_t){
  int l = blockIdx.x*256 + threadIdx.x;
  if (l >= LSP) return;
  int h = l >> 7, w = l & 127;
  float s0 = sinf((float)h),        c0 = cosf((float)h);
  float s1 = sinf((float)h*1e-4f),  c1 = cosf((float)h*1e-4f);
  float s2 = sinf((float)w),        c2 = cosf((float)w);
  float s3 = sinf((float)w*1e-4f),  c3 = cosf((float)w*1e-4f);
  float* sp = sin_t + l*8; float* cp = cos_t + l*8;
  sp[0]=s0; sp[1]=s0; sp[2]=s1; sp[3]=s1; sp[4]=s2; sp[5]=s2; sp[6]=s3; sp[7]=s3;
  cp[0]=c0; cp[1]=c0; cp[2]=c1; cp[3]=c1; cp[4]=c2; cp[5]=c2; cp[6]=c3; cp[7]=c3;
}

// ------------------- weight fp32 -> padded bf16 -------------------
__global__ void wconv_kernel(const float* __restrict__ src, unsigned short* __restrict__ dst,
                             int O, int K, int OP, int KP){
  int i = blockIdx.x*256 + threadIdx.x;
  if (i >= OP*KP) return;
  int o = i / KP, k = i - o*KP;
  float v = (o < O && k < K) ? src[o*K + k] : 0.f;
  dst[i] = f2bf(v);
}

// ------------------- q/o weight+bias reorder: rows [0..128)+[384..512) -------------------
__global__ void reorder_qo_kernel(const float* __restrict__ qkvo_w, const float* __restrict__ qkvo_b,
                                  unsigned short* __restrict__ wqo, float* __restrict__ qo_bias){
  int i = blockIdx.x*256 + threadIdx.x;
  if (i < 256){
    qo_bias[i] = qkvo_b[(i < 128) ? i : i + 256];
  }
  if (i >= 256*128) return;
  int o = i >> 7, k = i & 127;
  int srow = (o < 128) ? o : o + 256;
  wqo[i] = f2bf(qkvo_w[srow*128 + k]);
}

// ------------------- LayerNorm over 128 channels; out position-major bf16 -------------------
__launch_bounds__(256)
__global__ void ln_kernel(const float* __restrict__ x, const float* __restrict__ gam,
                          const float* __restrict__ bet, unsigned short* __restrict__ out_t){
  __shared__ float ps[2][128], pq[2][128];
  __shared__ unsigned short tile[128*132];
  int t = threadIdx.x;
  int pidx = t & 127;
  int half = t >> 7;
  int p0 = blockIdx.x*128;
  int p = p0 + pidx;
  int b = p >> 14, l = p & 16383;
  const float* xb = x + (((size_t)b) << 21) + (((size_t)(half*64)) << 14) + l;
  float vals[64];
  float s = 0.f, sq = 0.f;
  #pragma unroll
  for (int c = 0; c < 64; c++){
    float v = xb[(size_t)c << 14];
    vals[c] = v;
    s += v; sq += v*v;
  }
  ps[half][pidx] = s; pq[half][pidx] = sq;
  __syncthreads();
  float S = ps[0][pidx] + ps[1][pidx];
  float Q = pq[0][pidx] + pq[1][pidx];
  float mu = S * 0.0078125f;
  float var = Q * 0.0078125f - mu*mu;
  float rstd = rsqrtf(var + 1e-5f);
  #pragma unroll
  for (int c0 = 0; c0 < 64; c0 += 8){
    short8 vv;
    #pragma unroll
    for (int i = 0; i < 8; i++){
      int c = c0 + i;
      int cg = half*64 + c;
      vv[i] = (short)f2bf((vals[c] - mu) * rstd * gam[cg] + bet[cg]);
    }
    *(short8*)&tile[pidx*132 + half*64 + c0] = vv;
  }
  __syncthreads();
  unsigned short* og = out_t + ((size_t)p0 << 7);
  #pragma unroll
  for (int it = 0; it < 8; it++){
    int idx = it*256 + t;
    int row = idx >> 4;
    int col = (idx & 15) * 8;
    *(short8*)&og[(row << 7) + col] = *(const short8*)&tile[row*132 + col];
  }
}

// ------------------- MFMA GEMM: out[b][o][l] = sum_k W[o][k]*in_t[b*L+l][k] -------------------
// NL consecutive 128-position tiles per block. oc chunk from blockIdx.y.
template<int OPAD, int KPAD, int NL, bool HASBIAS, bool RESID, bool OUTBF16>
__launch_bounds__(256)
__global__ void gemm_kernel(const unsigned short* __restrict__ in_t,
                            const unsigned short* __restrict__ wb,
                            const float* __restrict__ bias,
                            const float* __restrict__ resid,
                            void* __restrict__ outp){
  constexpr int KS = KPAD / 32;
  constexpr int SBYTES = OUTBF16 ? (64*136*2) : (64*132*4);
  __shared__ __align__(16) unsigned char smem[SBYTES];
  const int t = threadIdx.x;
  const int lane = t & 63;
  const int wv = t >> 6;
  const int lane15 = lane & 15;
  const int quad = lane >> 4;
  const int oc = blockIdx.y;

  #pragma unroll 1
  for (int tl = 0; tl < NL; tl++){
    const int l0 = (blockIdx.x * NL + tl) * 128;
    const int b = l0 >> 14;
    const int lloc0 = l0 & 16383;

    short8 fb[2][KS];
    {
      const unsigned short* base = in_t + ((size_t)(l0 + wv*32 + lane15)) * KPAD + quad*8;
      #pragma unroll
      for (int nt = 0; nt < 2; nt++){
        #pragma unroll
        for (int ks = 0; ks < KS; ks++)
          fb[nt][ks] = *(const short8*)(base + (size_t)nt*16*KPAD + ks*32);
      }
    }
    floatx4 acc[4][2];
    #pragma unroll
    for (int mt=0; mt<4; mt++)
      #pragma unroll
      for (int nt=0; nt<2; nt++)
        acc[mt][nt] = (floatx4){0.f,0.f,0.f,0.f};
    #pragma unroll
    for (int ks = 0; ks < KS; ks++){
      short8 fa[4];
      const unsigned short* wrow = wb + ((size_t)(oc*64 + lane15)) * KPAD + ks*32 + quad*8;
      #pragma unroll
      for (int mt=0; mt<4; mt++)
        fa[mt] = *(const short8*)(wrow + (size_t)mt*16*KPAD);
      #pragma unroll
      for (int mt=0; mt<4; mt++)
        #pragma unroll
        for (int nt=0; nt<2; nt++)
          acc[mt][nt] = __builtin_amdgcn_mfma_f32_16x16x32_bf16(fa[mt], fb[nt][ks], acc[mt][nt], 0, 0, 0);
    }

    if (tl) __syncthreads();   // protect smem reuse across tiles

    if (OUTBF16){
      unsigned short* cs = (unsigned short*)smem;
      #pragma unroll
      for (int mt=0; mt<4; mt++)
        #pragma unroll
        for (int nt=0; nt<2; nt++)
          #pragma unroll
          for (int r=0; r<4; r++){
            const int o = mt*16 + quad*4 + r;
            float v = acc[mt][nt][r];
            if (HASBIAS) v += bias[oc*64 + o];
            cs[o*136 + wv*32 + nt*16 + lane15] = f2bf(v);
          }
      __syncthreads();
      unsigned short* og = (unsigned short*)outp;
      #pragma unroll
      for (int j=0; j<4; j++){
        int idx = j*256 + t;
        int row = idx >> 4;
        int col = (idx & 15) * 8;
        short8 v = *(const short8*)&cs[row*136 + col];
        *(short8*)&og[(((size_t)(b*OPAD + oc*64 + row)) << 14) + lloc0 + col] = v;
      }
    } else {
      float* cf = (float*)smem;
      #pragma unroll
      for (int mt=0; mt<4; mt++)
        #pragma unroll
        for (int nt=0; nt<2; nt++)
          #pragma unroll
          for (int r=0; r<4; r++){
            const int o = mt*16 + quad*4 + r;
            float v = acc[mt][nt][r];
            if (HASBIAS) v += bias[oc*64 + o];
            cf[o*132 + wv*32 + nt*16 + lane15] = v;
          }
      __syncthreads();
      float* og = (float*)outp;
      #pragma unroll
      for (int j=0; j<8; j++){
        int idx = j*256 + t;
        int row = idx >> 5;
        int col = (idx & 31) * 4;
        floatx4 v = *(const floatx4*)&cf[row*132 + col];
        if (RESID){
          floatx4 rv = *(const floatx4*)(resid + (((size_t)(b*128 + oc*64 + row)) << 14) + lloc0 + col);
          v += rv;
        }
        *(floatx4*)&og[(((size_t)(b*OPAD + oc*64 + row)) << 14) + lloc0 + col] = v;
      }
    }
  }
}

// ------------------- proj GEMM + residual + LayerNorm2 fused -------------------
// in_t: resg bf16 position-major. Computes x1 = W*in + b + x (fp32 -> x1out),
// then LN over the block's own 128-channel tile -> xn2 bf16 position-major,
// written IN PLACE over in_t rows (safe: full input tile register-loaded first).
__launch_bounds__(256)
__global__ void proj_ln_kernel(const unsigned short* __restrict__ in_t,
                               const unsigned short* __restrict__ wb,
                               const float* __restrict__ bias,
                               const float* __restrict__ resid,
                               const float* __restrict__ gam,
                               const float* __restrict__ bet,
                               float* __restrict__ x1out,
                               unsigned short* __restrict__ xn2out){
  __shared__ __align__(16) unsigned char smem[128*132*4];   // cf fp32 -> reused as tb ushort[128][136]
  __shared__ float ssum[8][128], qsum[8][128];
  __shared__ float muA[128], rsA[128];
  const int t = threadIdx.x;
  const int l0 = blockIdx.x * 128;
  const int b = l0 >> 14;
  const int lloc0 = l0 & 16383;
  const int lane = t & 63;
  const int wv = t >> 6;
  const int lane15 = lane & 15;
  const int quad = lane >> 4;

  // full input tile -> registers (enables in-place xn2 write later)
  short8 fb[2][4];
  {
    const unsigned short* base = in_t + ((size_t)(l0 + wv*32 + lane15)) * 128 + quad*8;
    #pragma unroll
    for (int nt = 0; nt < 2; nt++)
      #pragma unroll
      for (int ks = 0; ks < 4; ks++)
        fb[nt][ks] = *(const short8*)(base + (size_t)nt*16*128 + ks*32);
  }

  float* cf = (float*)smem;
  #pragma unroll 1
  for (int oc = 0; oc < 2; oc++){
    floatx4 acc[4][2];
    #pragma unroll
    for (int mt=0; mt<4; mt++)
      #pragma unroll
      for (int nt=0; nt<2; nt++)
        acc[mt][nt] = (floatx4){0.f,0.f,0.f,0.f};
    #pragma unroll
    for (int ks = 0; ks < 4; ks++){
      short8 fa[4];
      const unsigned short* wrow = wb + ((size_t)(oc*64 + lane15)) * 128 + ks*32 + quad*8;
      #pragma unroll
      for (int mt=0; mt<4; mt++)
        fa[mt] = *(const short8*)(wrow + (size_t)mt*16*128);
      #pragma unroll
      for (int mt=0; mt<4; mt++)
        #pragma unroll
        for (int nt=0; nt<2; nt++)
          acc[mt][nt] = __builtin_amdgcn_mfma_f32_16x16x32_bf16(fa[mt], fb[nt][ks], acc[mt][nt], 0, 0, 0);
    }
    #pragma unroll
    for (int mt=0; mt<4; mt++)
      #pragma unroll
      for (int nt=0; nt<2; nt++)
        #pragma unroll
        for (int r=0; r<4; r++){
          const int o = oc*64 + mt*16 + quad*4 + r;
          cf[o*132 + wv*32 + nt*16 + lane15] = acc[mt][nt][r] + bias[o];
        }
  }
  __syncthreads();

  // pass A: x1 = cf + resid -> global; keep in regs; per-position partial stats
  const int colg = (t & 31) * 4;
  const int rsub = t >> 5;             // 0..7
  floatx4 x1r[16];
  floatx4 s4 = (floatx4){0.f,0.f,0.f,0.f};
  floatx4 q4 = (floatx4){0.f,0.f,0.f,0.f};
  #pragma unroll
  for (int j=0; j<16; j++){
    int row = j*8 + rsub;              // channel 0..127
    floatx4 v = *(const floatx4*)&cf[row*132 + colg];
    floatx4 rv = *(const floatx4*)&resid[(((size_t)(b*128 + row)) << 14) + lloc0 + colg];
    v += rv;
    *(floatx4*)&x1out[(((size_t)(b*128 + row)) << 14) + lloc0 + colg] = v;
    x1r[j] = v;
    s4 += v;
    q4 += v*v;
  }
  #pragma unroll
  for (int e=0; e<4; e++){
    ssum[rsub][colg+e] = s4[e];
    qsum[rsub][colg+e] = q4[e];
  }
  __syncthreads();
  if (t < 128){
    float S = 0.f, Q = 0.f;
    #pragma unroll
    for (int g=0; g<8; g++){ S += ssum[g][t]; Q += qsum[g][t]; }
    float mu = S * 0.0078125f;
    float var = Q * 0.0078125f - mu*mu;
    muA[t] = mu;
    rsA[t] = rsqrtf(var + 1e-5f);
  }
  __syncthreads();

  // pass B: xn2 bf16 into transposed LDS tile (reuses cf memory; cf fully consumed)
  unsigned short* tb = (unsigned short*)smem;
  #pragma unroll
  for (int j=0; j<16; j++){
    int row = j*8 + rsub;
    float ga = gam[row], be = bet[row];
    #pragma unroll
    for (int e=0; e<4; e++){
      int p = colg + e;
      float xv = (x1r[j][e] - muA[p]) * rsA[p] * ga + be;
      tb[p*136 + row] = f2bf(xv);
    }
  }
  __syncthreads();
  unsigned short* og = xn2out + ((size_t)l0 << 7);
  #pragma unroll
  for (int it = 0; it < 8; it++){
    int idx = it*256 + t;
    int prow = idx >> 4;
    int ccol = (idx & 15) * 8;
    *(short8*)&og[(prow << 7) + ccol] = *(const short8*)&tb[prow*136 + ccol];
  }
}

// ------------------- FFN-out GEMM with fused transpose of g -------------------
__launch_bounds__(256)
__global__ void ffn_out_gemm(const unsigned short* __restrict__ g,
                             const unsigned short* __restrict__ wb,
                             float* __restrict__ outp){
  __shared__ __align__(16) unsigned char smem[64*132*4];   // union: 2x 10240B stage | cf
  const int t = threadIdx.x;
  const int l0 = blockIdx.x * 128;
  const int b = l0 >> 14;
  const int lloc0 = l0 & 16383;
  const int lane = t & 63;
  const int wv = t >> 6;
  const int lane15 = lane & 15;
  const int quad = lane >> 4;
  const int oc = blockIdx.y;
  const int jj = t >> 3;      // 0..31 : j within slice
  const int c8 = t & 7;       // chunk base

  auto stage = [&](int s, int bufi){
    unsigned short* buf = (unsigned short*)(smem + bufi*10240);
    int j = s*32 + jj;
    const unsigned short* src = g + (((size_t)(b*NHID + j)) << 14) + lloc0;
    #pragma unroll
    for (int cc=0; cc<2; cc++){
      int c = c8 + cc*8;
      short8 v = (short8){0,0,0,0,0,0,0,0};
      if (j < NHID) v = *(const short8*)(src + c*8);
      #pragma unroll
      for (int e=0; e<8; e++)
        buf[(c*8+e)*40 + jj] = (unsigned short)v[e];
    }
  };

  floatx4 acc[4][2];
  #pragma unroll
  for (int mt=0; mt<4; mt++)
    #pragma unroll
    for (int nt=0; nt<2; nt++)
      acc[mt][nt] = (floatx4){0.f,0.f,0.f,0.f};

  stage(0, 0);
  #pragma unroll 1
  for (int s=0; s<11; s++){
    __syncthreads();
    if (s < 10) stage(s+1, (s+1)&1);
    const unsigned short* cur = (const unsigned short*)(smem + (s&1)*10240);
    short8 fbv[2];
    #pragma unroll
    for (int nt=0; nt<2; nt++)
      fbv[nt] = *(const short8*)&cur[(wv*32 + nt*16 + lane15)*40 + quad*8];
    const unsigned short* wrow = wb + ((size_t)(oc*64 + lane15))*352 + s*32 + quad*8;
    short8 fa[4];
    #pragma unroll
    for (int mt=0; mt<4; mt++)
      fa[mt] = *(const short8*)(wrow + (size_t)mt*16*352);
    #pragma unroll
    for (int mt=0; mt<4; mt++)
      #pragma unroll
      for (int nt=0; nt<2; nt++)
        acc[mt][nt] = __builtin_amdgcn_mfma_f32_16x16x32_bf16(fa[mt], fbv[nt], acc[mt][nt], 0, 0, 0);
  }
  __syncthreads();
  float* cf = (float*)smem;
  #pragma unroll
  for (int mt=0; mt<4; mt++)
    #pragma unroll
    for (int nt=0; nt<2; nt++)
      #pragma unroll
      for (int r=0; r<4; r++){
        const int o = mt*16 + quad*4 + r;
        cf[o*132 + wv*32 + nt*16 + lane15] = acc[mt][nt][r];
      }
  __syncthreads();
  #pragma unroll
  for (int j=0; j<8; j++){
    int idx = j*256 + t;
    int row = idx >> 5;
    int col = (idx & 31) * 4;
    floatx4 v = *(const floatx4*)&cf[row*132 + col];
    size_t oi = (((size_t)(b*128 + row)) << 14) + lloc0 + col + (((size_t)(oc*64)) << 14);
    floatx4 rv = *(const floatx4*)&outp[oi];
    v += rv;
    *(floatx4*)&outp[oi] = v;
  }
}

// ------------------- lepe: depthwise 5x5, LDS-staged sliding window -------------------
__launch_bounds__(256)
__global__ void lepe_kernel(const unsigned short* __restrict__ kv,
                            const float* __restrict__ lw, const float* __restrict__ lb,
                            unsigned short* __restrict__ lepe){
  __shared__ unsigned short lds[132*136];     // rows h+2 (0..131), cols w+2 (0..131), stride 136
  int bc = blockIdx.x;                        // b*128 + c
  int b = bc >> 7, c = bc & 127;
  int t = threadIdx.x;
  #pragma unroll
  for (int i = t; i < 132*136/8; i += 256)
    *(short8*)(lds + i*8) = (short8){0,0,0,0,0,0,0,0};
  __syncthreads();
  int band = t >> 4, wi = t & 15, w0 = wi*8;
  const unsigned short* vp = kv + (((size_t)(b*256 + 128 + c)) << 14);
  {
    #pragma unroll
    for (int it = 0; it < 8; it++){
      int hh = band + it*16;
      short8 v = *(const short8*)(vp + (hh<<7) + w0);
      unsigned int* dst = (unsigned int*)&lds[(hh+2)*136 + w0 + 2];
      union { short8 s; unsigned int u[4]; } cv; cv.s = v;
      #pragma unroll
      for (int q=0;q<4;q++) dst[q] = cv.u[q];
    }
  }
  float wt[25];
  #pragma unroll
  for (int i=0;i<25;i++) wt[i] = lw[c*25 + i];
  float bias = lb[c];
  __syncthreads();
  int h0 = band*8;
  float win[5][12];
  #pragma unroll
  for (int m=0;m<4;m++) load_row12(&lds[(h0+m)*136 + w0], win[m]);
  unsigned short* outp = lepe + ((size_t)bc << 14);
  #pragma unroll
  for (int s=0;s<8;s++){
    load_row12(&lds[(h0+4+s)*136 + w0], win[(4+s)%5]);
    short8 ov;
    #pragma unroll
    for (int j=0;j<8;j++){
      float acc = bias;
      #pragma unroll
      for (int dy=0;dy<5;dy++){
        const float* r = win[(s+dy)%5];
        #pragma unroll
        for (int dx=0;dx<5;dx++) acc += wt[dy*5+dx]*r[j+dx];
      }
      ov[j] = (short)f2bf(acc);
    }
    *(short8*)(outp + (h0+s)*128 + w0) = ov;
  }
}

// ------------------- attention reduction partials per (b,head,chunk of 2048) -------------------
__launch_bounds__(256)
__global__ void attn_partial(const unsigned short* __restrict__ kv,
                             const float* __restrict__ sin_t, const float* __restrict__ cos_t,
                             float* __restrict__ partials){
  int pair = blockIdx.x >> 3;
  int chunk = blockIdx.x & 7;
  int b = pair >> 4, hd = pair & 15;
  const unsigned short* kb = kv + (((size_t)(b*256 + hd*8)) << 14);
  const unsigned short* vb = kb + ((size_t)128 << 14);
  float red[80];
  #pragma unroll
  for (int i=0;i<80;i++) red[i]=0.f;
  int l0 = chunk*2048;
  for (int li=0; li<8; li++){
    int l = l0 + li*256 + threadIdx.x;
    float k[8], v[8], ks[8];
    #pragma unroll
    for (int e=0;e<8;e++){
      float t = bf2f(kb[((size_t)e<<14)+l]);
      k[e] = t>0.f ? t+1.f : __expf(t);
      v[e] = bf2f(vb[((size_t)e<<14)+l]);
      red[e]   += k[e];
      red[8+e] += v[e];
    }
    const float* sp = sin_t + l*8;
    const float* cp = cos_t + l*8;
    #pragma unroll
    for (int j=0;j<4;j++){
      float x1=k[2*j], x2=k[2*j+1];
      ks[2*j]   = x1*cp[2*j]   - x2*sp[2*j];
      ks[2*j+1] = x2*cp[2*j+1] + x1*sp[2*j+1];
    }
    #pragma unroll
    for (int d=0; d<8; d++)
      #pragma unroll
      for (int e=0;e<8;e++)
        red[16 + d*8 + e] += ks[d]*v[e];
  }
  #pragma unroll
  for (int off=32; off>0; off>>=1){
    #pragma unroll
    for (int i=0;i<80;i++)
      red[i] += __shfl_down(red[i], off);
  }
  __shared__ float lds[4][80];
  int lane = threadIdx.x & 63, wv = threadIdx.x >> 6;
  if (lane==0){
    #pragma unroll
    for (int i=0;i<80;i++) lds[wv][i] = red[i];
  }
  __syncthreads();
  if (threadIdx.x < 80){
    float s = lds[0][threadIdx.x]+lds[1][threadIdx.x]+lds[2][threadIdx.x]+lds[3][threadIdx.x];
    partials[(size_t)blockIdx.x*80 + threadIdx.x] = s;
  }
}

__global__ void attn_combine(const float* __restrict__ partials, float* __restrict__ stats){
  int i = blockIdx.x*256 + threadIdx.x;
  if (i >= 128*80) return;
  int pair = i / 80, idx = i - pair*80;
  float s = 0.f;
  #pragma unroll
  for (int cc=0; cc<8; cc++)
    s += partials[(size_t)(pair*8+cc)*80+idx];
  s *= (idx < 16) ? (1.f/LSP) : (ATT_SCALE/LSP);
  stats[i] = s;
}

// ------------------- attention apply + lepe add + o-gate; out position-major bf16 -------------------
__launch_bounds__(256)
__global__ void attn_apply_kernel(const unsigned short* __restrict__ qo,
                                  const unsigned short* __restrict__ lepe,
                                  const float* __restrict__ stats,
                                  const float* __restrict__ sin_t,
                                  const float* __restrict__ cos_t,
                                  unsigned short* __restrict__ resg_t){
  __shared__ float st[8*80];
  __shared__ unsigned short tile[256*66];
  int p0 = blockIdx.x * 256;
  int b = p0 >> 14;
  int hg = blockIdx.y;
  for (int i = threadIdx.x; i < 8*80; i += 256) st[i] = stats[b*16*80 + hg*8*80 + i];
  __syncthreads();
  int t = threadIdx.x;
  int p = p0 + t;
  int l = p & 16383;
  float sv[8], cv[8];
  {
    const float* sp = sin_t + l*8;
    const float* cp = cos_t + l*8;
    #pragma unroll
    for (int i=0;i<8;i++){ sv[i]=sp[i]; cv[i]=cp[i]; }
  }
  #pragma unroll 1
  for (int hd8=0; hd8<8; hd8++){
    int hd = hg*8 + hd8;
    const float* S = st + hd8*80;
    const unsigned short* qb = qo + (((size_t)(b*256 + hd*8)) << 14) + l;
    const unsigned short* ob = qb + ((size_t)128 << 14);
    const unsigned short* lb = lepe + (((size_t)(b*128 + hd*8)) << 14) + l;
    float q[8];
    #pragma unroll
    for (int e=0;e<8;e++){
      float tq = bf2f(qb[(size_t)e<<14]);
      q[e] = tq > 0.f ? tq + 1.f : __expf(tq);
    }
    float z = 0.f;
    #pragma unroll
    for (int e=0;e<8;e++) z += q[e]*S[e];
    z *= ATT_SCALE;
    float qs[8];
    #pragma unroll
    for (int jj=0;jj<4;jj++){
      float x1=q[2*jj], x2=q[2*jj+1];
      qs[2*jj]   = x1*cv[2*jj]   - x2*sv[2*jj];
      qs[2*jj+1] = x2*cv[2*jj+1] + x1*sv[2*jj+1];
    }
    float fac = 1.f + 1.f/(z + 1e-6f);
    short8 vv;
    #pragma unroll
    for (int e=0;e<8;e++){
      float r = 0.f;
      #pragma unroll
      for (int d=0; d<8; d++) r += qs[d]*S[16 + d*8 + e];
      r = r*fac - z*S[8+e];
      float val = (r + bf2f(lb[(size_t)e<<14])) * bf2f(ob[(size_t)e<<14]);
      vv[e] = (short)f2bf(val);
    }
    *(short8*)&tile[t*66 + hd8*8] = vv;
  }
  __syncthreads();
  unsigned short* og = resg_t + ((size_t)p0 << 7) + hg*64;
  #pragma unroll
  for (int it = 0; it < 8; it++){
    int idx = it*256 + t;
    int row = idx >> 3;
    int col = (idx & 7) * 8;
    *(short8*)&og[(row << 7) + col] = *(const short8*)&tile[row*66 + col];
  }
}

// ------------------- ffn dw3x3 x2 + exact gelu gate, LDS-staged; plane-major out -------------------
#define FPL (66*144)
__launch_bounds__(256)
__global__ void ffn_dwg_kernel(const unsigned short* __restrict__ p,
                               const float* __restrict__ dw,
                               unsigned short* __restrict__ g){
  __shared__ unsigned short lds[2*FPL];     // 2 planes, rows 66 (h-halo), cols w+8 (0..143)
  int bid = blockIdx.x;
  int jc = bid % NHID;
  int rest = bid / NHID;
  int bb = rest & 1;
  int half = rest >> 1;
  int t = threadIdx.x;
  #pragma unroll
  for (int i = t; i < 2*FPL/8; i += 256)
    *(short8*)(lds + i*8) = (short8){0,0,0,0,0,0,0,0};
  __syncthreads();
  int band = t >> 4, wi = t & 15, w0 = wi*8;
  #pragma unroll
  for (int pl=0; pl<2; pl++){
    const unsigned short* src = p + (((size_t)(bb*704 + jc + pl*NHID)) << 14);
    #pragma unroll
    for (int it=0; it<5; it++){
      int r_idx = it*16 + band;
      if (r_idx < 66){
        int h = half*64 - 1 + r_idx;
        if ((unsigned)h < 128u){
          short8 v = *(const short8*)(src + (h<<7) + w0);
          *(short8*)(&lds[pl*FPL + r_idx*144 + w0 + 8]) = v;
        }
      }
    }
  }
  float w1[9], w2[9];
  #pragma unroll
  for (int i=0;i<9;i++){ w1[i] = dw[jc*9 + i]; w2[i] = dw[(jc+NHID)*9 + i]; }
  __syncthreads();
  int rb = band*4;
  float r1[3][10], r2[3][10];
  #pragma unroll
  for (int m=0;m<2;m++){
    load_row10(&lds[(rb+m)*144 + w0], r1[m]);
    load_row10(&lds[FPL + (rb+m)*144 + w0], r2[m]);
  }
  unsigned short* outp = g + (((size_t)(bb*NHID + jc)) << 14);
  #pragma unroll
  for (int s=0;s<4;s++){
    load_row10(&lds[(rb+2+s)*144 + w0], r1[(2+s)%3]);
    load_row10(&lds[FPL + (rb+2+s)*144 + w0], r2[(2+s)%3]);
    int h = half*64 + rb + s;
    short8 ov;
    #pragma unroll
    for (int j=0;j<8;j++){
      float c1 = 0.f, c2 = 0.f;
      #pragma unroll
      for (int dy=0;dy<3;dy++){
        const float* a = r1[(s+dy)%3];
        const float* bpt = r2[(s+dy)%3];
        #pragma unroll
        for (int dx=0;dx<3;dx++){
          c1 += w1[dy*3+dx]*a[j+dx];
          c2 += w2[dy*3+dx]*bpt[j+dx];
        }
      }
      float ge = 0.5f*c1*(1.f + erff(c1*0.70710678118654752f));
      ov[j] = (short)f2bf(ge*c2);
    }
    *(short8*)(outp + h*128 + w0) = ov;
  }
}

extern "C" void kernel_launch(void* const* d_in, const int* in_sizes, int n_in,
                              void* d_out, int out_size, void* d_ws, size_t ws_size,
                              hipStream_t stream){
  (void)in_sizes; (void)n_in; (void)out_size;
  if (ws_size < WS_NEEDED) return;
  const float* x        = (const float*)d_in[0];
  const float* ln1_w    = (const float*)d_in[1];
  const float* ln1_b    = (const float*)d_in[2];
  const float* qkvo_w   = (const float*)d_in[3];
  const float* qkvo_b   = (const float*)d_in[4];
  const float* lepe_w   = (const float*)d_in[5];
  const float* lepe_b   = (const float*)d_in[6];
  const float* proj_w   = (const float*)d_in[7];
  const float* proj_b   = (const float*)d_in[8];
  const float* ln2_w    = (const float*)d_in[9];
  const float* ln2_b    = (const float*)d_in[10];
  const float* ffn_in_w = (const float*)d_in[11];
  const float* ffn_dw_w = (const float*)d_in[12];
  const float* ffn_out_w= (const float*)d_in[13];

  char* ws = (char*)d_ws;
  unsigned short* bufA   = (unsigned short*)(ws + OFF_A);
  unsigned short* bufB   = (unsigned short*)(ws + OFF_B);
  unsigned short* lepe   = (unsigned short*)(ws + OFF_C);
  unsigned short* gbuf   = (unsigned short*)(ws + OFF_C);   // reuses lepe region in FFN phase
  float* stats           = (float*)(ws + OFF_STATS);
  float* sin_t           = (float*)(ws + OFF_SIN);
  float* cos_t           = (float*)(ws + OFF_COS);
  unsigned short* wq     = (unsigned short*)(ws + OFF_WQ);
  unsigned short* wqo    = (unsigned short*)(ws + OFF_WQO);
  float* qo_bias         = (float*)(ws + OFF_QOB);
  unsigned short* wp     = (unsigned short*)(ws + OFF_WP);
  unsigned short* wfi    = (unsigned short*)(ws + OFF_WFI);
  unsigned short* wfo    = (unsigned short*)(ws + OFF_WFO);
  const unsigned short* wkv = wq + 128*128;

  float* out_f = (float*)d_out;
  float* partials = out_f;       // d_out is dead until proj_ln -> safe attn-phase scratch
  dim3 blk(256);
  hipLaunchKernelGGL(rope_kernel, dim3(64), blk, 0, stream, sin_t, cos_t);
  hipLaunchKernelGGL(wconv_kernel, dim3((512*128)/256), blk, 0, stream, qkvo_w, wq, 512,128,512,128);
  hipLaunchKernelGGL(reorder_qo_kernel, dim3((256*128)/256), blk, 0, stream, qkvo_w, qkvo_b, wqo, qo_bias);
  hipLaunchKernelGGL(wconv_kernel, dim3((128*128)/256), blk, 0, stream, proj_w, wp, 128,128,128,128);
  hipLaunchKernelGGL(wconv_kernel, dim3((704*128)/256), blk, 0, stream, ffn_in_w, wfi, 680,128,704,128);
  hipLaunchKernelGGL(wconv_kernel, dim3((128*352)/256), blk, 0, stream, ffn_out_w, wfo, 128,340,128,352);

  // attention phase
  hipLaunchKernelGGL(ln_kernel, dim3(1024), blk, 0, stream, x, ln1_w, ln1_b, bufA);
  hipLaunchKernelGGL((gemm_kernel<256,128,8,true,false,true>), dim3(128,4), blk, 0, stream,
                     bufA, wkv, qkvo_b + 128, (const float*)nullptr, (void*)bufB);     // kv
  hipLaunchKernelGGL(lepe_kernel, dim3(1024), blk, 0, stream, bufB, lepe_w, lepe_b, lepe);
  hipLaunchKernelGGL(attn_partial, dim3(1024), blk, 0, stream, bufB, sin_t, cos_t, partials);
  hipLaunchKernelGGL(attn_combine, dim3(40), blk, 0, stream, partials, stats);
  hipLaunchKernelGGL((gemm_kernel<256,128,8,true,false,true>), dim3(128,4), blk, 0, stream,
                     bufA, wqo, qo_bias, (const float*)nullptr, (void*)bufB);          // qo
  hipLaunchKernelGGL(attn_apply_kernel, dim3(512,2), blk, 0, stream, bufB, lepe, stats, sin_t, cos_t, bufA);
  hipLaunchKernelGGL(proj_ln_kernel, dim3(1024), blk, 0, stream,
                     bufA, wp, proj_b, x, ln2_w, ln2_b, out_f, bufA);                  // x1 -> d_out, xn2 -> bufA

  // ffn phase
  for (int bp = 0; bp < 4; bp++){
    const unsigned short* xin = bufA + (size_t)bp*32768*128;
    float* outp = out_f + (size_t)bp*2*128*16384;
    hipLaunchKernelGGL((gemm_kernel<704,128,2,false,false,true>), dim3(128,11), blk, 0, stream,
                       xin, wfi, (const float*)nullptr, (const float*)nullptr, (void*)bufB);
    hipLaunchKernelGGL(ffn_dwg_kernel, dim3(1360), blk, 0, stream, bufB, ffn_dw_w, gbuf);
    hipLaunchKernelGGL(ffn_out_gemm, dim3(256,2), blk, 0, stream, gbuf, wfo, outp);
  }
}

// Round 10
// 637.037 us; speedup vs baseline: 1.3240x; 1.0397x over previous
//
#include <hip/hip_runtime.h>

#define LSP 16384            // H*W
#define NBATCH 8
#define NPOS (NBATCH*LSP)    // 131072
#define NHID 340
#define ATT_SCALE 0.35355339059327373f

// ---- workspace layout (bytes) ----
#define OFF_A        0ULL          // 32MB: xn_t -> resg_t -> xn2_t (in-place by proj_ln)
#define OFF_B        33554432ULL   // 67MB: kv -> qo ; FFN: pbuf2 (46MB)
#define OFF_C        100663296ULL  // 32MB: lepe ; FFN: gbuf (22.3MB)
#define OFF_STATS    134381568ULL  // 40KB
#define OFF_SIN      134422528ULL  // 512KB
#define OFF_COS      134946816ULL  // 512KB
#define OFF_WQ       135471104ULL  // 512x128 bf16
#define OFF_WQO      135602176ULL  // 256x128 bf16
#define OFF_QOB      135667712ULL  // 256 f32
#define OFF_WP       135668736ULL  // 128x128 bf16
#define OFF_WFI      135701504ULL  // 704x128 bf16
#define OFF_WFO      135881728ULL  // 128x352 bf16
#define WS_NEEDED    135971840ULL
// NOTE: attn partials (1024*80*4 = 327KB) live in d_out during the attention
// phase (d_out is dead until proj_ln writes it).

typedef __attribute__((ext_vector_type(8))) short short8;
typedef __attribute__((ext_vector_type(4))) float floatx4;

__device__ __forceinline__ float bf2f(unsigned short u){
  union { unsigned int i; float f; } c; c.i = ((unsigned int)u) << 16; return c.f;
}
__device__ __forceinline__ unsigned short f2bf(float f){
  union { float f; unsigned int i; } c; c.f = f;
  unsigned int r = c.i + 0x7fffu + ((c.i >> 16) & 1u);
  return (unsigned short)(r >> 16);
}

// read 12 bf16 (4B-aligned) from LDS -> fp32
__device__ __forceinline__ void load_row12(const unsigned short* p, float* r){
  const unsigned int* q = (const unsigned int*)p;
  #pragma unroll
  for (int i=0;i<6;i++){
    unsigned int u = q[i];
    r[2*i]   = bf2f((unsigned short)(u & 0xffffu));
    r[2*i+1] = bf2f((unsigned short)(u >> 16));
  }
}

// read 10 bf16 (1 edge + aligned 8 + 1 edge) from LDS -> fp32
__device__ __forceinline__ void load_row10(const unsigned short* base, float* r){
  short8 B = *(const short8*)(base + 8);
  r[0] = bf2f(base[7]);
  #pragma unroll
  for (int i=0;i<8;i++) r[1+i] = bf2f((unsigned short)B[i]);
  r[9] = bf2f(base[16]);
}

// ------------------- RoPE tables: sin/cos[l][8] fp32 -------------------
__global__ void rope_kernel(float* __restrict__ sin_t, float* __restrict__ cos_t){
  int l = blockIdx.x*256 + threadIdx.x;
  if (l >= LSP) return;
  int h = l >> 7, w = l & 127;
  float s0 = sinf((float)h),        c0 = cosf((float)h);
  float s1 = sinf((float)h*1e-4f),  c1 = cosf((float)h*1e-4f);
  float s2 = sinf((float)w),        c2 = cosf((float)w);
  float s3 = sinf((float)w*1e-4f),  c3 = cosf((float)w*1e-4f);
  float* sp = sin_t + l*8; float* cp = cos_t + l*8;
  sp[0]=s0; sp[1]=s0; sp[2]=s1; sp[3]=s1; sp[4]=s2; sp[5]=s2; sp[6]=s3; sp[7]=s3;
  cp[0]=c0; cp[1]=c0; cp[2]=c1; cp[3]=c1; cp[4]=c2; cp[5]=c2; cp[6]=c3; cp[7]=c3;
}

// ------------------- weight fp32 -> padded bf16 -------------------
__global__ void wconv_kernel(const float* __restrict__ src, unsigned short* __restrict__ dst,
                             int O, int K, int OP, int KP){
  int i = blockIdx.x*256 + threadIdx.x;
  if (i >= OP*KP) return;
  int o = i / KP, k = i - o*KP;
  float v = (o < O && k < K) ? src[o*K + k] : 0.f;
  dst[i] = f2bf(v);
}

// ------------------- q/o weight+bias reorder: rows [0..128)+[384..512) -------------------
__global__ void reorder_qo_kernel(const float* __restrict__ qkvo_w, const float* __restrict__ qkvo_b,
                                  unsigned short* __restrict__ wqo, float* __restrict__ qo_bias){
  int i = blockIdx.x*256 + threadIdx.x;
  if (i < 256){
    qo_bias[i] = qkvo_b[(i < 128) ? i : i + 256];
  }
  if (i >= 256*128) return;
  int o = i >> 7, k = i & 127;
  int srow = (o < 128) ? o : o + 256;
  wqo[i] = f2bf(qkvo_w[srow*128 + k]);
}

// ------------------- LayerNorm over 128 channels; out position-major bf16 -------------------
__launch_bounds__(256)
__global__ void ln_kernel(const float* __restrict__ x, const float* __restrict__ gam,
                          const float* __restrict__ bet, unsigned short* __restrict__ out_t){
  __shared__ float ps[2][128], pq[2][128];
  __shared__ unsigned short tile[128*132];
  int t = threadIdx.x;
  int pidx = t & 127;
  int half = t >> 7;
  int p0 = blockIdx.x*128;
  int p = p0 + pidx;
  int b = p >> 14, l = p & 16383;
  const float* xb = x + (((size_t)b) << 21) + (((size_t)(half*64)) << 14) + l;
  float vals[64];
  float s = 0.f, sq = 0.f;
  #pragma unroll
  for (int c = 0; c < 64; c++){
    float v = xb[(size_t)c << 14];
    vals[c] = v;
    s += v; sq += v*v;
  }
  ps[half][pidx] = s; pq[half][pidx] = sq;
  __syncthreads();
  float S = ps[0][pidx] + ps[1][pidx];
  float Q = pq[0][pidx] + pq[1][pidx];
  float mu = S * 0.0078125f;
  float var = Q * 0.0078125f - mu*mu;
  float rstd = rsqrtf(var + 1e-5f);
  #pragma unroll
  for (int c0 = 0; c0 < 64; c0 += 8){
    short8 vv;
    #pragma unroll
    for (int i = 0; i < 8; i++){
      int c = c0 + i;
      int cg = half*64 + c;
      vv[i] = (short)f2bf((vals[c] - mu) * rstd * gam[cg] + bet[cg]);
    }
    *(short8*)&tile[pidx*132 + half*64 + c0] = vv;
  }
  __syncthreads();
  unsigned short* og = out_t + ((size_t)p0 << 7);
  #pragma unroll
  for (int it = 0; it < 8; it++){
    int idx = it*256 + t;
    int row = idx >> 4;
    int col = (idx & 15) * 8;
    *(short8*)&og[(row << 7) + col] = *(const short8*)&tile[row*132 + col];
  }
}

// ------------------- MFMA GEMM: out[b][o][l] = sum_k W[o][k]*in_t[b*L+l][k] -------------------
// NL consecutive 128-position tiles per block. oc chunk from blockIdx.y.
template<int OPAD, int KPAD, int NL, bool HASBIAS, bool RESID, bool OUTBF16>
__launch_bounds__(256)
__global__ void gemm_kernel(const unsigned short* __restrict__ in_t,
                            const unsigned short* __restrict__ wb,
                            const float* __restrict__ bias,
                            const float* __restrict__ resid,
                            void* __restrict__ outp){
  constexpr int KS = KPAD / 32;
  constexpr int SBYTES = OUTBF16 ? (64*136*2) : (64*132*4);
  __shared__ __align__(16) unsigned char smem[SBYTES];
  const int t = threadIdx.x;
  const int lane = t & 63;
  const int wv = t >> 6;
  const int lane15 = lane & 15;
  const int quad = lane >> 4;
  const int oc = blockIdx.y;

  #pragma unroll 1
  for (int tl = 0; tl < NL; tl++){
    const int l0 = (blockIdx.x * NL + tl) * 128;
    const int b = l0 >> 14;
    const int lloc0 = l0 & 16383;

    short8 fb[2][KS];
    {
      const unsigned short* base = in_t + ((size_t)(l0 + wv*32 + lane15)) * KPAD + quad*8;
      #pragma unroll
      for (int nt = 0; nt < 2; nt++){
        #pragma unroll
        for (int ks = 0; ks < KS; ks++)
          fb[nt][ks] = *(const short8*)(base + (size_t)nt*16*KPAD + ks*32);
      }
    }
    floatx4 acc[4][2];
    #pragma unroll
    for (int mt=0; mt<4; mt++)
      #pragma unroll
      for (int nt=0; nt<2; nt++)
        acc[mt][nt] = (floatx4){0.f,0.f,0.f,0.f};
    #pragma unroll
    for (int ks = 0; ks < KS; ks++){
      short8 fa[4];
      const unsigned short* wrow = wb + ((size_t)(oc*64 + lane15)) * KPAD + ks*32 + quad*8;
      #pragma unroll
      for (int mt=0; mt<4; mt++)
        fa[mt] = *(const short8*)(wrow + (size_t)mt*16*KPAD);
      #pragma unroll
      for (int mt=0; mt<4; mt++)
        #pragma unroll
        for (int nt=0; nt<2; nt++)
          acc[mt][nt] = __builtin_amdgcn_mfma_f32_16x16x32_bf16(fa[mt], fb[nt][ks], acc[mt][nt], 0, 0, 0);
    }

    if (tl) __syncthreads();   // protect smem reuse across tiles

    if (OUTBF16){
      unsigned short* cs = (unsigned short*)smem;
      #pragma unroll
      for (int mt=0; mt<4; mt++)
        #pragma unroll
        for (int nt=0; nt<2; nt++)
          #pragma unroll
          for (int r=0; r<4; r++){
            const int o = mt*16 + quad*4 + r;
            float v = acc[mt][nt][r];
            if (HASBIAS) v += bias[oc*64 + o];
            cs[o*136 + wv*32 + nt*16 + lane15] = f2bf(v);
          }
      __syncthreads();
      unsigned short* og = (unsigned short*)outp;
      #pragma unroll
      for (int j=0; j<4; j++){
        int idx = j*256 + t;
        int row = idx >> 4;
        int col = (idx & 15) * 8;
        short8 v = *(const short8*)&cs[row*136 + col];
        *(short8*)&og[(((size_t)(b*OPAD + oc*64 + row)) << 14) + lloc0 + col] = v;
      }
    } else {
      float* cf = (float*)smem;
      #pragma unroll
      for (int mt=0; mt<4; mt++)
        #pragma unroll
        for (int nt=0; nt<2; nt++)
          #pragma unroll
          for (int r=0; r<4; r++){
            const int o = mt*16 + quad*4 + r;
            float v = acc[mt][nt][r];
            if (HASBIAS) v += bias[oc*64 + o];
            cf[o*132 + wv*32 + nt*16 + lane15] = v;
          }
      __syncthreads();
      float* og = (float*)outp;
      #pragma unroll
      for (int j=0; j<8; j++){
        int idx = j*256 + t;
        int row = idx >> 5;
        int col = (idx & 31) * 4;
        floatx4 v = *(const floatx4*)&cf[row*132 + col];
        if (RESID){
          floatx4 rv = *(const floatx4*)(resid + (((size_t)(b*128 + oc*64 + row)) << 14) + lloc0 + col);
          v += rv;
        }
        *(floatx4*)&og[(((size_t)(b*OPAD + oc*64 + row)) << 14) + lloc0 + col] = v;
      }
    }
  }
}

// ------------------- proj GEMM + residual + LayerNorm2 fused -------------------
// MFMA part stages C into cf (fp32, stride 132). LN part uses the ln_kernel
// per-position scheme (2 threads/position, 64 channels each): cf column reads
// are 2-way banked, resid/x1out accesses coalesced, xn2 tile writes short8 at
// stride 132 (ln_kernel-proven). xn2 written IN PLACE over in_t rows (block-local).
__launch_bounds__(256)
__global__ void proj_ln_kernel(const unsigned short* __restrict__ in_t,
                               const unsigned short* __restrict__ wb,
                               const float* __restrict__ bias,
                               const float* __restrict__ resid,
                               const float* __restrict__ gam,
                               const float* __restrict__ bet,
                               float* __restrict__ x1out,
                               unsigned short* __restrict__ xn2out){
  __shared__ __align__(16) unsigned char smem[128*132*4];   // cf fp32 -> reused as tb ushort[128][132]
  __shared__ float ps[2][128], pq[2][128];
  const int t = threadIdx.x;
  const int l0 = blockIdx.x * 128;
  const int b = l0 >> 14;
  const int lloc0 = l0 & 16383;
  const int lane = t & 63;
  const int wv = t >> 6;
  const int lane15 = lane & 15;
  const int quad = lane >> 4;

  // full input tile -> registers (enables in-place xn2 write later)
  short8 fb[2][4];
  {
    const unsigned short* base = in_t + ((size_t)(l0 + wv*32 + lane15)) * 128 + quad*8;
    #pragma unroll
    for (int nt = 0; nt < 2; nt++)
      #pragma unroll
      for (int ks = 0; ks < 4; ks++)
        fb[nt][ks] = *(const short8*)(base + (size_t)nt*16*128 + ks*32);
  }

  float* cf = (float*)smem;
  #pragma unroll 1
  for (int oc = 0; oc < 2; oc++){
    floatx4 acc[4][2];
    #pragma unroll
    for (int mt=0; mt<4; mt++)
      #pragma unroll
      for (int nt=0; nt<2; nt++)
        acc[mt][nt] = (floatx4){0.f,0.f,0.f,0.f};
    #pragma unroll
    for (int ks = 0; ks < 4; ks++){
      short8 fa[4];
      const unsigned short* wrow = wb + ((size_t)(oc*64 + lane15)) * 128 + ks*32 + quad*8;
      #pragma unroll
      for (int mt=0; mt<4; mt++)
        fa[mt] = *(const short8*)(wrow + (size_t)mt*16*128);
      #pragma unroll
      for (int mt=0; mt<4; mt++)
        #pragma unroll
        for (int nt=0; nt<2; nt++)
          acc[mt][nt] = __builtin_amdgcn_mfma_f32_16x16x32_bf16(fa[mt], fb[nt][ks], acc[mt][nt], 0, 0, 0);
    }
    #pragma unroll
    for (int mt=0; mt<4; mt++)
      #pragma unroll
      for (int nt=0; nt<2; nt++)
        #pragma unroll
        for (int r=0; r<4; r++){
          const int o = oc*64 + mt*16 + quad*4 + r;
          cf[o*132 + wv*32 + nt*16 + lane15] = acc[mt][nt][r] + bias[o];
        }
  }
  __syncthreads();

  // per-position LN (ln_kernel scheme): pidx = position, half = channel half
  const int pidx = t & 127;
  const int half = t >> 7;
  float vals[64];
  float s = 0.f, sq = 0.f;
  const float* resb = resid + (((size_t)(b*128 + half*64)) << 14) + lloc0 + pidx;
  float* x1b = x1out + (((size_t)(b*128 + half*64)) << 14) + lloc0 + pidx;
  #pragma unroll
  for (int c = 0; c < 64; c++){
    float v = cf[(half*64 + c)*132 + pidx] + resb[(size_t)c << 14];
    x1b[(size_t)c << 14] = v;
    vals[c] = v;
    s += v; sq += v*v;
  }
  ps[half][pidx] = s; pq[half][pidx] = sq;
  __syncthreads();                       // also fences all cf reads before tb overwrite
  float S = ps[0][pidx] + ps[1][pidx];
  float Q = pq[0][pidx] + pq[1][pidx];
  float mu = S * 0.0078125f;
  float var = Q * 0.0078125f - mu*mu;
  float rstd = rsqrtf(var + 1e-5f);
  unsigned short* tb = (unsigned short*)smem;   // aliases cf (fully consumed)
  #pragma unroll
  for (int c0 = 0; c0 < 64; c0 += 8){
    short8 vv;
    #pragma unroll
    for (int i = 0; i < 8; i++){
      int cg = half*64 + c0 + i;
      vv[i] = (short)f2bf((vals[c0+i] - mu) * rstd * gam[cg] + bet[cg]);
    }
    *(short8*)&tb[pidx*132 + half*64 + c0] = vv;
  }
  __syncthreads();
  unsigned short* og = xn2out + ((size_t)l0 << 7);
  #pragma unroll
  for (int it = 0; it < 8; it++){
    int idx = it*256 + t;
    int prow = idx >> 4;
    int ccol = (idx & 15) * 8;
    *(short8*)&og[(prow << 7) + ccol] = *(const short8*)&tb[prow*132 + ccol];
  }
}

// ------------------- FFN-out GEMM with fused transpose of g -------------------
__launch_bounds__(256)
__global__ void ffn_out_gemm(const unsigned short* __restrict__ g,
                             const unsigned short* __restrict__ wb,
                             float* __restrict__ outp){
  __shared__ __align__(16) unsigned char smem[64*132*4];   // union: 2x 10240B stage | cf
  const int t = threadIdx.x;
  const int l0 = blockIdx.x * 128;
  const int b = l0 >> 14;
  const int lloc0 = l0 & 16383;
  const int lane = t & 63;
  const int wv = t >> 6;
  const int lane15 = lane & 15;
  const int quad = lane >> 4;
  const int oc = blockIdx.y;
  const int jj = t >> 3;      // 0..31 : j within slice
  const int c8 = t & 7;       // chunk base

  auto stage = [&](int s, int bufi){
    unsigned short* buf = (unsigned short*)(smem + bufi*10240);
    int j = s*32 + jj;
    const unsigned short* src = g + (((size_t)(b*NHID + j)) << 14) + lloc0;
    #pragma unroll
    for (int cc=0; cc<2; cc++){
      int c = c8 + cc*8;
      short8 v = (short8){0,0,0,0,0,0,0,0};
      if (j < NHID) v = *(const short8*)(src + c*8);
      #pragma unroll
      for (int e=0; e<8; e++)
        buf[(c*8+e)*40 + jj] = (unsigned short)v[e];
    }
  };

  floatx4 acc[4][2];
  #pragma unroll
  for (int mt=0; mt<4; mt++)
    #pragma unroll
    for (int nt=0; nt<2; nt++)
      acc[mt][nt] = (floatx4){0.f,0.f,0.f,0.f};

  stage(0, 0);
  #pragma unroll 1
  for (int s=0; s<11; s++){
    __syncthreads();
    if (s < 10) stage(s+1, (s+1)&1);
    const unsigned short* cur = (const unsigned short*)(smem + (s&1)*10240);
    short8 fbv[2];
    #pragma unroll
    for (int nt=0; nt<2; nt++)
      fbv[nt] = *(const short8*)&cur[(wv*32 + nt*16 + lane15)*40 + quad*8];
    const unsigned short* wrow = wb + ((size_t)(oc*64 + lane15))*352 + s*32 + quad*8;
    short8 fa[4];
    #pragma unroll
    for (int mt=0; mt<4; mt++)
      fa[mt] = *(const short8*)(wrow + (size_t)mt*16*352);
    #pragma unroll
    for (int mt=0; mt<4; mt++)
      #pragma unroll
      for (int nt=0; nt<2; nt++)
        acc[mt][nt] = __builtin_amdgcn_mfma_f32_16x16x32_bf16(fa[mt], fbv[nt], acc[mt][nt], 0, 0, 0);
  }
  __syncthreads();
  float* cf = (float*)smem;
  #pragma unroll
  for (int mt=0; mt<4; mt++)
    #pragma unroll
    for (int nt=0; nt<2; nt++)
      #pragma unroll
      for (int r=0; r<4; r++){
        const int o = mt*16 + quad*4 + r;
        cf[o*132 + wv*32 + nt*16 + lane15] = acc[mt][nt][r];
      }
  __syncthreads();
  #pragma unroll
  for (int j=0; j<8; j++){
    int idx = j*256 + t;
    int row = idx >> 5;
    int col = (idx & 31) * 4;
    floatx4 v = *(const floatx4*)&cf[row*132 + col];
    size_t oi = (((size_t)(b*128 + oc*64 + row)) << 14) + lloc0 + col;
    floatx4 rv = *(const floatx4*)&outp[oi];
    v += rv;
    *(floatx4*)&outp[oi] = v;
  }
}

// ------------------- lepe: depthwise 5x5, LDS-staged sliding window -------------------
__launch_bounds__(256)
__global__ void lepe_kernel(const unsigned short* __restrict__ kv,
                            const float* __restrict__ lw, const float* __restrict__ lb,
                            unsigned short* __restrict__ lepe){
  __shared__ unsigned short lds[132*136];     // rows h+2 (0..131), cols w+2 (0..131), stride 136
  int bc = blockIdx.x;                        // b*128 + c
  int b = bc >> 7, c = bc & 127;
  int t = threadIdx.x;
  #pragma unroll
  for (int i = t; i < 132*136/8; i += 256)
    *(short8*)(lds + i*8) = (short8){0,0,0,0,0,0,0,0};
  __syncthreads();
  int band = t >> 4, wi = t & 15, w0 = wi*8;
  const unsigned short* vp = kv + (((size_t)(b*256 + 128 + c)) << 14);
  {
    #pragma unroll
    for (int it = 0; it < 8; it++){
      int hh = band + it*16;
      short8 v = *(const short8*)(vp + (hh<<7) + w0);
      unsigned int* dst = (unsigned int*)&lds[(hh+2)*136 + w0 + 2];
      union { short8 s; unsigned int u[4]; } cv; cv.s = v;
      #pragma unroll
      for (int q=0;q<4;q++) dst[q] = cv.u[q];
    }
  }
  float wt[25];
  #pragma unroll
  for (int i=0;i<25;i++) wt[i] = lw[c*25 + i];
  float bias = lb[c];
  __syncthreads();
  int h0 = band*8;
  float win[5][12];
  #pragma unroll
  for (int m=0;m<4;m++) load_row12(&lds[(h0+m)*136 + w0], win[m]);
  unsigned short* outp = lepe + ((size_t)bc << 14);
  #pragma unroll
  for (int s=0;s<8;s++){
    load_row12(&lds[(h0+4+s)*136 + w0], win[(4+s)%5]);
    short8 ov;
    #pragma unroll
    for (int j=0;j<8;j++){
      float acc = bias;
      #pragma unroll
      for (int dy=0;dy<5;dy++){
        const float* r = win[(s+dy)%5];
        #pragma unroll
        for (int dx=0;dx<5;dx++) acc += wt[dy*5+dx]*r[j+dx];
      }
      ov[j] = (short)f2bf(acc);
    }
    *(short8*)(outp + (h0+s)*128 + w0) = ov;
  }
}

// ------------------- attention reduction partials per (b,head,chunk of 2048) -------------------
__launch_bounds__(256)
__global__ void attn_partial(const unsigned short* __restrict__ kv,
                             const float* __restrict__ sin_t, const float* __restrict__ cos_t,
                             float* __restrict__ partials){
  int pair = blockIdx.x >> 3;
  int chunk = blockIdx.x & 7;
  int b = pair >> 4, hd = pair & 15;
  const unsigned short* kb = kv + (((size_t)(b*256 + hd*8)) << 14);
  const unsigned short* vb = kb + ((size_t)128 << 14);
  float red[80];
  #pragma unroll
  for (int i=0;i<80;i++) red[i]=0.f;
  int l0 = chunk*2048;
  for (int li=0; li<8; li++){
    int l = l0 + li*256 + threadIdx.x;
    float k[8], v[8], ks[8];
    #pragma unroll
    for (int e=0;e<8;e++){
      float t = bf2f(kb[((size_t)e<<14)+l]);
      k[e] = t>0.f ? t+1.f : __expf(t);
      v[e] = bf2f(vb[((size_t)e<<14)+l]);
      red[e]   += k[e];
      red[8+e] += v[e];
    }
    const float* sp = sin_t + l*8;
    const float* cp = cos_t + l*8;
    #pragma unroll
    for (int j=0;j<4;j++){
      float x1=k[2*j], x2=k[2*j+1];
      ks[2*j]   = x1*cp[2*j]   - x2*sp[2*j];
      ks[2*j+1] = x2*cp[2*j+1] + x1*sp[2*j+1];
    }
    #pragma unroll
    for (int d=0; d<8; d++)
      #pragma unroll
      for (int e=0;e<8;e++)
        red[16 + d*8 + e] += ks[d]*v[e];
  }
  #pragma unroll
  for (int off=32; off>0; off>>=1){
    #pragma unroll
    for (int i=0;i<80;i++)
      red[i] += __shfl_down(red[i], off);
  }
  __shared__ float lds[4][80];
  int lane = threadIdx.x & 63, wv = threadIdx.x >> 6;
  if (lane==0){
    #pragma unroll
    for (int i=0;i<80;i++) lds[wv][i] = red[i];
  }
  __syncthreads();
  if (threadIdx.x < 80){
    float s = lds[0][threadIdx.x]+lds[1][threadIdx.x]+lds[2][threadIdx.x]+lds[3][threadIdx.x];
    partials[(size_t)blockIdx.x*80 + threadIdx.x] = s;
  }
}

__global__ void attn_combine(const float* __restrict__ partials, float* __restrict__ stats){
  int i = blockIdx.x*256 + threadIdx.x;
  if (i >= 128*80) return;
  int pair = i / 80, idx = i - pair*80;
  float s = 0.f;
  #pragma unroll
  for (int cc=0; cc<8; cc++)
    s += partials[(size_t)(pair*8+cc)*80+idx];
  s *= (idx < 16) ? (1.f/LSP) : (ATT_SCALE/LSP);
  stats[i] = s;
}

// ------------------- attention apply + lepe add + o-gate; out position-major bf16 -------------------
__launch_bounds__(256)
__global__ void attn_apply_kernel(const unsigned short* __restrict__ qo,
                                  const unsigned short* __restrict__ lepe,
                                  const float* __restrict__ stats,
                                  const float* __restrict__ sin_t,
                                  const float* __restrict__ cos_t,
                                  unsigned short* __restrict__ resg_t){
  __shared__ float st[8*80];
  __shared__ unsigned short tile[256*66];
  int p0 = blockIdx.x * 256;
  int b = p0 >> 14;
  int hg = blockIdx.y;
  for (int i = threadIdx.x; i < 8*80; i += 256) st[i] = stats[b*16*80 + hg*8*80 + i];
  __syncthreads();
  int t = threadIdx.x;
  int p = p0 + t;
  int l = p & 16383;
  float sv[8], cv[8];
  {
    const float* sp = sin_t + l*8;
    const float* cp = cos_t + l*8;
    #pragma unroll
    for (int i=0;i<8;i++){ sv[i]=sp[i]; cv[i]=cp[i]; }
  }
  #pragma unroll 1
  for (int hd8=0; hd8<8; hd8++){
    int hd = hg*8 + hd8;
    const float* S = st + hd8*80;
    const unsigned short* qb = qo + (((size_t)(b*256 + hd*8)) << 14) + l;
    const unsigned short* ob = qb + ((size_t)128 << 14);
    const unsigned short* lb = lepe + (((size_t)(b*128 + hd*8)) << 14) + l;
    float q[8];
    #pragma unroll
    for (int e=0;e<8;e++){
      float tq = bf2f(qb[(size_t)e<<14]);
      q[e] = tq > 0.f ? tq + 1.f : __expf(tq);
    }
    float z = 0.f;
    #pragma unroll
    for (int e=0;e<8;e++) z += q[e]*S[e];
    z *= ATT_SCALE;
    float qs[8];
    #pragma unroll
    for (int jj=0;jj<4;jj++){
      float x1=q[2*jj], x2=q[2*jj+1];
      qs[2*jj]   = x1*cv[2*jj]   - x2*sv[2*jj];
      qs[2*jj+1] = x2*cv[2*jj+1] + x1*sv[2*jj+1];
    }
    float fac = 1.f + 1.f/(z + 1e-6f);
    short8 vv;
    #pragma unroll
    for (int e=0;e<8;e++){
      float r = 0.f;
      #pragma unroll
      for (int d=0; d<8; d++) r += qs[d]*S[16 + d*8 + e];
      r = r*fac - z*S[8+e];
      float val = (r + bf2f(lb[(size_t)e<<14])) * bf2f(ob[(size_t)e<<14]);
      vv[e] = (short)f2bf(val);
    }
    *(short8*)&tile[t*66 + hd8*8] = vv;
  }
  __syncthreads();
  unsigned short* og = resg_t + ((size_t)p0 << 7) + hg*64;
  #pragma unroll
  for (int it = 0; it < 8; it++){
    int idx = it*256 + t;
    int row = idx >> 3;
    int col = (idx & 7) * 8;
    *(short8*)&og[(row << 7) + col] = *(const short8*)&tile[row*66 + col];
  }
}

// ------------------- ffn dw3x3 x2 + exact gelu gate, LDS-staged; plane-major out -------------------
#define FPL (66*144)
__launch_bounds__(256)
__global__ void ffn_dwg_kernel(const unsigned short* __restrict__ p,
                               const float* __restrict__ dw,
                               unsigned short* __restrict__ g){
  __shared__ unsigned short lds[2*FPL];     // 2 planes, rows 66 (h-halo), cols w+8 (0..143)
  int bid = blockIdx.x;
  int jc = bid % NHID;
  int rest = bid / NHID;
  int bb = rest & 1;
  int half = rest >> 1;
  int t = threadIdx.x;
  #pragma unroll
  for (int i = t; i < 2*FPL/8; i += 256)
    *(short8*)(lds + i*8) = (short8){0,0,0,0,0,0,0,0};
  __syncthreads();
  int band = t >> 4, wi = t & 15, w0 = wi*8;
  #pragma unroll
  for (int pl=0; pl<2; pl++){
    const unsigned short* src = p + (((size_t)(bb*704 + jc + pl*NHID)) << 14);
    #pragma unroll
    for (int it=0; it<5; it++){
      int r_idx = it*16 + band;
      if (r_idx < 66){
        int h = half*64 - 1 + r_idx;
        if ((unsigned)h < 128u){
          short8 v = *(const short8*)(src + (h<<7) + w0);
          *(short8*)(&lds[pl*FPL + r_idx*144 + w0 + 8]) = v;
        }
      }
    }
  }
  float w1[9], w2[9];
  #pragma unroll
  for (int i=0;i<9;i++){ w1[i] = dw[jc*9 + i]; w2[i] = dw[(jc+NHID)*9 + i]; }
  __syncthreads();
  int rb = band*4;
  float r1[3][10], r2[3][10];
  #pragma unroll
  for (int m=0;m<2;m++){
    load_row10(&lds[(rb+m)*144 + w0], r1[m]);
    load_row10(&lds[FPL + (rb+m)*144 + w0], r2[m]);
  }
  unsigned short* outp = g + (((size_t)(bb*NHID + jc)) << 14);
  #pragma unroll
  for (int s=0;s<4;s++){
    load_row10(&lds[(rb+2+s)*144 + w0], r1[(2+s)%3]);
    load_row10(&lds[FPL + (rb+2+s)*144 + w0], r2[(2+s)%3]);
    int h = half*64 + rb + s;
    short8 ov;
    #pragma unroll
    for (int j=0;j<8;j++){
      float c1 = 0.f, c2 = 0.f;
      #pragma unroll
      for (int dy=0;dy<3;dy++){
        const float* a = r1[(s+dy)%3];
        const float* bpt = r2[(s+dy)%3];
        #pragma unroll
        for (int dx=0;dx<3;dx++){
          c1 += w1[dy*3+dx]*a[j+dx];
          c2 += w2[dy*3+dx]*bpt[j+dx];
        }
      }
      float ge = 0.5f*c1*(1.f + erff(c1*0.70710678118654752f));
      ov[j] = (short)f2bf(ge*c2);
    }
    *(short8*)(outp + h*128 + w0) = ov;
  }
}

extern "C" void kernel_launch(void* const* d_in, const int* in_sizes, int n_in,
                              void* d_out, int out_size, void* d_ws, size_t ws_size,
                              hipStream_t stream){
  (void)in_sizes; (void)n_in; (void)out_size;
  if (ws_size < WS_NEEDED) return;
  const float* x        = (const float*)d_in[0];
  const float* ln1_w    = (const float*)d_in[1];
  const float* ln1_b    = (const float*)d_in[2];
  const float* qkvo_w   = (const float*)d_in[3];
  const float* qkvo_b   = (const float*)d_in[4];
  const float* lepe_w   = (const float*)d_in[5];
  const float* lepe_b   = (const float*)d_in[6];
  const float* proj_w   = (const float*)d_in[7];
  const float* proj_b   = (const float*)d_in[8];
  const float* ln2_w    = (const float*)d_in[9];
  const float* ln2_b    = (const float*)d_in[10];
  const float* ffn_in_w = (const float*)d_in[11];
  const float* ffn_dw_w = (const float*)d_in[12];
  const float* ffn_out_w= (const float*)d_in[13];

  char* ws = (char*)d_ws;
  unsigned short* bufA   = (unsigned short*)(ws + OFF_A);
  unsigned short* bufB   = (unsigned short*)(ws + OFF_B);
  unsigned short* lepe   = (unsigned short*)(ws + OFF_C);
  unsigned short* gbuf   = (unsigned short*)(ws + OFF_C);   // reuses lepe region in FFN phase
  float* stats           = (float*)(ws + OFF_STATS);
  float* sin_t           = (float*)(ws + OFF_SIN);
  float* cos_t           = (float*)(ws + OFF_COS);
  unsigned short* wq     = (unsigned short*)(ws + OFF_WQ);
  unsigned short* wqo    = (unsigned short*)(ws + OFF_WQO);
  float* qo_bias         = (float*)(ws + OFF_QOB);
  unsigned short* wp     = (unsigned short*)(ws + OFF_WP);
  unsigned short* wfi    = (unsigned short*)(ws + OFF_WFI);
  unsigned short* wfo    = (unsigned short*)(ws + OFF_WFO);
  const unsigned short* wkv = wq + 128*128;

  float* out_f = (float*)d_out;
  float* partials = out_f;       // d_out is dead until proj_ln -> safe attn-phase scratch
  dim3 blk(256);
  hipLaunchKernelGGL(rope_kernel, dim3(64), blk, 0, stream, sin_t, cos_t);
  hipLaunchKernelGGL(wconv_kernel, dim3((512*128)/256), blk, 0, stream, qkvo_w, wq, 512,128,512,128);
  hipLaunchKernelGGL(reorder_qo_kernel, dim3((256*128)/256), blk, 0, stream, qkvo_w, qkvo_b, wqo, qo_bias);
  hipLaunchKernelGGL(wconv_kernel, dim3((128*128)/256), blk, 0, stream, proj_w, wp, 128,128,128,128);
  hipLaunchKernelGGL(wconv_kernel, dim3((704*128)/256), blk, 0, stream, ffn_in_w, wfi, 680,128,704,128);
  hipLaunchKernelGGL(wconv_kernel, dim3((128*352)/256), blk, 0, stream, ffn_out_w, wfo, 128,340,128,352);

  // attention phase
  hipLaunchKernelGGL(ln_kernel, dim3(1024), blk, 0, stream, x, ln1_w, ln1_b, bufA);
  hipLaunchKernelGGL((gemm_kernel<256,128,8,true,false,true>), dim3(128,4), blk, 0, stream,
                     bufA, wkv, qkvo_b + 128, (const float*)nullptr, (void*)bufB);     // kv
  hipLaunchKernelGGL(lepe_kernel, dim3(1024), blk, 0, stream, bufB, lepe_w, lepe_b, lepe);
  hipLaunchKernelGGL(attn_partial, dim3(1024), blk, 0, stream, bufB, sin_t, cos_t, partials);
  hipLaunchKernelGGL(attn_combine, dim3(40), blk, 0, stream, partials, stats);
  hipLaunchKernelGGL((gemm_kernel<256,128,8,true,false,true>), dim3(128,4), blk, 0, stream,
                     bufA, wqo, qo_bias, (const float*)nullptr, (void*)bufB);          // qo
  hipLaunchKernelGGL(attn_apply_kernel, dim3(512,2), blk, 0, stream, bufB, lepe, stats, sin_t, cos_t, bufA);
  hipLaunchKernelGGL(proj_ln_kernel, dim3(1024), blk, 0, stream,
                     bufA, wp, proj_b, x, ln2_w, ln2_b, out_f, bufA);                  // x1 -> d_out, xn2 -> bufA

  // ffn phase
  for (int bp = 0; bp < 4; bp++){
    const unsigned short* xin = bufA + (size_t)bp*32768*128;
    float* outp = out_f + (size_t)bp*2*128*16384;
    hipLaunchKernelGGL((gemm_kernel<704,128,4,false,false,true>), dim3(64,11), blk, 0, stream,
                       xin, wfi, (const float*)nullptr, (const float*)nullptr, (void*)bufB);
    hipLaunchKernelGGL(ffn_dwg_kernel, dim3(1360), blk, 0, stream, bufB, ffn_dw_w, gbuf);
    hipLaunchKernelGGL(ffn_out_gemm, dim3(256,2), blk, 0, stream, gbuf, wfo, outp);
  }
}